// Round 2
// baseline (1682.167 us; speedup 1.0000x reference)
//
#include <hip/hip_runtime.h>
#include <hip/hip_bf16.h>

// Problem constants (from reference)
#define LSEQ   2048
#define BSZN   2
#define DMODEL 1024
#define NHEAD  16
#define DH     64
#define MPROJ  256
#define PF     512   // 2*MPROJ feature dim
#define CHK    64    // chunk length
#define NCHK   32    // LSEQ/CHK
#define BHN    32    // BSZN*NHEAD
#define NQKV   3088  // NHEAD*(3*DH+1)

typedef __hip_bfloat16 bf16;

// unpack a u32 holding two bf16 (little-endian: low half = first element)
#define UNP(u, a, b) { a = __uint_as_float((unsigned)(u) << 16); b = __uint_as_float((unsigned)(u) & 0xffff0000u); }

static __device__ __forceinline__ float b2f(bf16 x) {
  unsigned short us = *(unsigned short*)&x;
  return __uint_as_float((unsigned)us << 16);
}
static __device__ __forceinline__ bf16 f2b(float x) { return __float2bfloat16(x); }

// ---------------------------------------------------------------------------
// K1: qkvb = h @ W_qkvb, scattered to per-head (bh, l, *) layout (q/k/v bf16),
// sigmoid on b (f32). f32 tiled GEMM, BM=128, BN=64, BK=16, 256 thr, 8x4 tile.
// ---------------------------------------------------------------------------
__global__ __launch_bounds__(256)
void k_qkvb(const float* __restrict__ h, const float* __restrict__ Wq,
            bf16* __restrict__ qh, bf16* __restrict__ kh,
            bf16* __restrict__ vh, float* __restrict__ bbuf)
{
  __shared__ float sA[16][128];
  __shared__ float sB[16][68];
  const int tid = threadIdx.x;
  const int m0 = blockIdx.y * 128, n0 = blockIdx.x * 64;
  const int ty = tid >> 4, tx = tid & 15;
  float acc[8][4];
#pragma unroll
  for (int i = 0; i < 8; i++)
#pragma unroll
    for (int j = 0; j < 4; j++) acc[i][j] = 0.f;

  for (int k0 = 0; k0 < DMODEL; k0 += 16) {
    {
      const int row = tid >> 1;
      const int kq = (tid & 1) * 8;
      const float4 a0 = *(const float4*)&h[(size_t)(m0 + row) * DMODEL + k0 + kq];
      const float4 a1 = *(const float4*)&h[(size_t)(m0 + row) * DMODEL + k0 + kq + 4];
      sA[kq + 0][row] = a0.x; sA[kq + 1][row] = a0.y; sA[kq + 2][row] = a0.z; sA[kq + 3][row] = a0.w;
      sA[kq + 4][row] = a1.x; sA[kq + 5][row] = a1.y; sA[kq + 6][row] = a1.z; sA[kq + 7][row] = a1.w;
    }
    {
      const int krow = tid >> 4;
      const int nq = (tid & 15) * 4;
      const int col = n0 + nq;
      float4 b4 = make_float4(0.f, 0.f, 0.f, 0.f);
      if (col < NQKV) b4 = *(const float4*)&Wq[(size_t)(k0 + krow) * NQKV + col];
      sB[krow][nq + 0] = b4.x; sB[krow][nq + 1] = b4.y; sB[krow][nq + 2] = b4.z; sB[krow][nq + 3] = b4.w;
    }
    __syncthreads();
#pragma unroll
    for (int kk = 0; kk < 16; kk++) {
      const float4 av0 = *(const float4*)&sA[kk][ty * 8];
      const float4 av1 = *(const float4*)&sA[kk][ty * 8 + 4];
      const float4 bv  = *(const float4*)&sB[kk][tx * 4];
      const float a[8] = {av0.x, av0.y, av0.z, av0.w, av1.x, av1.y, av1.z, av1.w};
      const float b[4] = {bv.x, bv.y, bv.z, bv.w};
#pragma unroll
      for (int i = 0; i < 8; i++)
#pragma unroll
        for (int j = 0; j < 4; j++) acc[i][j] = fmaf(a[i], b[j], acc[i][j]);
    }
    __syncthreads();
  }

#pragma unroll
  for (int i = 0; i < 8; i++) {
    const int row = m0 + ty * 8 + i;
    const int l = row >> 1, bidx = row & 1;
#pragma unroll
    for (int j = 0; j < 4; j++) {
      const int col = n0 + tx * 4 + j;
      if (col >= NQKV) continue;
      const int hd = col / 193;
      const int rem = col - hd * 193;
      const int bhi = bidx * NHEAD + hd;
      const float v = acc[i][j];
      const size_t o = ((size_t)bhi * LSEQ + l) * DH;
      if (rem < 64)        qh[o + rem] = f2b(v);
      else if (rem < 128)  kh[o + rem - 64] = f2b(v);
      else if (rem < 192)  vh[o + rem - 128] = f2b(v);
      else                 bbuf[(size_t)bhi * LSEQ + l] = 1.f / (1.f + __expf(-v));
    }
  }
}

// ---------------------------------------------------------------------------
// K2: FAVOR+ features for q and k, normalized over the 512 dims, stored bf16.
// One block per (l, bh); 256 threads = 256 projection columns.
// ---------------------------------------------------------------------------
__global__ __launch_bounds__(256)
void k_feat(const bf16* __restrict__ qh, const bf16* __restrict__ kh,
            const float* __restrict__ pm,
            bf16* __restrict__ Qp, bf16* __restrict__ Kp)
{
  const int l = blockIdx.x;
  const int bhi = blockIdx.y;
  const int tid = threadIdx.x;
  __shared__ float xr[DH];
  __shared__ float red[4];
  __shared__ float stot;

  for (int which = 0; which < 2; which++) {
    const bf16* src = which ? kh : qh;
    bf16* dst = which ? Kp : Qp;
    if (tid < DH) xr[tid] = b2f(src[((size_t)bhi * LSEQ + l) * DH + tid]) * 0.35355339059327373f;
    __syncthreads();
    float hn = 0.f;
#pragma unroll
    for (int d = 0; d < DH; d++) hn = fmaf(xr[d], xr[d], hn);
    hn *= 0.5f;
    float pr = 0.f;
#pragma unroll
    for (int d = 0; d < DH; d++) pr = fmaf(xr[d], pm[d * MPROJ + tid], pr);
    const float ep = __expf(pr - hn) + 1e-4f;
    const float en = __expf(-pr - hn) + 1e-4f;
    float s = ep + en;
    for (int off = 32; off > 0; off >>= 1) s += __shfl_down(s, off);
    if ((tid & 63) == 0) red[tid >> 6] = s;
    __syncthreads();
    if (tid == 0) stot = red[0] + red[1] + red[2] + red[3];
    __syncthreads();
    const float inv = 1.f / stot;
    const size_t base = ((size_t)bhi * LSEQ + l) * PF;
    dst[base + tid] = f2b(ep * inv);
    dst[base + MPROJ + tid] = f2b(en * inv);
    __syncthreads();
  }
}

// ---------------------------------------------------------------------------
// K3: fused per (chunk, bh):
//   S = Kp Kp^T (f32, LDS), Gs = triu_strict(Qp Kp^T) (bf16, global),
//   T = (I + tril_strict(diag(b)S))^{-1} diag(b)  (forward substitution,
//   64 columns, one per lane of wave 0), stored bf16 full 64x64 (upper = 0).
// ---------------------------------------------------------------------------
__global__ __launch_bounds__(256)
void k_sgsolve(const bf16* __restrict__ Kp, const bf16* __restrict__ Qp,
               const float* __restrict__ bbuf,
               bf16* __restrict__ Gs, bf16* __restrict__ Tm)
{
  __shared__ float sK[CHK][65];   // staging; reused as S after the GEMM loop
  __shared__ float sQ[CHK][65];   // staging; reused as T
  __shared__ float sBeta[CHK];
  const int tid = threadIdx.x;
  const int c = blockIdx.x, bhi = blockIdx.y;
  const int ty = tid >> 4, tx = tid & 15;
  const size_t cb = ((size_t)bhi * LSEQ + (size_t)c * CHK) * PF;
  const size_t rowb = (size_t)bhi * LSEQ + (size_t)c * CHK;

  float accS[4][4], accG[4][4];
#pragma unroll
  for (int i = 0; i < 4; i++)
#pragma unroll
    for (int j = 0; j < 4; j++) { accS[i][j] = 0.f; accG[i][j] = 0.f; }

  for (int p0 = 0; p0 < PF; p0 += 64) {
    {
      const int row = tid >> 2;
      const int pc = (tid & 3) * 16;
      const uint4* sk = (const uint4*)(Kp + cb + (size_t)row * PF + p0 + pc);
      const uint4* sq = (const uint4*)(Qp + cb + (size_t)row * PF + p0 + pc);
      const uint4 k0 = sk[0], k1 = sk[1], q0 = sq[0], q1 = sq[1];
      float f[16];
      UNP(k0.x, f[0], f[1]); UNP(k0.y, f[2], f[3]); UNP(k0.z, f[4], f[5]); UNP(k0.w, f[6], f[7]);
      UNP(k1.x, f[8], f[9]); UNP(k1.y, f[10], f[11]); UNP(k1.z, f[12], f[13]); UNP(k1.w, f[14], f[15]);
#pragma unroll
      for (int t = 0; t < 16; t++) sK[row][pc + t] = f[t];
      UNP(q0.x, f[0], f[1]); UNP(q0.y, f[2], f[3]); UNP(q0.z, f[4], f[5]); UNP(q0.w, f[6], f[7]);
      UNP(q1.x, f[8], f[9]); UNP(q1.y, f[10], f[11]); UNP(q1.z, f[12], f[13]); UNP(q1.w, f[14], f[15]);
#pragma unroll
      for (int t = 0; t < 16; t++) sQ[row][pc + t] = f[t];
    }
    __syncthreads();
#pragma unroll 8
    for (int kk = 0; kk < 64; kk++) {
      float bj[4], ai[4], aq[4];
#pragma unroll
      for (int j = 0; j < 4; j++) bj[j] = sK[tx * 4 + j][kk];
#pragma unroll
      for (int i = 0; i < 4; i++) { ai[i] = sK[ty * 4 + i][kk]; aq[i] = sQ[ty * 4 + i][kk]; }
#pragma unroll
      for (int i = 0; i < 4; i++)
#pragma unroll
        for (int j = 0; j < 4; j++) {
          accS[i][j] = fmaf(ai[i], bj[j], accS[i][j]);
          accG[i][j] = fmaf(aq[i], bj[j], accG[i][j]);
        }
    }
    __syncthreads();
  }

  const size_t sb = (((size_t)bhi * NCHK + c) * CHK) * CHK;
#pragma unroll
  for (int i = 0; i < 4; i++) {
    const int ri = ty * 4 + i;
#pragma unroll
    for (int j = 0; j < 4; j++) {
      const int cj = tx * 4 + j;
      Gs[sb + ri * CHK + cj] = f2b((cj > ri) ? accG[i][j] : 0.f);
      sK[ri][cj] = accS[i][j];          // stash full S
    }
  }
  if (tid < CHK) sBeta[tid] = bbuf[rowb + tid];
  __syncthreads();

  // forward substitution, column j per lane; rows i<j fall out as exact zeros
  if (tid < CHK) {
    const int j = tid;
    for (int i = 0; i < CHK; i++) {
      float acc = (i == j) ? 1.f : 0.f;
      for (int k = 0; k < i; k++) acc = fmaf(-sK[i][k], sQ[k][j], acc);
      sQ[i][j] = sBeta[i] * acc;
    }
  }
  __syncthreads();
  for (int t = tid; t < CHK * CHK; t += 256)
    Tm[sb + t] = f2b(sQ[t >> 6][t & 63]);
}

// ---------------------------------------------------------------------------
// K4: sequential chunk scan, fused output. One block per (d-block of 16, bh).
// LDS-resident W (512 x 16, f32, row stride 18). Per chunk:
//   upre = V - Kp*W ; U = T*upre ; W += Kp^T U ; out = 0.125*(Qp*W - Gs*U)
// (Gs = strict-upper(QpKp^T); W here is the post-update state, identity
//  out_i = W_new^T q_i - sum_{j>i} (k_j.q_i) u_j.)
// ---------------------------------------------------------------------------
#define STAGE_CHUNK(SRC) \
  for (int t = tid; t < CHK * PF / 8; t += 512) { \
    const int idx = t << 3; \
    const int r = idx >> 9, pc = idx & 511; \
    *(uint4*)&sbuf[r * 520 + pc] = *(const uint4*)((SRC) + (size_t)r * PF + pc); \
  }

#define STAGE_T(SRC) \
  { const int idx = tid << 3; const int r = idx >> 6, cc = idx & 63; \
    *(uint4*)&tB[r * 72 + cc] = *(const uint4*)((SRC) + idx); }

#define DOT8(SROW, P) \
  { const uint4 v = *(const uint4*)((SROW) + (P)); \
    float f0,f1,f2,f3,f4,f5,f6,f7; \
    UNP(v.x, f0, f1); UNP(v.y, f2, f3); UNP(v.z, f4, f5); UNP(v.w, f6, f7); \
    const float* wp = sW + (P) * 18 + dd; \
    float2 w; \
    w = *(const float2*)(wp +   0); a0 = fmaf(f0, w.x, a0); a1 = fmaf(f0, w.y, a1); \
    w = *(const float2*)(wp +  18); a0 = fmaf(f1, w.x, a0); a1 = fmaf(f1, w.y, a1); \
    w = *(const float2*)(wp +  36); a0 = fmaf(f2, w.x, a0); a1 = fmaf(f2, w.y, a1); \
    w = *(const float2*)(wp +  54); a0 = fmaf(f3, w.x, a0); a1 = fmaf(f3, w.y, a1); \
    w = *(const float2*)(wp +  72); a0 = fmaf(f4, w.x, a0); a1 = fmaf(f4, w.y, a1); \
    w = *(const float2*)(wp +  90); a0 = fmaf(f5, w.x, a0); a1 = fmaf(f5, w.y, a1); \
    w = *(const float2*)(wp + 108); a0 = fmaf(f6, w.x, a0); a1 = fmaf(f6, w.y, a1); \
    w = *(const float2*)(wp + 126); a0 = fmaf(f7, w.x, a0); a1 = fmaf(f7, w.y, a1); }

__global__ __launch_bounds__(512)
void k_scan(const bf16* __restrict__ Kp, const bf16* __restrict__ Qp,
            const bf16* __restrict__ vh, const bf16* __restrict__ Tm,
            const bf16* __restrict__ Gs, float* __restrict__ lo)
{
  __shared__ float sW[PF * 18];                 // W, row stride 18 (bank spread)
  __shared__ __align__(16) bf16 sbuf[CHK * 520];
  __shared__ float uB[CHK][16];
  __shared__ __align__(16) bf16 tB[CHK * 72];   // T, then Gs (row stride 72)

  const int tid = threadIdx.x;
  const int dq = blockIdx.x;          // 0..3, local d-cols [dq*16, dq*16+16)
  const int bhi = blockIdx.y;
  const int bidx = bhi >> 4, hd = bhi & 15;

  for (int t = tid; t < PF * 18; t += 512) sW[t] = 0.f;

  const int yi = tid >> 3;            // 0..63 (row in chunk)
  const int dd = (tid & 7) * 2;       // 0,2,...,14 (local d pair)

  for (int c = 0; c < NCHK; c++) {
    const size_t cb = ((size_t)bhi * LSEQ + (size_t)c * CHK) * PF;
    const size_t tb = (((size_t)bhi * NCHK + c) * CHK) * CHK;
    const size_t rowb = (size_t)bhi * LSEQ + (size_t)c * CHK;

    __syncthreads();                  // (A) prior chunk's readers done
    STAGE_CHUNK(Kp + cb);
    STAGE_T(Tm + tb);
    __syncthreads();                  // (B)

    // upre = V - Kp*W
    {
      float a0 = 0.f, a1 = 0.f;
      const bf16* srow = &sbuf[yi * 520];
#pragma unroll 4
      for (int p = 0; p < PF; p += 8) DOT8(srow, p);
      const unsigned vv = *(const unsigned*)&vh[(rowb + yi) * DH + dq * 16 + dd];
      float v0, v1; UNP(vv, v0, v1);
      uB[yi][dd]     = v0 - a0;
      uB[yi][dd + 1] = v1 - a1;
    }
    __syncthreads();                  // (C)

    // U = T * upre (T has exact zeros above diagonal)
    float u0 = 0.f, u1 = 0.f;
#pragma unroll 8
    for (int j = 0; j < CHK; j++) {
      const float tv = b2f(tB[yi * 72 + j]);
      u0 = fmaf(tv, uB[j][dd], u0);
      u1 = fmaf(tv, uB[j][dd + 1], u1);
    }
    __syncthreads();                  // (D) readers of upre done
    uB[yi][dd] = u0; uB[yi][dd + 1] = u1;
    __syncthreads();                  // (E)

    // W += Kp^T U   (sbuf still holds Kp)
    {
      const int p = tid;
      float acc[16];
#pragma unroll
      for (int t = 0; t < 16; t++) acc[t] = 0.f;
#pragma unroll 4
      for (int j = 0; j < CHK; j++) {
        const float kv = b2f(sbuf[j * 520 + p]);
        const float4 w0 = *(const float4*)&uB[j][0];
        const float4 w1 = *(const float4*)&uB[j][4];
        const float4 w2 = *(const float4*)&uB[j][8];
        const float4 w3 = *(const float4*)&uB[j][12];
        acc[0] = fmaf(kv, w0.x, acc[0]);   acc[1] = fmaf(kv, w0.y, acc[1]);
        acc[2] = fmaf(kv, w0.z, acc[2]);   acc[3] = fmaf(kv, w0.w, acc[3]);
        acc[4] = fmaf(kv, w1.x, acc[4]);   acc[5] = fmaf(kv, w1.y, acc[5]);
        acc[6] = fmaf(kv, w1.z, acc[6]);   acc[7] = fmaf(kv, w1.w, acc[7]);
        acc[8] = fmaf(kv, w2.x, acc[8]);   acc[9] = fmaf(kv, w2.y, acc[9]);
        acc[10] = fmaf(kv, w2.z, acc[10]); acc[11] = fmaf(kv, w2.w, acc[11]);
        acc[12] = fmaf(kv, w3.x, acc[12]); acc[13] = fmaf(kv, w3.y, acc[13]);
        acc[14] = fmaf(kv, w3.z, acc[14]); acc[15] = fmaf(kv, w3.w, acc[15]);
      }
      float* wrow = sW + p * 18;
#pragma unroll
      for (int t = 0; t < 16; t++) wrow[t] += acc[t];
    }
    __syncthreads();                  // (F)
    STAGE_CHUNK(Qp + cb);
    STAGE_T(Gs + tb);
    __syncthreads();                  // (G)

    // out = 0.125 * (Qp*W_new - Gs*U)
    {
      float a0 = 0.f, a1 = 0.f;
      const bf16* srow = &sbuf[yi * 520];
#pragma unroll 4
      for (int p = 0; p < PF; p += 8) DOT8(srow, p);
#pragma unroll 8
      for (int j = 0; j < CHK; j++) {
        const float g = b2f(tB[yi * 72 + j]);
        a0 = fmaf(-g, uB[j][dd], a0);
        a1 = fmaf(-g, uB[j][dd + 1], a1);
      }
      const int l = c * CHK + yi;
      float2 o; o.x = 0.125f * a0; o.y = 0.125f * a1;
      *(float2*)&lo[((size_t)l * BSZN + bidx) * DMODEL + hd * DH + dq * 16 + dd] = o;
    }
  }
}

// ---------------------------------------------------------------------------
// K5a: ao = h + lo @ W_o (f32 tiled GEMM)
// ---------------------------------------------------------------------------
__global__ __launch_bounds__(256)
void k_outgemm(const float* __restrict__ lo, const float* __restrict__ Wo,
               const float* __restrict__ h, float* __restrict__ ao)
{
  __shared__ float sA[16][128];
  __shared__ float sB[16][68];
  const int tid = threadIdx.x;
  const int m0 = blockIdx.y * 128, n0 = blockIdx.x * 64;
  const int ty = tid >> 4, tx = tid & 15;
  float acc[8][4];
#pragma unroll
  for (int i = 0; i < 8; i++)
#pragma unroll
    for (int j = 0; j < 4; j++) acc[i][j] = 0.f;

  for (int k0 = 0; k0 < DMODEL; k0 += 16) {
    {
      const int row = tid >> 1;
      const int kq = (tid & 1) * 8;
      const float4 a0 = *(const float4*)&lo[(size_t)(m0 + row) * DMODEL + k0 + kq];
      const float4 a1 = *(const float4*)&lo[(size_t)(m0 + row) * DMODEL + k0 + kq + 4];
      sA[kq + 0][row] = a0.x; sA[kq + 1][row] = a0.y; sA[kq + 2][row] = a0.z; sA[kq + 3][row] = a0.w;
      sA[kq + 4][row] = a1.x; sA[kq + 5][row] = a1.y; sA[kq + 6][row] = a1.z; sA[kq + 7][row] = a1.w;
    }
    {
      const int krow = tid >> 4;
      const int nq = (tid & 15) * 4;
      const float4 b4 = *(const float4*)&Wo[(size_t)(k0 + krow) * DMODEL + n0 + nq];
      sB[krow][nq + 0] = b4.x; sB[krow][nq + 1] = b4.y; sB[krow][nq + 2] = b4.z; sB[krow][nq + 3] = b4.w;
    }
    __syncthreads();
#pragma unroll
    for (int kk = 0; kk < 16; kk++) {
      const float4 av0 = *(const float4*)&sA[kk][ty * 8];
      const float4 av1 = *(const float4*)&sA[kk][ty * 8 + 4];
      const float4 bv  = *(const float4*)&sB[kk][tx * 4];
      const float a[8] = {av0.x, av0.y, av0.z, av0.w, av1.x, av1.y, av1.z, av1.w};
      const float b[4] = {bv.x, bv.y, bv.z, bv.w};
#pragma unroll
      for (int i = 0; i < 8; i++)
#pragma unroll
        for (int j = 0; j < 4; j++) acc[i][j] = fmaf(a[i], b[j], acc[i][j]);
    }
    __syncthreads();
  }

#pragma unroll
  for (int i = 0; i < 8; i++) {
    const int row = m0 + ty * 8 + i;
    const float4 hv = *(const float4*)&h[(size_t)row * DMODEL + n0 + tx * 4];
    float4 o;
    o.x = acc[i][0] + hv.x; o.y = acc[i][1] + hv.y;
    o.z = acc[i][2] + hv.z; o.w = acc[i][3] + hv.w;
    *(float4*)&ao[(size_t)row * DMODEL + n0 + tx * 4] = o;
  }
}

// ---------------------------------------------------------------------------
// K5b: LayerNorm over last dim (1024), one block per row.
// ---------------------------------------------------------------------------
__global__ __launch_bounds__(256)
void k_ln(const float* __restrict__ ao, const float* __restrict__ gamma,
          const float* __restrict__ beta, float* __restrict__ out)
{
  const int row = blockIdx.x;
  const int tid = threadIdx.x;
  __shared__ float r1[4], r2[4];
  const float4 v = *(const float4*)&ao[(size_t)row * DMODEL + tid * 4];
  float s1 = v.x + v.y + v.z + v.w;
  float s2 = v.x * v.x + v.y * v.y + v.z * v.z + v.w * v.w;
  for (int off = 32; off > 0; off >>= 1) {
    s1 += __shfl_down(s1, off);
    s2 += __shfl_down(s2, off);
  }
  if ((tid & 63) == 0) { r1[tid >> 6] = s1; r2[tid >> 6] = s2; }
  __syncthreads();
  const float ts1 = r1[0] + r1[1] + r1[2] + r1[3];
  const float ts2 = r2[0] + r2[1] + r2[2] + r2[3];
  const float mu = ts1 * (1.f / DMODEL);
  const float var = ts2 * (1.f / DMODEL) - mu * mu;
  const float rs = rsqrtf(var + 1e-5f);
  const float4 g = *(const float4*)&gamma[tid * 4];
  const float4 b = *(const float4*)&beta[tid * 4];
  float4 o;
  o.x = (v.x - mu) * rs * g.x + b.x;
  o.y = (v.y - mu) * rs * g.y + b.y;
  o.z = (v.z - mu) * rs * g.z + b.z;
  o.w = (v.w - mu) * rs * g.w + b.w;
  *(float4*)&out[(size_t)row * DMODEL + tid * 4] = o;
}

// ---------------------------------------------------------------------------
extern "C" void kernel_launch(void* const* d_in, const int* in_sizes, int n_in,
                              void* d_out, int out_size, void* d_ws, size_t ws_size,
                              hipStream_t stream)
{
  (void)in_sizes; (void)n_in; (void)out_size; (void)ws_size;
  const float* h   = (const float*)d_in[0];
  const float* Wq  = (const float*)d_in[1];
  const float* Wo  = (const float*)d_in[2];
  const float* gam = (const float*)d_in[3];
  const float* bet = (const float*)d_in[4];
  const float* pm  = (const float*)d_in[5];
  float* out = (float*)d_out;

  char* ws = (char*)d_ws;
  size_t off = 0;
  auto alloc = [&](size_t bytes) -> void* {
    void* p = ws + off;
    off += (bytes + 255) & ~(size_t)255;
    return p;
  };
  // total workspace: ~176.5 MB
  bf16*  qh  = (bf16*)alloc((size_t)BHN * LSEQ * DH * 2);          //  8.4 MB
  bf16*  kh  = (bf16*)alloc((size_t)BHN * LSEQ * DH * 2);          //  8.4 MB
  bf16*  vh  = (bf16*)alloc((size_t)BHN * LSEQ * DH * 2);          //  8.4 MB
  float* bbf = (float*)alloc((size_t)BHN * LSEQ * 4);              //  0.3 MB
  bf16*  Kp  = (bf16*)alloc((size_t)BHN * LSEQ * PF * 2);          // 67.1 MB
  bf16*  Qp  = (bf16*)alloc((size_t)BHN * LSEQ * PF * 2);          // 67.1 MB
  bf16*  Tm  = (bf16*)alloc((size_t)BHN * NCHK * CHK * CHK * 2);   //  8.4 MB
  bf16*  Gs  = (bf16*)alloc((size_t)BHN * NCHK * CHK * CHK * 2);   //  8.4 MB
  float* lo  = (float*)d_out;      // d_out as scratch; fully rewritten by k_ln
  float* ao  = (float*)qh;         // qh+kh dead after k_feat; 16.8 MB reuse

  k_qkvb   <<<dim3((NQKV + 63) / 64, 4096 / 128), 256, 0, stream>>>(h, Wq, qh, kh, vh, bbf);
  k_feat   <<<dim3(LSEQ, BHN),                    256, 0, stream>>>(qh, kh, pm, Qp, Kp);
  k_sgsolve<<<dim3(NCHK, BHN),                    256, 0, stream>>>(Kp, Qp, bbf, Gs, Tm);
  k_scan   <<<dim3(4, BHN),                       512, 0, stream>>>(Kp, Qp, vh, Tm, Gs, lo);
  k_outgemm<<<dim3(DMODEL / 64, 4096 / 128),      256, 0, stream>>>(lo, Wo, h, ao);
  k_ln     <<<dim3(4096),                         256, 0, stream>>>(ao, gam, bet, out);
}

// Round 3
// 974.463 us; speedup vs baseline: 1.7263x; 1.7263x over previous
//
#include <hip/hip_runtime.h>
#include <hip/hip_bf16.h>

// Problem constants (from reference)
#define LSEQ   2048
#define BSZN   2
#define DMODEL 1024
#define NHEAD  16
#define DH     64
#define MPROJ  256
#define PF     512   // 2*MPROJ feature dim
#define CHK    64    // chunk length
#define NCHK   32    // LSEQ/CHK
#define BHN    32    // BSZN*NHEAD
#define NQKV   3088  // NHEAD*(3*DH+1)

typedef __hip_bfloat16 bf16;
typedef short bf16x8 __attribute__((ext_vector_type(8)));
typedef float f32x4 __attribute__((ext_vector_type(4)));

#define MFMA(a, b, c) __builtin_amdgcn_mfma_f32_16x16x32_bf16(a, b, c, 0, 0, 0)

// unpack a u32 holding two bf16 (little-endian: low half = first element)
#define UNP(u, a, b) { a = __uint_as_float((unsigned)(u) << 16); b = __uint_as_float((unsigned)(u) & 0xffff0000u); }

static __device__ __forceinline__ float b2f(bf16 x) {
  unsigned short us = *(unsigned short*)&x;
  return __uint_as_float((unsigned)us << 16);
}
static __device__ __forceinline__ bf16 f2b(float x) { return __float2bfloat16(x); }
static __device__ __forceinline__ unsigned pkbf(float a, float b) {
  bf16 x = __float2bfloat16(a), y = __float2bfloat16(b);
  return ((unsigned)(*(unsigned short*)&y) << 16) | (unsigned)(*(unsigned short*)&x);
}

// async global->LDS, 16B per lane. ldst must be the wave-uniform segment base.
static __device__ __forceinline__ void gl_lds16(const void* gsrc, void* ldst) {
  __builtin_amdgcn_global_load_lds(
      (const __attribute__((address_space(1))) unsigned int*)gsrc,
      (__attribute__((address_space(3))) unsigned int*)ldst, 16, 0, 0);
}

#define MEMFENCE asm volatile("" ::: "memory")
#define WAITV(n) asm volatile("s_waitcnt vmcnt(" #n ")" ::: "memory")
#define WAITLGKM asm volatile("s_waitcnt lgkmcnt(0)" ::: "memory")
#define BARRIER() __builtin_amdgcn_s_barrier()

// ---------------------------------------------------------------------------
// K1: qkvb = h @ W_qkvb -> qh/kh/vh (bf16) + sigmoid(b) (f32). (unchanged)
// ---------------------------------------------------------------------------
__global__ __launch_bounds__(256)
void k_qkvb(const float* __restrict__ h, const float* __restrict__ Wq,
            bf16* __restrict__ qh, bf16* __restrict__ kh,
            bf16* __restrict__ vh, float* __restrict__ bbuf)
{
  __shared__ float sA[16][128];
  __shared__ float sB[16][68];
  const int tid = threadIdx.x;
  const int m0 = blockIdx.y * 128, n0 = blockIdx.x * 64;
  const int ty = tid >> 4, tx = tid & 15;
  float acc[8][4];
#pragma unroll
  for (int i = 0; i < 8; i++)
#pragma unroll
    for (int j = 0; j < 4; j++) acc[i][j] = 0.f;

  for (int k0 = 0; k0 < DMODEL; k0 += 16) {
    {
      const int row = tid >> 1;
      const int kq = (tid & 1) * 8;
      const float4 a0 = *(const float4*)&h[(size_t)(m0 + row) * DMODEL + k0 + kq];
      const float4 a1 = *(const float4*)&h[(size_t)(m0 + row) * DMODEL + k0 + kq + 4];
      sA[kq + 0][row] = a0.x; sA[kq + 1][row] = a0.y; sA[kq + 2][row] = a0.z; sA[kq + 3][row] = a0.w;
      sA[kq + 4][row] = a1.x; sA[kq + 5][row] = a1.y; sA[kq + 6][row] = a1.z; sA[kq + 7][row] = a1.w;
    }
    {
      const int krow = tid >> 4;
      const int nq = (tid & 15) * 4;
      const int col = n0 + nq;
      float4 b4 = make_float4(0.f, 0.f, 0.f, 0.f);
      if (col < NQKV) b4 = *(const float4*)&Wq[(size_t)(k0 + krow) * NQKV + col];
      sB[krow][nq + 0] = b4.x; sB[krow][nq + 1] = b4.y; sB[krow][nq + 2] = b4.z; sB[krow][nq + 3] = b4.w;
    }
    __syncthreads();
#pragma unroll
    for (int kk = 0; kk < 16; kk++) {
      const float4 av0 = *(const float4*)&sA[kk][ty * 8];
      const float4 av1 = *(const float4*)&sA[kk][ty * 8 + 4];
      const float4 bv  = *(const float4*)&sB[kk][tx * 4];
      const float a[8] = {av0.x, av0.y, av0.z, av0.w, av1.x, av1.y, av1.z, av1.w};
      const float b[4] = {bv.x, bv.y, bv.z, bv.w};
#pragma unroll
      for (int i = 0; i < 8; i++)
#pragma unroll
        for (int j = 0; j < 4; j++) acc[i][j] = fmaf(a[i], b[j], acc[i][j]);
    }
    __syncthreads();
  }

#pragma unroll
  for (int i = 0; i < 8; i++) {
    const int row = m0 + ty * 8 + i;
    const int l = row >> 1, bidx = row & 1;
#pragma unroll
    for (int j = 0; j < 4; j++) {
      const int col = n0 + tx * 4 + j;
      if (col >= NQKV) continue;
      const int hd = col / 193;
      const int rem = col - hd * 193;
      const int bhi = bidx * NHEAD + hd;
      const float v = acc[i][j];
      const size_t o = ((size_t)bhi * LSEQ + l) * DH;
      if (rem < 64)        qh[o + rem] = f2b(v);
      else if (rem < 128)  kh[o + rem - 64] = f2b(v);
      else if (rem < 192)  vh[o + rem - 128] = f2b(v);
      else                 bbuf[(size_t)bhi * LSEQ + l] = 1.f / (1.f + __expf(-v));
    }
  }
}

// ---------------------------------------------------------------------------
// K2: FAVOR+ features. 16 rows per block, pm column in registers (64 VGPR),
// outputs written XOR-swizzled at 16B-unit granularity: unit' = unit ^ (l&7).
// ---------------------------------------------------------------------------
__global__ __launch_bounds__(256)
void k_feat(const bf16* __restrict__ qh, const bf16* __restrict__ kh,
            const float* __restrict__ pm,
            bf16* __restrict__ Qp, bf16* __restrict__ Kp)
{
  const int tid = threadIdx.x;
  const int l0 = blockIdx.x * 16;
  const int bhi = blockIdx.y;
  const int lane = tid & 63, w = tid >> 6;
  __shared__ float xs[2][16][68];
  __shared__ float hns[2][16];
  __shared__ float psum[4][2][16];
  float pmr[64];
#pragma unroll
  for (int d = 0; d < 64; d++) pmr[d] = pm[d * MPROJ + tid];

  for (int t = tid; t < 2048; t += 256) {
    const int wh = t >> 10, r = (t >> 6) & 15, d = t & 63;
    const bf16* src = wh ? kh : qh;
    xs[wh][r][d] = b2f(src[((size_t)bhi * LSEQ + l0 + r) * DH + d]) * 0.35355339059327373f;
  }
  __syncthreads();
  if (tid < 32) {
    const int wh = tid >> 4, r = tid & 15;
    float hn = 0.f;
#pragma unroll
    for (int d = 0; d < 64; d++) hn = fmaf(xs[wh][r][d], xs[wh][r][d], hn);
    hns[wh][r] = 0.5f * hn;
  }
  __syncthreads();

  for (int wh = 0; wh < 2; wh++) {
    bf16* dst = wh ? Kp : Qp;
    float ep[16], en[16];
#pragma unroll
    for (int r = 0; r < 16; r++) {
      float pr = 0.f;
#pragma unroll
      for (int d0 = 0; d0 < 64; d0 += 4) {
        const float4 xv = *(const float4*)&xs[wh][r][d0];
        pr = fmaf(xv.x, pmr[d0], pr);     pr = fmaf(xv.y, pmr[d0 + 1], pr);
        pr = fmaf(xv.z, pmr[d0 + 2], pr); pr = fmaf(xv.w, pmr[d0 + 3], pr);
      }
      const float hn = hns[wh][r];
      ep[r] = __expf(pr - hn) + 1e-4f;
      en[r] = __expf(-pr - hn) + 1e-4f;
      float s = ep[r] + en[r];
#pragma unroll
      for (int off = 32; off > 0; off >>= 1) s += __shfl_down(s, off);
      if (lane == 0) psum[w][wh][r] = s;
    }
    __syncthreads();
#pragma unroll
    for (int r = 0; r < 16; r++) {
      const float tot = psum[0][wh][r] + psum[1][wh][r] + psum[2][wh][r] + psum[3][wh][r];
      const float inv = 1.f / tot;
      const size_t base = ((size_t)bhi * LSEQ + l0 + r) * PF;
      const int ue = ((tid >> 3) ^ (r & 7));
      const int un = (32 + ((tid >> 3) ^ (r & 7)));
      dst[base + (ue << 3) + (tid & 7)] = f2b(ep[r] * inv);
      dst[base + (un << 3) + (tid & 7)] = f2b(en[r] * inv);
    }
    __syncthreads();
  }
}

// ---------------------------------------------------------------------------
// K3: per (chunk, bh): S = Kp Kp^T, Gs = -triu_strict(Qp Kp^T) (bf16, swz),
// T = (I + tril_strict(diag(b)S))^{-1} diag(b) (bf16, swz), KpT (bf16, swz).
// Kp/Qp globals are 16B-unit swizzled (unit ^ row&7) -> adjusted reads.
// ---------------------------------------------------------------------------
__global__ __launch_bounds__(256)
void k_sgsolve(const bf16* __restrict__ Kp, const bf16* __restrict__ Qp,
               const float* __restrict__ bbuf,
               bf16* __restrict__ Gs, bf16* __restrict__ Tm,
               bf16* __restrict__ KpT)
{
  __shared__ float sK[CHK][65];   // staging; reused as S after the GEMM loop
  __shared__ float sQ[CHK][65];   // staging; reused as T
  __shared__ float sBeta[CHK];
  const int tid = threadIdx.x;
  const int c = blockIdx.x, bhi = blockIdx.y;
  const int ty = tid >> 4, tx = tid & 15;
  const size_t cb = ((size_t)bhi * LSEQ + (size_t)c * CHK) * PF;
  const size_t rowb = (size_t)bhi * LSEQ + (size_t)c * CHK;
  const size_t ktb = (((size_t)bhi * NCHK + c) * 512) * 64;

  float accS[4][4], accG[4][4];
#pragma unroll
  for (int i = 0; i < 4; i++)
#pragma unroll
    for (int j = 0; j < 4; j++) { accS[i][j] = 0.f; accG[i][j] = 0.f; }

  for (int p0 = 0; p0 < PF; p0 += 64) {
    {
      const int row = tid >> 2;
      const int pc = (tid & 3) * 16;
      const int u = (p0 + pc) >> 3;  // even unit index
      const int su0 = (u ^ (row & 7)), su1 = ((u + 1) ^ (row & 7));
      const uint4 k0 = *(const uint4*)(Kp + cb + (size_t)row * PF + (su0 << 3));
      const uint4 k1 = *(const uint4*)(Kp + cb + (size_t)row * PF + (su1 << 3));
      const uint4 q0 = *(const uint4*)(Qp + cb + (size_t)row * PF + (su0 << 3));
      const uint4 q1 = *(const uint4*)(Qp + cb + (size_t)row * PF + (su1 << 3));
      float f[16];
      UNP(k0.x, f[0], f[1]); UNP(k0.y, f[2], f[3]); UNP(k0.z, f[4], f[5]); UNP(k0.w, f[6], f[7]);
      UNP(k1.x, f[8], f[9]); UNP(k1.y, f[10], f[11]); UNP(k1.z, f[12], f[13]); UNP(k1.w, f[14], f[15]);
#pragma unroll
      for (int t = 0; t < 16; t++) sK[row][pc + t] = f[t];
      UNP(q0.x, f[0], f[1]); UNP(q0.y, f[2], f[3]); UNP(q0.z, f[4], f[5]); UNP(q0.w, f[6], f[7]);
      UNP(q1.x, f[8], f[9]); UNP(q1.y, f[10], f[11]); UNP(q1.z, f[12], f[13]); UNP(q1.w, f[14], f[15]);
#pragma unroll
      for (int t = 0; t < 16; t++) sQ[row][pc + t] = f[t];
    }
    __syncthreads();
#pragma unroll 8
    for (int kk = 0; kk < 64; kk++) {
      float bj[4], ai[4], aq[4];
#pragma unroll
      for (int j = 0; j < 4; j++) bj[j] = sK[tx * 4 + j][kk];
#pragma unroll
      for (int i = 0; i < 4; i++) { ai[i] = sK[ty * 4 + i][kk]; aq[i] = sQ[ty * 4 + i][kk]; }
#pragma unroll
      for (int i = 0; i < 4; i++)
#pragma unroll
        for (int j = 0; j < 4; j++) {
          accS[i][j] = fmaf(ai[i], bj[j], accS[i][j]);
          accG[i][j] = fmaf(aq[i], bj[j], accG[i][j]);
        }
    }
    // emit KpT slice [p0..p0+63][64 l], bf16, unit-swizzled (unit = l>>3 ^ p&7)
    for (int t = tid; t < 512; t += 256) {
      const int pl = t >> 3, l8 = t & 7;
      const int p = p0 + pl;
      unsigned rr[4];
#pragma unroll
      for (int jj = 0; jj < 4; jj++)
        rr[jj] = pkbf(sK[l8 * 8 + jj * 2][pl], sK[l8 * 8 + jj * 2 + 1][pl]);
      *(uint4*)&KpT[ktb + (size_t)p * 64 + ((l8 ^ (p & 7)) << 3)] =
          make_uint4(rr[0], rr[1], rr[2], rr[3]);
    }
    __syncthreads();
  }

  const size_t sb = (((size_t)bhi * NCHK + c) * CHK) * CHK;
#pragma unroll
  for (int i = 0; i < 4; i++) {
    const int ri = ty * 4 + i;
#pragma unroll
    for (int j = 0; j < 4; j++) {
      const int cj = tx * 4 + j;
      // Gs: strict upper, NEGATED, swizzled
      Gs[sb + ri * 64 + (((cj >> 3) ^ (ri & 7)) << 3) + (cj & 7)] =
          f2b((cj > ri) ? -accG[i][j] : 0.f);
      sK[ri][cj] = accS[i][j];          // stash full S
    }
  }
  if (tid < CHK) sBeta[tid] = bbuf[rowb + tid];
  __syncthreads();

  if (tid < CHK) {
    const int j = tid;
    for (int i = 0; i < CHK; i++) {
      float acc = (i == j) ? 1.f : 0.f;
      for (int k = 0; k < i; k++) acc = fmaf(-sK[i][k], sQ[k][j], acc);
      sQ[i][j] = sBeta[i] * acc;
    }
  }
  __syncthreads();
  for (int t = tid; t < CHK * CHK; t += 256) {
    const int r = t >> 6, ccj = t & 63;
    Tm[sb + r * 64 + (((ccj >> 3) ^ (r & 7)) << 3) + (ccj & 7)] = f2b(sQ[r][ccj]);
  }
}

// ---------------------------------------------------------------------------
// K4: MFMA chunk scan. 128 blocks = (bh:32) x (d-slice:4), 256 threads/4 waves.
// blockIdx.x = bh + 32*dq so the 4 d-siblings of one bh share an XCD L2.
// W state: 8 mfma C tiles (f32) per lane; bf16 shadow WT[16][512] in LDS (xor).
// Per chunk: upre=V-Kp*W | U=T*upre | W+=KpT*U | out=0.125*(Qp*W_new - Gs*U).
// Staging: global_load_lds w16, counted vmcnt, raw barriers. Stage ownership
// per wave == fragment-read ownership, so gl_lds completion is wave-local.
// ---------------------------------------------------------------------------
__global__ __launch_bounds__(256, 1)
void k_scan(const bf16* __restrict__ Kp, const bf16* __restrict__ Qp,
            const bf16* __restrict__ vh, const bf16* __restrict__ Tm,
            const bf16* __restrict__ Gs, const bf16* __restrict__ KpT,
            float* __restrict__ lo)
{
  __shared__ __align__(16) char sb[2][65536];   // dbuf: Kp / KpT / Qp
  __shared__ __align__(16) char sWT[16384];     // WT[d=16][p=512] bf16, xor-swz
  __shared__ __align__(16) char sTG[8192];      // T then Gs (producer-swz)
  __shared__ __align__(16) char sUT[2048];      // U^T[d=16][l=64] bf16, xor-swz
  __shared__ __align__(16) char suP[2048];      // upre^T, same layout

  const int tid = threadIdx.x;
  const int w = tid >> 6, lane = tid & 63;
  const int l16 = lane & 15, lg = lane >> 4;
  const int bhi = blockIdx.x & 31, dq = blockIdx.x >> 5;
  const int bidx = bhi >> 4, hd = bhi & 15;
  const int xs = l16 & 7;                       // xor key (row&7 == col&7 here)

  for (int i = tid; i < 4096; i += 256) ((unsigned*)sWT)[i] = 0u;

  f32x4 Wacc[8];
#pragma unroll
  for (int i = 0; i < 8; i++) Wacc[i] = (f32x4){0.f, 0.f, 0.f, 0.f};

  const size_t bh_base = (size_t)bhi * LSEQ * PF;
  const size_t tg0 = ((size_t)bhi * NCHK) * 4096;
  const size_t kt0 = ((size_t)bhi * NCHK) * (512 * 64);

  // prologue: stage Kp(0) into sb[0]
  {
    const char* g = (const char*)(Kp + bh_base);
#pragma unroll
    for (int j = 0; j < 16; j++)
      gl_lds16(g + (w * 16 + j) * 1024 + lane * 16, &sb[0][(w * 16 + j) * 1024]);
  }
  MEMFENCE;
  WAITLGKM; BARRIER();   // sWT zeros visible

  int cur = 0;
  for (int c = 0; c < NCHK; c++) {
    BARRIER();  // B0: prev-iter readers of sb/sTG/sUT done

    const size_t cb = bh_base + (size_t)c * CHK * PF;
    const char* TmC  = (const char*)(Tm + tg0 + (size_t)c * 4096);
    const char* GsC  = (const char*)(Gs + tg0 + (size_t)c * 4096);
    const char* KpTC = (const char*)(KpT + kt0 + (size_t)c * (512 * 64));
    const char* QpC  = (const char*)(Qp + cb);
    const char* KpN  = (const char*)(Kp + cb + CHK * PF);

    // V (compiler-managed waits)
    const bf16* vp = vh + ((size_t)bhi * LSEQ + c * 64 + w * 16 + lg * 4) * 64 + dq * 16 + l16;
    const float v0 = b2f(vp[0]),   v1 = b2f(vp[64]);
    const float v2 = b2f(vp[128]), v3 = b2f(vp[192]);
    MEMFENCE;
    // stage T(c) -> sTG
#pragma unroll
    for (int j = 0; j < 2; j++)
      gl_lds16(TmC + (w * 2 + j) * 1024 + lane * 16, &sTG[(w * 2 + j) * 1024]);
    MEMFENCE;
    // stage KpT(c) -> sb[cur^1]
#pragma unroll
    for (int j = 0; j < 16; j++)
      gl_lds16(KpTC + (w * 16 + j) * 1024 + lane * 16, &sb[cur ^ 1][(w * 16 + j) * 1024]);
    MEMFENCE;
    WAITV(22);  // Kp(c) ready (younger: stores4? + T2 + KpT16)

    // ---- upre = V - Kp*W(old) ----
    f32x4 a0v = (f32x4){0.f,0.f,0.f,0.f}, a1v = (f32x4){0.f,0.f,0.f,0.f};
#pragma unroll
    for (int ks = 0; ks < 16; ks += 2) {
      const bf16x8 aa0 = *(const bf16x8*)&sb[cur][(16 * w + l16) * 1024 + ((((ks    ) * 4 + lg) ^ xs) << 4)];
      const bf16x8 bb0 = *(const bf16x8*)&sWT[l16 * 1024 + ((((ks    ) * 4 + lg) ^ xs) << 4)];
      a0v = MFMA(aa0, bb0, a0v);
      const bf16x8 aa1 = *(const bf16x8*)&sb[cur][(16 * w + l16) * 1024 + ((((ks + 1) * 4 + lg) ^ xs) << 4)];
      const bf16x8 bb1 = *(const bf16x8*)&sWT[l16 * 1024 + ((((ks + 1) * 4 + lg) ^ xs) << 4)];
      a1v = MFMA(aa1, bb1, a1v);
    }
    {
      const int l0r = 16 * w + lg * 4;
      const unsigned plo = pkbf(v0 - (a0v[0] + a1v[0]), v1 - (a0v[1] + a1v[1]));
      const unsigned phi = pkbf(v2 - (a0v[2] + a1v[2]), v3 - (a0v[3] + a1v[3]));
      *(uint2*)&suP[l16 * 128 + ((((l0r >> 3)) ^ xs) << 4) + (l0r & 7) * 2] = make_uint2(plo, phi);
    }
    WAITLGKM; BARRIER();  // B1: suP ready
    WAITV(16);            // T ready (younger: KpT16)

    // ---- U = T * upre ----
    {
      f32x4 ua = (f32x4){0.f,0.f,0.f,0.f};
#pragma unroll
      for (int ks = 0; ks < 2; ks++) {
        const bf16x8 aa = *(const bf16x8*)&sTG[(16 * w + l16) * 128 + (((ks * 4 + lg) ^ xs) << 4)];
        const bf16x8 bb = *(const bf16x8*)&suP[l16 * 128 + (((ks * 4 + lg) ^ xs) << 4)];
        ua = MFMA(aa, bb, ua);
      }
      const int l0r = 16 * w + lg * 4;
      *(uint2*)&sUT[l16 * 128 + ((((l0r >> 3)) ^ xs) << 4) + (l0r & 7) * 2] =
          make_uint2(pkbf(ua[0], ua[1]), pkbf(ua[2], ua[3]));
    }
    WAITLGKM; BARRIER();  // B2: sUT ready

    // stage Qp(c) -> sb[cur] (Kp fully consumed by all waves: B1+B2 passed)
#pragma unroll
    for (int j = 0; j < 16; j++)
      gl_lds16(QpC + (w * 16 + j) * 1024 + lane * 16, &sb[cur][(w * 16 + j) * 1024]);
    MEMFENCE;
    WAITV(16);            // KpT ready (younger: Qp16)

    // ---- W += KpT * U ----
    {
      bf16x8 bu[2];
#pragma unroll
      for (int ks = 0; ks < 2; ks++)
        bu[ks] = *(const bf16x8*)&sUT[l16 * 128 + (((ks * 4 + lg) ^ xs) << 4)];
#pragma unroll
      for (int mt = 0; mt < 8; mt++) {
        const int p = w * 128 + mt * 16 + l16;
#pragma unroll
        for (int ks = 0; ks < 2; ks++) {
          const bf16x8 aa = *(const bf16x8*)&sb[cur ^ 1][p * 128 + (((ks * 4 + lg) ^ xs) << 4)];
          Wacc[mt] = MFMA(aa, bu[ks], Wacc[mt]);
        }
      }
      // shadow WT = bf16(W_new)
#pragma unroll
      for (int mt = 0; mt < 8; mt++) {
        const int p0m = w * 128 + mt * 16 + lg * 4;
        *(uint2*)&sWT[l16 * 1024 + ((((p0m >> 3)) ^ xs) << 4) + (p0m & 7) * 2] =
            make_uint2(pkbf(Wacc[mt][0], Wacc[mt][1]), pkbf(Wacc[mt][2], Wacc[mt][3]));
      }
    }
    WAITLGKM; BARRIER();  // B3: sWT(new) ready

    // stage Gs(c) -> sTG ; prefetch Kp(c+1) -> sb[cur^1]
#pragma unroll
    for (int j = 0; j < 2; j++)
      gl_lds16(GsC + (w * 2 + j) * 1024 + lane * 16, &sTG[(w * 2 + j) * 1024]);
    MEMFENCE;
    if (c < NCHK - 1) {
#pragma unroll
      for (int j = 0; j < 16; j++)
        gl_lds16(KpN + (w * 16 + j) * 1024 + lane * 16, &sb[cur ^ 1][(w * 16 + j) * 1024]);
    }
    MEMFENCE;
    if (c < NCHK - 1) { WAITV(18); } else { WAITV(2); }   // Qp ready

    // ---- out = 0.125 * (Qp*W_new - Gs*U) ----
    f32x4 o0 = (f32x4){0.f,0.f,0.f,0.f}, o1 = (f32x4){0.f,0.f,0.f,0.f};
#pragma unroll
    for (int ks = 0; ks < 16; ks += 2) {
      const bf16x8 aa0 = *(const bf16x8*)&sb[cur][(16 * w + l16) * 1024 + ((((ks    ) * 4 + lg) ^ xs) << 4)];
      const bf16x8 bb0 = *(const bf16x8*)&sWT[l16 * 1024 + ((((ks    ) * 4 + lg) ^ xs) << 4)];
      o0 = MFMA(aa0, bb0, o0);
      const bf16x8 aa1 = *(const bf16x8*)&sb[cur][(16 * w + l16) * 1024 + ((((ks + 1) * 4 + lg) ^ xs) << 4)];
      const bf16x8 bb1 = *(const bf16x8*)&sWT[l16 * 1024 + ((((ks + 1) * 4 + lg) ^ xs) << 4)];
      o1 = MFMA(aa1, bb1, o1);
    }
    if (c < NCHK - 1) { WAITV(16); } else { WAITV(0); }   // Gs ready
#pragma unroll
    for (int ks = 0; ks < 2; ks++) {
      const bf16x8 aa = *(const bf16x8*)&sTG[(16 * w + l16) * 128 + (((ks * 4 + lg) ^ xs) << 4)];
      const bf16x8 bb = *(const bf16x8*)&sUT[l16 * 128 + (((ks * 4 + lg) ^ xs) << 4)];
      o0 = MFMA(aa, bb, o0);   // Gs pre-negated by producer
    }
    {
      float* op = lo + ((size_t)(c * 64 + 16 * w + lg * 4) * BSZN + bidx) * DMODEL
                     + hd * 64 + dq * 16 + l16;
      op[0]                = 0.125f * (o0[0] + o1[0]);
      op[BSZN * DMODEL]    = 0.125f * (o0[1] + o1[1]);
      op[2 * BSZN * DMODEL] = 0.125f * (o0[2] + o1[2]);
      op[3 * BSZN * DMODEL] = 0.125f * (o0[3] + o1[3]);
    }
    cur ^= 1;
  }
}

// ---------------------------------------------------------------------------
// K5a: ao = h + lo @ W_o (f32 tiled GEMM, unchanged)
// ---------------------------------------------------------------------------
__global__ __launch_bounds__(256)
void k_outgemm(const float* __restrict__ lo, const float* __restrict__ Wo,
               const float* __restrict__ h, float* __restrict__ ao)
{
  __shared__ float sA[16][128];
  __shared__ float sB[16][68];
  const int tid = threadIdx.x;
  const int m0 = blockIdx.y * 128, n0 = blockIdx.x * 64;
  const int ty = tid >> 4, tx = tid & 15;
  float acc[8][4];
#pragma unroll
  for (int i = 0; i < 8; i++)
#pragma unroll
    for (int j = 0; j < 4; j++) acc[i][j] = 0.f;

  for (int k0 = 0; k0 < DMODEL; k0 += 16) {
    {
      const int row = tid >> 1;
      const int kq = (tid & 1) * 8;
      const float4 a0 = *(const float4*)&lo[(size_t)(m0 + row) * DMODEL + k0 + kq];
      const float4 a1 = *(const float4*)&lo[(size_t)(m0 + row) * DMODEL + k0 + kq + 4];
      sA[kq + 0][row] = a0.x; sA[kq + 1][row] = a0.y; sA[kq + 2][row] = a0.z; sA[kq + 3][row] = a0.w;
      sA[kq + 4][row] = a1.x; sA[kq + 5][row] = a1.y; sA[kq + 6][row] = a1.z; sA[kq + 7][row] = a1.w;
    }
    {
      const int krow = tid >> 4;
      const int nq = (tid & 15) * 4;
      const float4 b4 = *(const float4*)&Wo[(size_t)(k0 + krow) * DMODEL + n0 + nq];
      sB[krow][nq + 0] = b4.x; sB[krow][nq + 1] = b4.y; sB[krow][nq + 2] = b4.z; sB[krow][nq + 3] = b4.w;
    }
    __syncthreads();
#pragma unroll
    for (int kk = 0; kk < 16; kk++) {
      const float4 av0 = *(const float4*)&sA[kk][ty * 8];
      const float4 av1 = *(const float4*)&sA[kk][ty * 8 + 4];
      const float4 bv  = *(const float4*)&sB[kk][tx * 4];
      const float a[8] = {av0.x, av0.y, av0.z, av0.w, av1.x, av1.y, av1.z, av1.w};
      const float b[4] = {bv.x, bv.y, bv.z, bv.w};
#pragma unroll
      for (int i = 0; i < 8; i++)
#pragma unroll
        for (int j = 0; j < 4; j++) acc[i][j] = fmaf(a[i], b[j], acc[i][j]);
    }
    __syncthreads();
  }

#pragma unroll
  for (int i = 0; i < 8; i++) {
    const int row = m0 + ty * 8 + i;
    const float4 hv = *(const float4*)&h[(size_t)row * DMODEL + n0 + tx * 4];
    float4 o;
    o.x = acc[i][0] + hv.x; o.y = acc[i][1] + hv.y;
    o.z = acc[i][2] + hv.z; o.w = acc[i][3] + hv.w;
    *(float4*)&ao[(size_t)row * DMODEL + n0 + tx * 4] = o;
  }
}

// ---------------------------------------------------------------------------
// K5b: LayerNorm (unchanged)
// ---------------------------------------------------------------------------
__global__ __launch_bounds__(256)
void k_ln(const float* __restrict__ ao, const float* __restrict__ gamma,
          const float* __restrict__ beta, float* __restrict__ out)
{
  const int row = blockIdx.x;
  const int tid = threadIdx.x;
  __shared__ float r1[4], r2[4];
  const float4 v = *(const float4*)&ao[(size_t)row * DMODEL + tid * 4];
  float s1 = v.x + v.y + v.z + v.w;
  float s2 = v.x * v.x + v.y * v.y + v.z * v.z + v.w * v.w;
  for (int off = 32; off > 0; off >>= 1) {
    s1 += __shfl_down(s1, off);
    s2 += __shfl_down(s2, off);
  }
  if ((tid & 63) == 0) { r1[tid >> 6] = s1; r2[tid >> 6] = s2; }
  __syncthreads();
  const float ts1 = r1[0] + r1[1] + r1[2] + r1[3];
  const float ts2 = r2[0] + r2[1] + r2[2] + r2[3];
  const float mu = ts1 * (1.f / DMODEL);
  const float var = ts2 * (1.f / DMODEL) - mu * mu;
  const float rs = rsqrtf(var + 1e-5f);
  const float4 g = *(const float4*)&gamma[tid * 4];
  const float4 b = *(const float4*)&beta[tid * 4];
  float4 o;
  o.x = (v.x - mu) * rs * g.x + b.x;
  o.y = (v.y - mu) * rs * g.y + b.y;
  o.z = (v.z - mu) * rs * g.z + b.z;
  o.w = (v.w - mu) * rs * g.w + b.w;
  *(float4*)&out[(size_t)row * DMODEL + tid * 4] = o;
}

// ---------------------------------------------------------------------------
extern "C" void kernel_launch(void* const* d_in, const int* in_sizes, int n_in,
                              void* d_out, int out_size, void* d_ws, size_t ws_size,
                              hipStream_t stream)
{
  (void)in_sizes; (void)n_in; (void)out_size; (void)ws_size;
  const float* h   = (const float*)d_in[0];
  const float* Wq  = (const float*)d_in[1];
  const float* Wo  = (const float*)d_in[2];
  const float* gam = (const float*)d_in[3];
  const float* bet = (const float*)d_in[4];
  const float* pm  = (const float*)d_in[5];
  float* out = (float*)d_out;

  char* ws = (char*)d_ws;
  size_t off = 0;
  auto alloc = [&](size_t bytes) -> void* {
    void* p = ws + off;
    off += (bytes + 255) & ~(size_t)255;
    return p;
  };
  // total workspace ~= 227 MB
  bf16*  vh  = (bf16*)alloc((size_t)BHN * LSEQ * DH * 2);            //  8.4 MB
  float* bbf = (float*)alloc((size_t)BHN * LSEQ * 4);                //  0.3 MB
  bf16*  Kp  = (bf16*)alloc((size_t)BHN * LSEQ * PF * 2);            // 67.1 MB
  bf16*  Qp  = (bf16*)alloc((size_t)BHN * LSEQ * PF * 2);            // 67.1 MB
  bf16*  Tm  = (bf16*)alloc((size_t)BHN * NCHK * CHK * CHK * 2);     //  8.4 MB
  bf16*  Gs  = (bf16*)alloc((size_t)BHN * NCHK * CHK * CHK * 2);     //  8.4 MB
  char*  R   = (char*)alloc((size_t)BHN * NCHK * 512 * 64 * 2);      // 67.1 MB shared region
  // region R lifetimes: [qh|kh] (qkvb->feat) -> KpT (sgsolve->scan) -> ao (outgemm->ln)
  bf16*  qh  = (bf16*)R;
  bf16*  kh  = (bf16*)(R + (size_t)BHN * LSEQ * DH * 2);
  bf16*  KpT = (bf16*)R;
  float* ao  = (float*)R;
  float* lo  = (float*)d_out;   // d_out as scratch; fully rewritten by k_ln

  k_qkvb   <<<dim3((NQKV + 63) / 64, 4096 / 128), 256, 0, stream>>>(h, Wq, qh, kh, vh, bbf);
  k_feat   <<<dim3(LSEQ / 16, BHN),               256, 0, stream>>>(qh, kh, pm, Qp, Kp);
  k_sgsolve<<<dim3(NCHK, BHN),                    256, 0, stream>>>(Kp, Qp, bbf, Gs, Tm, KpT);
  k_scan   <<<dim3(128),                          256, 0, stream>>>(Kp, Qp, vh, Tm, Gs, KpT, lo);
  k_outgemm<<<dim3(DMODEL / 64, 4096 / 128),      256, 0, stream>>>(lo, Wo, h, ao);
  k_ln     <<<dim3(4096),                         256, 0, stream>>>(ao, gam, bet, out);
}

// Round 4
// 581.864 us; speedup vs baseline: 2.8910x; 1.6747x over previous
//
#include <hip/hip_runtime.h>
#include <hip/hip_bf16.h>

// Problem constants (from reference)
#define LSEQ   2048
#define BSZN   2
#define DMODEL 1024
#define NHEAD  16
#define DH     64
#define MPROJ  256
#define PF     512   // 2*MPROJ feature dim
#define CHK    64    // chunk length
#define NCHK   32    // LSEQ/CHK
#define BHN    32    // BSZN*NHEAD
#define NQKV   3088  // NHEAD*(3*DH+1)
#define NQPAD  3200  // NQKV padded to 25*128

typedef __hip_bfloat16 bf16;
typedef short bf16x8 __attribute__((ext_vector_type(8)));
typedef float f32x4 __attribute__((ext_vector_type(4)));

#define MFMA(a, b, c) __builtin_amdgcn_mfma_f32_16x16x32_bf16(a, b, c, 0, 0, 0)

// unpack a u32 holding two bf16 (little-endian: low half = first element)
#define UNP(u, a, b) { a = __uint_as_float((unsigned)(u) << 16); b = __uint_as_float((unsigned)(u) & 0xffff0000u); }

static __device__ __forceinline__ float b2f(bf16 x) {
  unsigned short us = *(unsigned short*)&x;
  return __uint_as_float((unsigned)us << 16);
}
static __device__ __forceinline__ bf16 f2b(float x) { return __float2bfloat16(x); }
static __device__ __forceinline__ unsigned pkbf(float a, float b) {
  bf16 x = __float2bfloat16(a), y = __float2bfloat16(b);
  return ((unsigned)(*(unsigned short*)&y) << 16) | (unsigned)(*(unsigned short*)&x);
}

// async global->LDS, 16B per lane. gsrc is PER-LANE; ldst wave-uniform base.
static __device__ __forceinline__ void gl_lds16(const void* gsrc, void* ldst) {
  __builtin_amdgcn_global_load_lds(
      (const __attribute__((address_space(1))) unsigned int*)gsrc,
      (__attribute__((address_space(3))) unsigned int*)ldst, 16, 0, 0);
}

#define MEMFENCE asm volatile("" ::: "memory")
#define WAITV(n) asm volatile("s_waitcnt vmcnt(" #n ")" ::: "memory")
#define WAITLGKM asm volatile("s_waitcnt lgkmcnt(0)" ::: "memory")
#define BARRIER() __builtin_amdgcn_s_barrier()

// ---------------------------------------------------------------------------
// K0a: h (f32) -> hbf (bf16), pre-swizzled: within each 64-elem group, 16B
// unit u stored at u ^ (row&7).
// ---------------------------------------------------------------------------
__global__ __launch_bounds__(256)
void k_cvth(const float* __restrict__ h, bf16* __restrict__ hbf)
{
  const int gt = blockIdx.x * 256 + threadIdx.x;   // unit id, 4096*128 total
  const int r = gt >> 7, ug = gt & 127;
  const int grp = ug >> 3, u = ug & 7;
  const float4 f0 = *(const float4*)&h[(size_t)r * 1024 + grp * 64 + u * 8];
  const float4 f1 = *(const float4*)&h[(size_t)r * 1024 + grp * 64 + u * 8 + 4];
  uint4 o;
  o.x = pkbf(f0.x, f0.y); o.y = pkbf(f0.z, f0.w);
  o.z = pkbf(f1.x, f1.y); o.w = pkbf(f1.z, f1.w);
  *(uint4*)&hbf[(size_t)r * 1024 + grp * 64 + ((u ^ (r & 7)) << 3)] = o;
}

// ---------------------------------------------------------------------------
// K0b: W [1024][nsrc] f32 -> WT [gridDim.x*64][1024] bf16 transposed,
// pre-swizzled, zero-padded rows beyond nsrc.
// ---------------------------------------------------------------------------
__global__ __launch_bounds__(256)
void k_cvtw(const float* __restrict__ W, bf16* __restrict__ WT, int nsrc)
{
  __shared__ float sT[64][65];
  const int tid = threadIdx.x;
  const int n0 = blockIdx.x * 64, k0 = blockIdx.y * 64;
#pragma unroll
  for (int j = 0; j < 16; j++) {
    const int e = j * 256 + tid;
    const int r = e >> 6, c = e & 63;
    sT[r][c] = (n0 + c < nsrc) ? W[(size_t)(k0 + r) * nsrc + n0 + c] : 0.f;
  }
  __syncthreads();
#pragma unroll
  for (int j = 0; j < 2; j++) {
    const int uid = j * 256 + tid;
    const int rp = uid >> 3, u = uid & 7;
    uint4 o;
    o.x = pkbf(sT[u * 8 + 0][rp], sT[u * 8 + 1][rp]);
    o.y = pkbf(sT[u * 8 + 2][rp], sT[u * 8 + 3][rp]);
    o.z = pkbf(sT[u * 8 + 4][rp], sT[u * 8 + 5][rp]);
    o.w = pkbf(sT[u * 8 + 6][rp], sT[u * 8 + 7][rp]);
    *(uint4*)&WT[(size_t)(n0 + rp) * 1024 + k0 + ((u ^ (rp & 7)) << 3)] = o;
  }
}

// ---------------------------------------------------------------------------
// MFMA GEMM core: C[128m x 128n] tile, BK=64, 4 waves (2x2), double-buffered
// global_load_lds staging, xor-swizzled LDS reads (sources pre-swizzled).
// ---------------------------------------------------------------------------
#define GEMM_STAGE(Abase, Bbase, kt, b) {                                      \
  const size_t kb = (size_t)(kt) * 128;   /* byte offset of k-window */        \
  _Pragma("unroll")                                                            \
  for (int j = 0; j < 4; j++) {                                                \
    const int row = (w * 4 + j) * 8 + (lane >> 3);                             \
    gl_lds16((const char*)(Abase) + (size_t)(m0 + row) * 2048 + kb + (lane & 7) * 16, \
             &sA[b][(w * 4 + j) * 1024]);                                      \
  }                                                                            \
  _Pragma("unroll")                                                            \
  for (int j = 0; j < 4; j++) {                                                \
    const int row = (w * 4 + j) * 8 + (lane >> 3);                             \
    gl_lds16((const char*)(Bbase) + (size_t)(n0 + row) * 2048 + kb + (lane & 7) * 16, \
             &sB[b][(w * 4 + j) * 1024]);                                      \
  } }

#define GEMM_COMPUTE(b) {                                                      \
  _Pragma("unroll")                                                            \
  for (int ks = 0; ks < 2; ks++) {                                             \
    bf16x8 af[4], bfr[4];                                                      \
    _Pragma("unroll")                                                          \
    for (int f = 0; f < 4; f++) {                                              \
      const int row = wm * 64 + f * 16 + l16;                                  \
      af[f] = *(const bf16x8*)&sA[b][row * 128 + (((ks * 4 + lg) ^ xs) << 4)]; \
    }                                                                          \
    _Pragma("unroll")                                                          \
    for (int f = 0; f < 4; f++) {                                              \
      const int row = wn * 64 + f * 16 + l16;                                  \
      bfr[f] = *(const bf16x8*)&sB[b][row * 128 + (((ks * 4 + lg) ^ xs) << 4)]; \
    }                                                                          \
    _Pragma("unroll")                                                          \
    for (int fm = 0; fm < 4; fm++)                                             \
      _Pragma("unroll")                                                        \
      for (int fn = 0; fn < 4; fn++)                                           \
        acc[fm][fn] = MFMA(af[fm], bfr[fn], acc[fm][fn]);                      \
  } }

#define GEMM_PREAMBLE                                                          \
  __shared__ __align__(16) char sA[2][16384];                                  \
  __shared__ __align__(16) char sB[2][16384];                                  \
  const int tid = threadIdx.x, w = tid >> 6, lane = tid & 63;                  \
  const int l16 = lane & 15, lg = lane >> 4;                                   \
  const int wm = w >> 1, wn = w & 1;                                           \
  const int m0 = blockIdx.y * 128, n0 = blockIdx.x * 128;                      \
  const int xs = l16 & 7;                                                      \
  f32x4 acc[4][4];                                                             \
  _Pragma("unroll")                                                            \
  for (int i = 0; i < 4; i++)                                                  \
    _Pragma("unroll")                                                          \
    for (int j = 0; j < 4; j++) acc[i][j] = (f32x4){0.f, 0.f, 0.f, 0.f};

// K1: qkvb = hbf @ WqT^T, epilogue scatters to qh/kh/vh (bf16) + sigmoid b.
__global__ __launch_bounds__(256, 2)
void k_gemm_qkvb(const bf16* __restrict__ A, const bf16* __restrict__ B,
                 bf16* __restrict__ qh, bf16* __restrict__ kh,
                 bf16* __restrict__ vh, float* __restrict__ bbuf)
{
  GEMM_PREAMBLE
  GEMM_STAGE(A, B, 0, 0);
  __syncthreads();
  for (int kt = 0; kt < 16; kt++) {
    const int b = kt & 1;
    if (kt < 15) GEMM_STAGE(A, B, kt + 1, b ^ 1);
    GEMM_COMPUTE(b);
    __syncthreads();
  }
#pragma unroll
  for (int fm = 0; fm < 4; fm++)
#pragma unroll
    for (int fn = 0; fn < 4; fn++)
#pragma unroll
      for (int reg = 0; reg < 4; reg++) {
        const int m = m0 + wm * 64 + fm * 16 + lg * 4 + reg;
        const int n = n0 + wn * 64 + fn * 16 + l16;
        if (n >= NQKV) continue;
        const float v = acc[fm][fn][reg];
        const int l = m >> 1, bidx = m & 1;
        const int hd = n / 193;
        const int rem = n - hd * 193;
        const int bhi = bidx * NHEAD + hd;
        const size_t o = ((size_t)bhi * LSEQ + l) * DH;
        if (rem < 64)        qh[o + rem] = f2b(v);
        else if (rem < 128)  kh[o + rem - 64] = f2b(v);
        else if (rem < 192)  vh[o + rem - 128] = f2b(v);
        else                 bbuf[(size_t)bhi * LSEQ + l] = 1.f / (1.f + __expf(-v));
      }
}

// K5a: ao = h + lobf @ WoT^T (f32 out)
__global__ __launch_bounds__(256, 2)
void k_gemm_out(const bf16* __restrict__ A, const bf16* __restrict__ B,
                const float* __restrict__ h, float* __restrict__ ao)
{
  GEMM_PREAMBLE
  GEMM_STAGE(A, B, 0, 0);
  __syncthreads();
  for (int kt = 0; kt < 16; kt++) {
    const int b = kt & 1;
    if (kt < 15) GEMM_STAGE(A, B, kt + 1, b ^ 1);
    GEMM_COMPUTE(b);
    __syncthreads();
  }
#pragma unroll
  for (int fm = 0; fm < 4; fm++)
#pragma unroll
    for (int fn = 0; fn < 4; fn++)
#pragma unroll
      for (int reg = 0; reg < 4; reg++) {
        const int m = m0 + wm * 64 + fm * 16 + lg * 4 + reg;
        const int n = n0 + wn * 64 + fn * 16 + l16;
        const size_t o = (size_t)m * DMODEL + n;
        ao[o] = acc[fm][fn][reg] + h[o];
      }
}

// ---------------------------------------------------------------------------
// K2: FAVOR+ features. 16 rows per block, pm column in registers,
// outputs written XOR-swizzled at 16B-unit granularity: unit' = unit ^ (l&7).
// ---------------------------------------------------------------------------
__global__ __launch_bounds__(256)
void k_feat(const bf16* __restrict__ qh, const bf16* __restrict__ kh,
            const float* __restrict__ pm,
            bf16* __restrict__ Qp, bf16* __restrict__ Kp)
{
  const int tid = threadIdx.x;
  const int l0 = blockIdx.x * 16;
  const int bhi = blockIdx.y;
  const int lane = tid & 63, w = tid >> 6;
  __shared__ float xs[2][16][68];
  __shared__ float hns[2][16];
  __shared__ float psum[4][2][16];
  float pmr[64];
#pragma unroll
  for (int d = 0; d < 64; d++) pmr[d] = pm[d * MPROJ + tid];

  for (int t = tid; t < 2048; t += 256) {
    const int wh = t >> 10, r = (t >> 6) & 15, d = t & 63;
    const bf16* src = wh ? kh : qh;
    xs[wh][r][d] = b2f(src[((size_t)bhi * LSEQ + l0 + r) * DH + d]) * 0.35355339059327373f;
  }
  __syncthreads();
  if (tid < 32) {
    const int wh = tid >> 4, r = tid & 15;
    float hn = 0.f;
#pragma unroll
    for (int d = 0; d < 64; d++) hn = fmaf(xs[wh][r][d], xs[wh][r][d], hn);
    hns[wh][r] = 0.5f * hn;
  }
  __syncthreads();

  for (int wh = 0; wh < 2; wh++) {
    bf16* dst = wh ? Kp : Qp;
    float ep[16], en[16];
#pragma unroll
    for (int r = 0; r < 16; r++) {
      float pr = 0.f;
#pragma unroll
      for (int d0 = 0; d0 < 64; d0 += 4) {
        const float4 xv = *(const float4*)&xs[wh][r][d0];
        pr = fmaf(xv.x, pmr[d0], pr);     pr = fmaf(xv.y, pmr[d0 + 1], pr);
        pr = fmaf(xv.z, pmr[d0 + 2], pr); pr = fmaf(xv.w, pmr[d0 + 3], pr);
      }
      const float hn = hns[wh][r];
      ep[r] = __expf(pr - hn) + 1e-4f;
      en[r] = __expf(-pr - hn) + 1e-4f;
      float s = ep[r] + en[r];
#pragma unroll
      for (int off = 32; off > 0; off >>= 1) s += __shfl_down(s, off);
      if (lane == 0) psum[w][wh][r] = s;
    }
    __syncthreads();
#pragma unroll
    for (int r = 0; r < 16; r++) {
      const float tot = psum[0][wh][r] + psum[1][wh][r] + psum[2][wh][r] + psum[3][wh][r];
      const float inv = 1.f / tot;
      const size_t base = ((size_t)bhi * LSEQ + l0 + r) * PF;
      const int ue = ((tid >> 3) ^ (r & 7));
      const int un = (32 + ((tid >> 3) ^ (r & 7)));
      dst[base + (ue << 3) + (tid & 7)] = f2b(ep[r] * inv);
      dst[base + (un << 3) + (tid & 7)] = f2b(en[r] * inv);
    }
    __syncthreads();
  }
}

// ---------------------------------------------------------------------------
// K3: per (chunk, bh): S = Kp Kp^T, Gs = -triu_strict(Qp Kp^T) (bf16, swz),
// T = (I + tril_strict(diag(b)S))^{-1} diag(b) (bf16, swz), KpT (bf16, swz).
// ---------------------------------------------------------------------------
__global__ __launch_bounds__(256)
void k_sgsolve(const bf16* __restrict__ Kp, const bf16* __restrict__ Qp,
               const float* __restrict__ bbuf,
               bf16* __restrict__ Gs, bf16* __restrict__ Tm,
               bf16* __restrict__ KpT)
{
  __shared__ float sK[CHK][65];   // staging; reused as S after the GEMM loop
  __shared__ float sQ[CHK][65];   // staging; reused as T
  __shared__ float sBeta[CHK];
  const int tid = threadIdx.x;
  const int c = blockIdx.x, bhi = blockIdx.y;
  const int ty = tid >> 4, tx = tid & 15;
  const size_t cb = ((size_t)bhi * LSEQ + (size_t)c * CHK) * PF;
  const size_t rowb = (size_t)bhi * LSEQ + (size_t)c * CHK;
  const size_t ktb = (((size_t)bhi * NCHK + c) * 512) * 64;

  float accS[4][4], accG[4][4];
#pragma unroll
  for (int i = 0; i < 4; i++)
#pragma unroll
    for (int j = 0; j < 4; j++) { accS[i][j] = 0.f; accG[i][j] = 0.f; }

  for (int p0 = 0; p0 < PF; p0 += 64) {
    {
      const int row = tid >> 2;
      const int pc = (tid & 3) * 16;
      const int u = (p0 + pc) >> 3;  // even unit index
      const int su0 = (u ^ (row & 7)), su1 = ((u + 1) ^ (row & 7));
      const uint4 k0 = *(const uint4*)(Kp + cb + (size_t)row * PF + (su0 << 3));
      const uint4 k1 = *(const uint4*)(Kp + cb + (size_t)row * PF + (su1 << 3));
      const uint4 q0 = *(const uint4*)(Qp + cb + (size_t)row * PF + (su0 << 3));
      const uint4 q1 = *(const uint4*)(Qp + cb + (size_t)row * PF + (su1 << 3));
      float f[16];
      UNP(k0.x, f[0], f[1]); UNP(k0.y, f[2], f[3]); UNP(k0.z, f[4], f[5]); UNP(k0.w, f[6], f[7]);
      UNP(k1.x, f[8], f[9]); UNP(k1.y, f[10], f[11]); UNP(k1.z, f[12], f[13]); UNP(k1.w, f[14], f[15]);
#pragma unroll
      for (int t = 0; t < 16; t++) sK[row][pc + t] = f[t];
      UNP(q0.x, f[0], f[1]); UNP(q0.y, f[2], f[3]); UNP(q0.z, f[4], f[5]); UNP(q0.w, f[6], f[7]);
      UNP(q1.x, f[8], f[9]); UNP(q1.y, f[10], f[11]); UNP(q1.z, f[12], f[13]); UNP(q1.w, f[14], f[15]);
#pragma unroll
      for (int t = 0; t < 16; t++) sQ[row][pc + t] = f[t];
    }
    __syncthreads();
#pragma unroll 8
    for (int kk = 0; kk < 64; kk++) {
      float bj[4], ai[4], aq[4];
#pragma unroll
      for (int j = 0; j < 4; j++) bj[j] = sK[tx * 4 + j][kk];
#pragma unroll
      for (int i = 0; i < 4; i++) { ai[i] = sK[ty * 4 + i][kk]; aq[i] = sQ[ty * 4 + i][kk]; }
#pragma unroll
      for (int i = 0; i < 4; i++)
#pragma unroll
        for (int j = 0; j < 4; j++) {
          accS[i][j] = fmaf(ai[i], bj[j], accS[i][j]);
          accG[i][j] = fmaf(aq[i], bj[j], accG[i][j]);
        }
    }
    // emit KpT slice [p0..p0+63][64 l], bf16, unit-swizzled (unit = l>>3 ^ p&7)
    for (int t = tid; t < 512; t += 256) {
      const int pl = t >> 3, l8 = t & 7;
      const int p = p0 + pl;
      unsigned rr[4];
#pragma unroll
      for (int jj = 0; jj < 4; jj++)
        rr[jj] = pkbf(sK[l8 * 8 + jj * 2][pl], sK[l8 * 8 + jj * 2 + 1][pl]);
      *(uint4*)&KpT[ktb + (size_t)p * 64 + ((l8 ^ (p & 7)) << 3)] =
          make_uint4(rr[0], rr[1], rr[2], rr[3]);
    }
    __syncthreads();
  }

  const size_t sb = (((size_t)bhi * NCHK + c) * CHK) * CHK;
#pragma unroll
  for (int i = 0; i < 4; i++) {
    const int ri = ty * 4 + i;
#pragma unroll
    for (int j = 0; j < 4; j++) {
      const int cj = tx * 4 + j;
      Gs[sb + ri * 64 + (((cj >> 3) ^ (ri & 7)) << 3) + (cj & 7)] =
          f2b((cj > ri) ? -accG[i][j] : 0.f);
      sK[ri][cj] = accS[i][j];          // stash full S
    }
  }
  if (tid < CHK) sBeta[tid] = bbuf[rowb + tid];
  __syncthreads();

  if (tid < CHK) {
    const int j = tid;
    for (int i = 0; i < CHK; i++) {
      float acc = (i == j) ? 1.f : 0.f;
      for (int k = 0; k < i; k++) acc = fmaf(-sK[i][k], sQ[k][j], acc);
      sQ[i][j] = sBeta[i] * acc;
    }
  }
  __syncthreads();
  for (int t = tid; t < CHK * CHK; t += 256) {
    const int r = t >> 6, ccj = t & 63;
    Tm[sb + r * 64 + (((ccj >> 3) ^ (r & 7)) << 3) + (ccj & 7)] = f2b(sQ[r][ccj]);
  }
}

// ---------------------------------------------------------------------------
// K4: MFMA chunk scan (unchanged structure; output now bf16 pre-swizzled
// into lobf so k_gemm_out can consume it directly).
// ---------------------------------------------------------------------------
__global__ __launch_bounds__(256, 1)
void k_scan(const bf16* __restrict__ Kp, const bf16* __restrict__ Qp,
            const bf16* __restrict__ vh, const bf16* __restrict__ Tm,
            const bf16* __restrict__ Gs, const bf16* __restrict__ KpT,
            bf16* __restrict__ lobf)
{
  __shared__ __align__(16) char sb[2][65536];   // dbuf: Kp / KpT / Qp
  __shared__ __align__(16) char sWT[16384];     // WT[d=16][p=512] bf16, xor-swz
  __shared__ __align__(16) char sTG[8192];      // T then Gs (producer-swz)
  __shared__ __align__(16) char sUT[2048];      // U^T[d=16][l=64] bf16, xor-swz
  __shared__ __align__(16) char suP[2048];      // upre^T, same layout

  const int tid = threadIdx.x;
  const int w = tid >> 6, lane = tid & 63;
  const int l16 = lane & 15, lg = lane >> 4;
  const int bhi = blockIdx.x & 31, dq = blockIdx.x >> 5;
  const int bidx = bhi >> 4, hd = bhi & 15;
  const int xs = l16 & 7;                       // xor key

  for (int i = tid; i < 4096; i += 256) ((unsigned*)sWT)[i] = 0u;

  f32x4 Wacc[8];
#pragma unroll
  for (int i = 0; i < 8; i++) Wacc[i] = (f32x4){0.f, 0.f, 0.f, 0.f};

  const size_t bh_base = (size_t)bhi * LSEQ * PF;
  const size_t tg0 = ((size_t)bhi * NCHK) * 4096;
  const size_t kt0 = ((size_t)bhi * NCHK) * (512 * 64);

  // prologue: stage Kp(0) into sb[0]
  {
    const char* g = (const char*)(Kp + bh_base);
#pragma unroll
    for (int j = 0; j < 16; j++)
      gl_lds16(g + (w * 16 + j) * 1024 + lane * 16, &sb[0][(w * 16 + j) * 1024]);
  }
  MEMFENCE;
  WAITLGKM; BARRIER();   // sWT zeros visible

  int cur = 0;
  for (int c = 0; c < NCHK; c++) {
    BARRIER();  // B0: prev-iter readers of sb/sTG/sUT done

    const size_t cb = bh_base + (size_t)c * CHK * PF;
    const char* TmC  = (const char*)(Tm + tg0 + (size_t)c * 4096);
    const char* GsC  = (const char*)(Gs + tg0 + (size_t)c * 4096);
    const char* KpTC = (const char*)(KpT + kt0 + (size_t)c * (512 * 64));
    const char* QpC  = (const char*)(Qp + cb);
    const char* KpN  = (const char*)(Kp + cb + CHK * PF);

    // V (compiler-managed waits)
    const bf16* vp = vh + ((size_t)bhi * LSEQ + c * 64 + w * 16 + lg * 4) * 64 + dq * 16 + l16;
    const float v0 = b2f(vp[0]),   v1 = b2f(vp[64]);
    const float v2 = b2f(vp[128]), v3 = b2f(vp[192]);
    MEMFENCE;
    // stage T(c) -> sTG
#pragma unroll
    for (int j = 0; j < 2; j++)
      gl_lds16(TmC + (w * 2 + j) * 1024 + lane * 16, &sTG[(w * 2 + j) * 1024]);
    MEMFENCE;
    // stage KpT(c) -> sb[cur^1]
#pragma unroll
    for (int j = 0; j < 16; j++)
      gl_lds16(KpTC + (w * 16 + j) * 1024 + lane * 16, &sb[cur ^ 1][(w * 16 + j) * 1024]);
    MEMFENCE;
    WAITV(22);  // Kp(c) ready

    // ---- upre = V - Kp*W(old) ----
    f32x4 a0v = (f32x4){0.f,0.f,0.f,0.f}, a1v = (f32x4){0.f,0.f,0.f,0.f};
#pragma unroll
    for (int ks = 0; ks < 16; ks += 2) {
      const bf16x8 aa0 = *(const bf16x8*)&sb[cur][(16 * w + l16) * 1024 + ((((ks    ) * 4 + lg) ^ xs) << 4)];
      const bf16x8 bb0 = *(const bf16x8*)&sWT[l16 * 1024 + ((((ks    ) * 4 + lg) ^ xs) << 4)];
      a0v = MFMA(aa0, bb0, a0v);
      const bf16x8 aa1 = *(const bf16x8*)&sb[cur][(16 * w + l16) * 1024 + ((((ks + 1) * 4 + lg) ^ xs) << 4)];
      const bf16x8 bb1 = *(const bf16x8*)&sWT[l16 * 1024 + ((((ks + 1) * 4 + lg) ^ xs) << 4)];
      a1v = MFMA(aa1, bb1, a1v);
    }
    {
      const int l0r = 16 * w + lg * 4;
      const unsigned plo = pkbf(v0 - (a0v[0] + a1v[0]), v1 - (a0v[1] + a1v[1]));
      const unsigned phi = pkbf(v2 - (a0v[2] + a1v[2]), v3 - (a0v[3] + a1v[3]));
      *(uint2*)&suP[l16 * 128 + ((((l0r >> 3)) ^ xs) << 4) + (l0r & 7) * 2] = make_uint2(plo, phi);
    }
    WAITLGKM; BARRIER();  // B1: suP ready
    WAITV(16);            // T ready

    // ---- U = T * upre ----
    {
      f32x4 ua = (f32x4){0.f,0.f,0.f,0.f};
#pragma unroll
      for (int ks = 0; ks < 2; ks++) {
        const bf16x8 aa = *(const bf16x8*)&sTG[(16 * w + l16) * 128 + (((ks * 4 + lg) ^ xs) << 4)];
        const bf16x8 bb = *(const bf16x8*)&suP[l16 * 128 + (((ks * 4 + lg) ^ xs) << 4)];
        ua = MFMA(aa, bb, ua);
      }
      const int l0r = 16 * w + lg * 4;
      *(uint2*)&sUT[l16 * 128 + ((((l0r >> 3)) ^ xs) << 4) + (l0r & 7) * 2] =
          make_uint2(pkbf(ua[0], ua[1]), pkbf(ua[2], ua[3]));
    }
    WAITLGKM; BARRIER();  // B2: sUT ready

    // stage Qp(c) -> sb[cur]
#pragma unroll
    for (int j = 0; j < 16; j++)
      gl_lds16(QpC + (w * 16 + j) * 1024 + lane * 16, &sb[cur][(w * 16 + j) * 1024]);
    MEMFENCE;
    WAITV(16);            // KpT ready

    // ---- W += KpT * U ----
    {
      bf16x8 bu[2];
#pragma unroll
      for (int ks = 0; ks < 2; ks++)
        bu[ks] = *(const bf16x8*)&sUT[l16 * 128 + (((ks * 4 + lg) ^ xs) << 4)];
#pragma unroll
      for (int mt = 0; mt < 8; mt++) {
        const int p = w * 128 + mt * 16 + l16;
#pragma unroll
        for (int ks = 0; ks < 2; ks++) {
          const bf16x8 aa = *(const bf16x8*)&sb[cur ^ 1][p * 128 + (((ks * 4 + lg) ^ xs) << 4)];
          Wacc[mt] = MFMA(aa, bu[ks], Wacc[mt]);
        }
      }
#pragma unroll
      for (int mt = 0; mt < 8; mt++) {
        const int p0m = w * 128 + mt * 16 + lg * 4;
        *(uint2*)&sWT[l16 * 1024 + ((((p0m >> 3)) ^ xs) << 4) + (p0m & 7) * 2] =
            make_uint2(pkbf(Wacc[mt][0], Wacc[mt][1]), pkbf(Wacc[mt][2], Wacc[mt][3]));
      }
    }
    WAITLGKM; BARRIER();  // B3: sWT(new) ready

    // stage Gs(c) -> sTG ; prefetch Kp(c+1) -> sb[cur^1]
#pragma unroll
    for (int j = 0; j < 2; j++)
      gl_lds16(GsC + (w * 2 + j) * 1024 + lane * 16, &sTG[(w * 2 + j) * 1024]);
    MEMFENCE;
    if (c < NCHK - 1) {
#pragma unroll
      for (int j = 0; j < 16; j++)
        gl_lds16(KpN + (w * 16 + j) * 1024 + lane * 16, &sb[cur ^ 1][(w * 16 + j) * 1024]);
    }
    MEMFENCE;
    if (c < NCHK - 1) { WAITV(18); } else { WAITV(2); }   // Qp ready

    // ---- out = 0.125 * (Qp*W_new - Gs*U) ----
    f32x4 o0 = (f32x4){0.f,0.f,0.f,0.f}, o1 = (f32x4){0.f,0.f,0.f,0.f};
#pragma unroll
    for (int ks = 0; ks < 16; ks += 2) {
      const bf16x8 aa0 = *(const bf16x8*)&sb[cur][(16 * w + l16) * 1024 + ((((ks    ) * 4 + lg) ^ xs) << 4)];
      const bf16x8 bb0 = *(const bf16x8*)&sWT[l16 * 1024 + ((((ks    ) * 4 + lg) ^ xs) << 4)];
      o0 = MFMA(aa0, bb0, o0);
      const bf16x8 aa1 = *(const bf16x8*)&sb[cur][(16 * w + l16) * 1024 + ((((ks + 1) * 4 + lg) ^ xs) << 4)];
      const bf16x8 bb1 = *(const bf16x8*)&sWT[l16 * 1024 + ((((ks + 1) * 4 + lg) ^ xs) << 4)];
      o1 = MFMA(aa1, bb1, o1);
    }
    if (c < NCHK - 1) { WAITV(16); } else { WAITV(0); }   // Gs ready
#pragma unroll
    for (int ks = 0; ks < 2; ks++) {
      const bf16x8 aa = *(const bf16x8*)&sTG[(16 * w + l16) * 128 + (((ks * 4 + lg) ^ xs) << 4)];
      const bf16x8 bb = *(const bf16x8*)&sUT[l16 * 128 + (((ks * 4 + lg) ^ xs) << 4)];
      o0 = MFMA(aa, bb, o0);   // Gs pre-negated by producer
    }
    {
      const int colb = hd * 64 + dq * 16 + l16;
#pragma unroll
      for (int reg = 0; reg < 4; reg++) {
        const int l = c * 64 + 16 * w + lg * 4 + reg;
        const int r = l * BSZN + bidx;
        const int cp = (colb & ~63) | ((((colb >> 3) & 7) ^ (r & 7)) << 3) | (colb & 7);
        lobf[(size_t)r * DMODEL + cp] = f2b(0.125f * (o0[reg] + o1[reg]));
      }
    }
    cur ^= 1;
  }
}

// ---------------------------------------------------------------------------
// K5b: LayerNorm (unchanged)
// ---------------------------------------------------------------------------
__global__ __launch_bounds__(256)
void k_ln(const float* __restrict__ ao, const float* __restrict__ gamma,
          const float* __restrict__ beta, float* __restrict__ out)
{
  const int row = blockIdx.x;
  const int tid = threadIdx.x;
  __shared__ float r1[4], r2[4];
  const float4 v = *(const float4*)&ao[(size_t)row * DMODEL + tid * 4];
  float s1 = v.x + v.y + v.z + v.w;
  float s2 = v.x * v.x + v.y * v.y + v.z * v.z + v.w * v.w;
  for (int off = 32; off > 0; off >>= 1) {
    s1 += __shfl_down(s1, off);
    s2 += __shfl_down(s2, off);
  }
  if ((tid & 63) == 0) { r1[tid >> 6] = s1; r2[tid >> 6] = s2; }
  __syncthreads();
  const float ts1 = r1[0] + r1[1] + r1[2] + r1[3];
  const float ts2 = r2[0] + r2[1] + r2[2] + r2[3];
  const float mu = ts1 * (1.f / DMODEL);
  const float var = ts2 * (1.f / DMODEL) - mu * mu;
  const float rs = rsqrtf(var + 1e-5f);
  const float4 g = *(const float4*)&gamma[tid * 4];
  const float4 b = *(const float4*)&beta[tid * 4];
  float4 o;
  o.x = (v.x - mu) * rs * g.x + b.x;
  o.y = (v.y - mu) * rs * g.y + b.y;
  o.z = (v.z - mu) * rs * g.z + b.z;
  o.w = (v.w - mu) * rs * g.w + b.w;
  *(float4*)&out[(size_t)row * DMODEL + tid * 4] = o;
}

// ---------------------------------------------------------------------------
extern "C" void kernel_launch(void* const* d_in, const int* in_sizes, int n_in,
                              void* d_out, int out_size, void* d_ws, size_t ws_size,
                              hipStream_t stream)
{
  (void)in_sizes; (void)n_in; (void)out_size; (void)ws_size;
  const float* h   = (const float*)d_in[0];
  const float* Wq  = (const float*)d_in[1];
  const float* Wo  = (const float*)d_in[2];
  const float* gam = (const float*)d_in[3];
  const float* bet = (const float*)d_in[4];
  const float* pm  = (const float*)d_in[5];
  float* out = (float*)d_out;

  char* ws = (char*)d_ws;
  size_t off = 0;
  auto alloc = [&](size_t bytes) -> void* {
    void* p = ws + off;
    off += (bytes + 255) & ~(size_t)255;
    return p;
  };
  // total workspace ~= 229 MB
  bf16*  vh  = (bf16*)alloc((size_t)BHN * LSEQ * DH * 2);            //  8.4 MB
  float* bbf = (float*)alloc((size_t)BHN * LSEQ * 4);                //  0.3 MB
  bf16*  Kp  = (bf16*)alloc((size_t)BHN * LSEQ * PF * 2);            // 67.1 MB
  bf16*  Qp  = (bf16*)alloc((size_t)BHN * LSEQ * PF * 2);            // 67.1 MB
  bf16*  Tm  = (bf16*)alloc((size_t)BHN * NCHK * CHK * CHK * 2);     //  8.4 MB
  bf16*  Gs  = (bf16*)alloc((size_t)BHN * NCHK * CHK * CHK * 2);     //  8.4 MB
  char*  R   = (char*)alloc((size_t)BHN * NCHK * 512 * 64 * 2);      // 67.1 MB shared
  bf16*  WoT = (bf16*)alloc((size_t)DMODEL * DMODEL * 2);            //  2.1 MB
  // region R lifetimes:
  //  phase1 (cvt/qkvb/feat): qh(8.4) | kh(8.4) | hbf(8.4) | WqT(6.6)
  //  phase2 (sgsolve/scan):  KpT (67.1)
  //  phase3 (outgemm/ln):    ao (16.8 f32)
  bf16*  qh  = (bf16*)R;
  bf16*  kh  = (bf16*)(R + (size_t)BHN * LSEQ * DH * 2);
  bf16*  hbf = (bf16*)(R + (size_t)2 * BHN * LSEQ * DH * 2);
  bf16*  WqT = (bf16*)(R + (size_t)3 * BHN * LSEQ * DH * 2);
  bf16*  KpT = (bf16*)R;
  float* ao  = (float*)R;
  bf16*  lobf = (bf16*)d_out;   // d_out scratch; fully rewritten by k_ln

  k_cvth     <<<dim3(2048),                       256, 0, stream>>>(h, hbf);
  k_cvtw     <<<dim3(NQPAD / 64, 16),             256, 0, stream>>>(Wq, WqT, NQKV);
  k_cvtw     <<<dim3(DMODEL / 64, 16),            256, 0, stream>>>(Wo, WoT, DMODEL);
  k_gemm_qkvb<<<dim3(NQPAD / 128, 4096 / 128),    256, 0, stream>>>(hbf, WqT, qh, kh, vh, bbf);
  k_feat     <<<dim3(LSEQ / 16, BHN),             256, 0, stream>>>(qh, kh, pm, Qp, Kp);
  k_sgsolve  <<<dim3(NCHK, BHN),                  256, 0, stream>>>(Kp, Qp, bbf, Gs, Tm, KpT);
  k_scan     <<<dim3(128),                        256, 0, stream>>>(Kp, Qp, vh, Tm, Gs, KpT, lobf);
  k_gemm_out <<<dim3(DMODEL / 128, 4096 / 128),   256, 0, stream>>>(lobf, WoT, h, ao);
  k_ln       <<<dim3(4096),                       256, 0, stream>>>(ao, gam, bet, out);
}

// Round 5
// 513.793 us; speedup vs baseline: 3.2740x; 1.1325x over previous
//
#include <hip/hip_runtime.h>
#include <hip/hip_bf16.h>

// Problem constants (from reference)
#define LSEQ   2048
#define BSZN   2
#define DMODEL 1024
#define NHEAD  16
#define DH     64
#define MPROJ  256
#define PF     512   // 2*MPROJ feature dim
#define CHK    64    // chunk length
#define NCHK   32    // LSEQ/CHK
#define BHN    32    // BSZN*NHEAD
#define NQKV   3088  // NHEAD*(3*DH+1)
#define NQPAD  3200  // NQKV padded to 25*128

typedef __hip_bfloat16 bf16;
typedef short bf16x8 __attribute__((ext_vector_type(8)));
typedef float f32x4 __attribute__((ext_vector_type(4)));

#define MFMA(a, b, c) __builtin_amdgcn_mfma_f32_16x16x32_bf16(a, b, c, 0, 0, 0)

// unpack a u32 holding two bf16 (little-endian: low half = first element)
#define UNP(u, a, b) { a = __uint_as_float((unsigned)(u) << 16); b = __uint_as_float((unsigned)(u) & 0xffff0000u); }

static __device__ __forceinline__ float b2f(bf16 x) {
  unsigned short us = *(unsigned short*)&x;
  return __uint_as_float((unsigned)us << 16);
}
static __device__ __forceinline__ bf16 f2b(float x) { return __float2bfloat16(x); }
static __device__ __forceinline__ unsigned pkbf(float a, float b) {
  bf16 x = __float2bfloat16(a), y = __float2bfloat16(b);
  return ((unsigned)(*(unsigned short*)&y) << 16) | (unsigned)(*(unsigned short*)&x);
}

// async global->LDS, 16B per lane. gsrc is PER-LANE; ldst wave-uniform base.
static __device__ __forceinline__ void gl_lds16(const void* gsrc, void* ldst) {
  __builtin_amdgcn_global_load_lds(
      (const __attribute__((address_space(1))) unsigned int*)gsrc,
      (__attribute__((address_space(3))) unsigned int*)ldst, 16, 0, 0);
}

#define MEMFENCE asm volatile("" ::: "memory")
#define WAITV(n) asm volatile("s_waitcnt vmcnt(" #n ")" ::: "memory")
#define WAITLGKM asm volatile("s_waitcnt lgkmcnt(0)" ::: "memory")
#define BARRIER() __builtin_amdgcn_s_barrier()

// ---------------------------------------------------------------------------
// K0a: h (f32) -> hbf (bf16), pre-swizzled: within each 64-elem group, 16B
// unit u stored at u ^ (row&7).
// ---------------------------------------------------------------------------
__global__ __launch_bounds__(256)
void k_cvth(const float* __restrict__ h, bf16* __restrict__ hbf)
{
  const int gt = blockIdx.x * 256 + threadIdx.x;   // unit id, 4096*128 total
  const int r = gt >> 7, ug = gt & 127;
  const int grp = ug >> 3, u = ug & 7;
  const float4 f0 = *(const float4*)&h[(size_t)r * 1024 + grp * 64 + u * 8];
  const float4 f1 = *(const float4*)&h[(size_t)r * 1024 + grp * 64 + u * 8 + 4];
  uint4 o;
  o.x = pkbf(f0.x, f0.y); o.y = pkbf(f0.z, f0.w);
  o.z = pkbf(f1.x, f1.y); o.w = pkbf(f1.z, f1.w);
  *(uint4*)&hbf[(size_t)r * 1024 + grp * 64 + ((u ^ (r & 7)) << 3)] = o;
}

// ---------------------------------------------------------------------------
// K0b: W [1024][nsrc] f32 -> WT [gridDim.x*64][1024] bf16 transposed,
// pre-swizzled, zero-padded rows beyond nsrc.
// ---------------------------------------------------------------------------
__global__ __launch_bounds__(256)
void k_cvtw(const float* __restrict__ W, bf16* __restrict__ WT, int nsrc)
{
  __shared__ float sT[64][65];
  const int tid = threadIdx.x;
  const int n0 = blockIdx.x * 64, k0 = blockIdx.y * 64;
#pragma unroll
  for (int j = 0; j < 16; j++) {
    const int e = j * 256 + tid;
    const int r = e >> 6, c = e & 63;
    sT[r][c] = (n0 + c < nsrc) ? W[(size_t)(k0 + r) * nsrc + n0 + c] : 0.f;
  }
  __syncthreads();
#pragma unroll
  for (int j = 0; j < 2; j++) {
    const int uid = j * 256 + tid;
    const int rp = uid >> 3, u = uid & 7;
    uint4 o;
    o.x = pkbf(sT[u * 8 + 0][rp], sT[u * 8 + 1][rp]);
    o.y = pkbf(sT[u * 8 + 2][rp], sT[u * 8 + 3][rp]);
    o.z = pkbf(sT[u * 8 + 4][rp], sT[u * 8 + 5][rp]);
    o.w = pkbf(sT[u * 8 + 6][rp], sT[u * 8 + 7][rp]);
    *(uint4*)&WT[(size_t)(n0 + rp) * 1024 + k0 + ((u ^ (rp & 7)) << 3)] = o;
  }
}

// ---------------------------------------------------------------------------
// MFMA GEMM core: C[128m x 128n] tile, BK=64, 4 waves (2x2), double-buffered
// global_load_lds staging, xor-swizzled LDS reads (sources pre-swizzled).
// ---------------------------------------------------------------------------
#define GEMM_STAGE(Abase, Bbase, kt, b) {                                      \
  const size_t kb = (size_t)(kt) * 128;   /* byte offset of k-window */        \
  _Pragma("unroll")                                                            \
  for (int j = 0; j < 4; j++) {                                                \
    const int row = (w * 4 + j) * 8 + (lane >> 3);                             \
    gl_lds16((const char*)(Abase) + (size_t)(m0 + row) * 2048 + kb + (lane & 7) * 16, \
             &sA[b][(w * 4 + j) * 1024]);                                      \
  }                                                                            \
  _Pragma("unroll")                                                            \
  for (int j = 0; j < 4; j++) {                                                \
    const int row = (w * 4 + j) * 8 + (lane >> 3);                             \
    gl_lds16((const char*)(Bbase) + (size_t)(n0 + row) * 2048 + kb + (lane & 7) * 16, \
             &sB[b][(w * 4 + j) * 1024]);                                      \
  } }

#define GEMM_COMPUTE(b) {                                                      \
  _Pragma("unroll")                                                            \
  for (int ks = 0; ks < 2; ks++) {                                             \
    bf16x8 af[4], bfr[4];                                                      \
    _Pragma("unroll")                                                          \
    for (int f = 0; f < 4; f++) {                                              \
      const int row = wm * 64 + f * 16 + l16;                                  \
      af[f] = *(const bf16x8*)&sA[b][row * 128 + (((ks * 4 + lg) ^ xs) << 4)]; \
    }                                                                          \
    _Pragma("unroll")                                                          \
    for (int f = 0; f < 4; f++) {                                              \
      const int row = wn * 64 + f * 16 + l16;                                  \
      bfr[f] = *(const bf16x8*)&sB[b][row * 128 + (((ks * 4 + lg) ^ xs) << 4)]; \
    }                                                                          \
    _Pragma("unroll")                                                          \
    for (int fm = 0; fm < 4; fm++)                                             \
      _Pragma("unroll")                                                        \
      for (int fn = 0; fn < 4; fn++)                                           \
        acc[fm][fn] = MFMA(af[fm], bfr[fn], acc[fm][fn]);                      \
  } }

#define GEMM_PREAMBLE                                                          \
  __shared__ __align__(16) char sA[2][16384];                                  \
  __shared__ __align__(16) char sB[2][16384];                                  \
  const int tid = threadIdx.x, w = tid >> 6, lane = tid & 63;                  \
  const int l16 = lane & 15, lg = lane >> 4;                                   \
  const int wm = w >> 1, wn = w & 1;                                           \
  const int m0 = blockIdx.y * 128, n0 = blockIdx.x * 128;                      \
  const int xs = l16 & 7;                                                      \
  f32x4 acc[4][4];                                                             \
  _Pragma("unroll")                                                            \
  for (int i = 0; i < 4; i++)                                                  \
    _Pragma("unroll")                                                          \
    for (int j = 0; j < 4; j++) acc[i][j] = (f32x4){0.f, 0.f, 0.f, 0.f};

// K1: qkvb = hbf @ WqT^T, epilogue scatters to qh/kh/vh (bf16) + sigmoid b.
__global__ __launch_bounds__(256, 2)
void k_gemm_qkvb(const bf16* __restrict__ A, const bf16* __restrict__ B,
                 bf16* __restrict__ qh, bf16* __restrict__ kh,
                 bf16* __restrict__ vh, float* __restrict__ bbuf)
{
  GEMM_PREAMBLE
  GEMM_STAGE(A, B, 0, 0);
  __syncthreads();
  for (int kt = 0; kt < 16; kt++) {
    const int b = kt & 1;
    if (kt < 15) GEMM_STAGE(A, B, kt + 1, b ^ 1);
    GEMM_COMPUTE(b);
    __syncthreads();
  }
#pragma unroll
  for (int fm = 0; fm < 4; fm++)
#pragma unroll
    for (int fn = 0; fn < 4; fn++)
#pragma unroll
      for (int reg = 0; reg < 4; reg++) {
        const int m = m0 + wm * 64 + fm * 16 + lg * 4 + reg;
        const int n = n0 + wn * 64 + fn * 16 + l16;
        if (n >= NQKV) continue;
        const float v = acc[fm][fn][reg];
        const int l = m >> 1, bidx = m & 1;
        const int hd = n / 193;
        const int rem = n - hd * 193;
        const int bhi = bidx * NHEAD + hd;
        const size_t o = ((size_t)bhi * LSEQ + l) * DH;
        if (rem < 64)        qh[o + rem] = f2b(v);
        else if (rem < 128)  kh[o + rem - 64] = f2b(v);
        else if (rem < 192)  vh[o + rem - 128] = f2b(v);
        else                 bbuf[(size_t)bhi * LSEQ + l] = 1.f / (1.f + __expf(-v));
      }
}

// K5a: ao = h + lobf @ WoT^T (f32 out)
__global__ __launch_bounds__(256, 2)
void k_gemm_out(const bf16* __restrict__ A, const bf16* __restrict__ B,
                const float* __restrict__ h, float* __restrict__ ao)
{
  GEMM_PREAMBLE
  GEMM_STAGE(A, B, 0, 0);
  __syncthreads();
  for (int kt = 0; kt < 16; kt++) {
    const int b = kt & 1;
    if (kt < 15) GEMM_STAGE(A, B, kt + 1, b ^ 1);
    GEMM_COMPUTE(b);
    __syncthreads();
  }
#pragma unroll
  for (int fm = 0; fm < 4; fm++)
#pragma unroll
    for (int fn = 0; fn < 4; fn++)
#pragma unroll
      for (int reg = 0; reg < 4; reg++) {
        const int m = m0 + wm * 64 + fm * 16 + lg * 4 + reg;
        const int n = n0 + wn * 64 + fn * 16 + l16;
        const size_t o = (size_t)m * DMODEL + n;
        ao[o] = acc[fm][fn][reg] + h[o];
      }
}

// ---------------------------------------------------------------------------
// K2: FAVOR+ features. 16 rows per block, pm column in registers,
// outputs written XOR-swizzled at 16B-unit granularity: unit' = unit ^ (l&7).
// ---------------------------------------------------------------------------
__global__ __launch_bounds__(256)
void k_feat(const bf16* __restrict__ qh, const bf16* __restrict__ kh,
            const float* __restrict__ pm,
            bf16* __restrict__ Qp, bf16* __restrict__ Kp)
{
  const int tid = threadIdx.x;
  const int l0 = blockIdx.x * 16;
  const int bhi = blockIdx.y;
  const int lane = tid & 63, w = tid >> 6;
  __shared__ float xs[2][16][68];
  __shared__ float hns[2][16];
  __shared__ float psum[4][2][16];
  float pmr[64];
#pragma unroll
  for (int d = 0; d < 64; d++) pmr[d] = pm[d * MPROJ + tid];

  for (int t = tid; t < 2048; t += 256) {
    const int wh = t >> 10, r = (t >> 6) & 15, d = t & 63;
    const bf16* src = wh ? kh : qh;
    xs[wh][r][d] = b2f(src[((size_t)bhi * LSEQ + l0 + r) * DH + d]) * 0.35355339059327373f;
  }
  __syncthreads();
  if (tid < 32) {
    const int wh = tid >> 4, r = tid & 15;
    float hn = 0.f;
#pragma unroll
    for (int d = 0; d < 64; d++) hn = fmaf(xs[wh][r][d], xs[wh][r][d], hn);
    hns[wh][r] = 0.5f * hn;
  }
  __syncthreads();

  for (int wh = 0; wh < 2; wh++) {
    bf16* dst = wh ? Kp : Qp;
    float ep[16], en[16];
#pragma unroll
    for (int r = 0; r < 16; r++) {
      float pr = 0.f;
#pragma unroll
      for (int d0 = 0; d0 < 64; d0 += 4) {
        const float4 xv = *(const float4*)&xs[wh][r][d0];
        pr = fmaf(xv.x, pmr[d0], pr);     pr = fmaf(xv.y, pmr[d0 + 1], pr);
        pr = fmaf(xv.z, pmr[d0 + 2], pr); pr = fmaf(xv.w, pmr[d0 + 3], pr);
      }
      const float hn = hns[wh][r];
      ep[r] = __expf(pr - hn) + 1e-4f;
      en[r] = __expf(-pr - hn) + 1e-4f;
      float s = ep[r] + en[r];
#pragma unroll
      for (int off = 32; off > 0; off >>= 1) s += __shfl_down(s, off);
      if (lane == 0) psum[w][wh][r] = s;
    }
    __syncthreads();
#pragma unroll
    for (int r = 0; r < 16; r++) {
      const float tot = psum[0][wh][r] + psum[1][wh][r] + psum[2][wh][r] + psum[3][wh][r];
      const float inv = 1.f / tot;
      const size_t base = ((size_t)bhi * LSEQ + l0 + r) * PF;
      const int ue = ((tid >> 3) ^ (r & 7));
      const int un = (32 + ((tid >> 3) ^ (r & 7)));
      dst[base + (ue << 3) + (tid & 7)] = f2b(ep[r] * inv);
      dst[base + (un << 3) + (tid & 7)] = f2b(en[r] * inv);
    }
    __syncthreads();
  }
}

// ---------------------------------------------------------------------------
// K3 (MFMA rewrite): per (chunk, bh), 4 waves, 2 blocks/CU:
//   S = Kp Kp^T and G = Qp Kp^T via mfma_16x16x32 (wave w owns 16-row strip),
//   KpT emission fused (reads staged Kp windows from LDS),
//   T = (I + tril_strict(diag(b)S))^{-1} diag(b) by 64-lane forward subst.
// vmcnt is counted: per-wave issue order stage(w),em(w-1)[2st],stage(w+1)[4ld]
// -> WAITV(6) steady, 4 at w=0, 2 at w=7.
// ---------------------------------------------------------------------------
__global__ __launch_bounds__(256, 2)
void k_sgsolve(const bf16* __restrict__ Kp, const bf16* __restrict__ Qp,
               const float* __restrict__ bbuf,
               bf16* __restrict__ Gs, bf16* __restrict__ Tm,
               bf16* __restrict__ KpT)
{
  __shared__ __align__(16) char bufK[2][8192];
  __shared__ __align__(16) char bufQ[2][8192];
  __shared__ float sS[CHK][65];
  __shared__ float sT[CHK][65];
  __shared__ float sBeta[CHK];

  const int tid = threadIdx.x, w = tid >> 6, lane = tid & 63;
  const int l16 = lane & 15, lg = lane >> 4;
  const int xs = l16 & 7;
  const int c = blockIdx.x, bhi = blockIdx.y;
  const size_t cb = ((size_t)bhi * LSEQ + (size_t)c * CHK) * PF;
  const size_t rowb = (size_t)bhi * LSEQ + (size_t)c * CHK;
  const size_t ktb = (((size_t)bhi * NCHK + c) * 512) * 64;
  const size_t sb = (((size_t)bhi * NCHK + c) * CHK) * CHK;

  if (tid < CHK) sBeta[tid] = bbuf[rowb + tid];

  f32x4 accS[4], accG[4];
#pragma unroll
  for (int i = 0; i < 4; i++) { accS[i] = (f32x4){0.f,0.f,0.f,0.f}; accG[i] = (f32x4){0.f,0.f,0.f,0.f}; }

#define SG_STAGE(win, b) {                                                     \
  _Pragma("unroll")                                                            \
  for (int j = 0; j < 2; j++) {                                                \
    const int row = w * 16 + j * 8 + (lane >> 3);                              \
    gl_lds16((const char*)(Kp + cb) + (size_t)row * 1024 + (size_t)(win) * 128 + (lane & 7) * 16, \
             &bufK[b][(w * 16 + j * 8) * 128]);                                \
  }                                                                            \
  _Pragma("unroll")                                                            \
  for (int j = 0; j < 2; j++) {                                                \
    const int row = w * 16 + j * 8 + (lane >> 3);                              \
    gl_lds16((const char*)(Qp + cb) + (size_t)row * 1024 + (size_t)(win) * 128 + (lane & 7) * 16, \
             &bufQ[b][(w * 16 + j * 8) * 128]);                                \
  } }

  SG_STAGE(0, 0);
  MEMFENCE;

  for (int win = 0; win < 8; win++) {
    const int b = win & 1;
    if (win < 7) { SG_STAGE(win + 1, b ^ 1); MEMFENCE; }
    if (win == 0)      { WAITV(4); }
    else if (win < 7)  { WAITV(6); }
    else               { WAITV(2); }
    BARRIER();

    // MFMA: wave w computes S/G rows [16w,16w+16) x all 64 cols, k=win*64..
#pragma unroll
    for (int ks = 0; ks < 2; ks++) {
      const bf16x8 aK = *(const bf16x8*)&bufK[b][(16 * w + l16) * 128 + (((ks * 4 + lg) ^ xs) << 4)];
      const bf16x8 aQ = *(const bf16x8*)&bufQ[b][(16 * w + l16) * 128 + (((ks * 4 + lg) ^ xs) << 4)];
      bf16x8 bK[4];
#pragma unroll
      for (int nt = 0; nt < 4; nt++)
        bK[nt] = *(const bf16x8*)&bufK[b][(nt * 16 + l16) * 128 + (((ks * 4 + lg) ^ xs) << 4)];
#pragma unroll
      for (int nt = 0; nt < 4; nt++) {
        accS[nt] = MFMA(aK, bK[nt], accS[nt]);
        accG[nt] = MFMA(aQ, bK[nt], accG[nt]);
      }
    }

    // KpT emission for this window: KpT[p][l], p = win*64 + pl
#pragma unroll
    for (int jj = 0; jj < 2; jj++) {
      const int idx = jj * 256 + tid;
      const int pl = idx >> 3, l8 = idx & 7;
      unsigned short v[8];
#pragma unroll
      for (int j = 0; j < 8; j++) {
        const int l = l8 * 8 + j;
        v[j] = *(const unsigned short*)&bufK[b][l * 128 + (((pl >> 3) ^ (l & 7)) << 4) + (pl & 7) * 2];
      }
      uint4 o;
      o.x = ((unsigned)v[1] << 16) | v[0];
      o.y = ((unsigned)v[3] << 16) | v[2];
      o.z = ((unsigned)v[5] << 16) | v[4];
      o.w = ((unsigned)v[7] << 16) | v[6];
      const int p = win * 64 + pl;
      *(uint4*)&KpT[ktb + (size_t)p * 64 + ((l8 ^ (p & 7)) << 3)] = o;
    }
    BARRIER();
  }
#undef SG_STAGE

  // epilogue: S -> LDS f32, G -> global (negated strict-upper, swizzled)
#pragma unroll
  for (int nt = 0; nt < 4; nt++)
#pragma unroll
    for (int reg = 0; reg < 4; reg++) {
      const int ri = 16 * w + lg * 4 + reg;
      const int cj = nt * 16 + l16;
      sS[ri][cj] = accS[nt][reg];
      Gs[sb + ri * 64 + (((cj >> 3) ^ (ri & 7)) << 3) + (cj & 7)] =
          f2b((cj > ri) ? -accG[nt][reg] : 0.f);
    }
  __syncthreads();

  // forward substitution, column j per lane (sS[i][k] broadcasts across lanes)
  if (tid < CHK) {
    const int j = tid;
    for (int i = 0; i < CHK; i++) {
      float acc = (i == j) ? 1.f : 0.f;
      for (int k = 0; k < i; k++) acc = fmaf(-sS[i][k], sT[k][j], acc);
      sT[i][j] = sBeta[i] * acc;
    }
  }
  __syncthreads();
  for (int t = tid; t < CHK * CHK; t += 256) {
    const int r = t >> 6, ccj = t & 63;
    Tm[sb + r * 64 + (((ccj >> 3) ^ (r & 7)) << 3) + (ccj & 7)] = f2b(sT[r][ccj]);
  }
}

// ---------------------------------------------------------------------------
// K4: MFMA chunk scan (unchanged; verified in rounds 3-4)
// ---------------------------------------------------------------------------
__global__ __launch_bounds__(256, 1)
void k_scan(const bf16* __restrict__ Kp, const bf16* __restrict__ Qp,
            const bf16* __restrict__ vh, const bf16* __restrict__ Tm,
            const bf16* __restrict__ Gs, const bf16* __restrict__ KpT,
            bf16* __restrict__ lobf)
{
  __shared__ __align__(16) char sb[2][65536];   // dbuf: Kp / KpT / Qp
  __shared__ __align__(16) char sWT[16384];     // WT[d=16][p=512] bf16, xor-swz
  __shared__ __align__(16) char sTG[8192];      // T then Gs (producer-swz)
  __shared__ __align__(16) char sUT[2048];      // U^T[d=16][l=64] bf16, xor-swz
  __shared__ __align__(16) char suP[2048];      // upre^T, same layout

  const int tid = threadIdx.x;
  const int w = tid >> 6, lane = tid & 63;
  const int l16 = lane & 15, lg = lane >> 4;
  const int bhi = blockIdx.x & 31, dq = blockIdx.x >> 5;
  const int bidx = bhi >> 4, hd = bhi & 15;
  const int xs = l16 & 7;                       // xor key

  for (int i = tid; i < 4096; i += 256) ((unsigned*)sWT)[i] = 0u;

  f32x4 Wacc[8];
#pragma unroll
  for (int i = 0; i < 8; i++) Wacc[i] = (f32x4){0.f, 0.f, 0.f, 0.f};

  const size_t bh_base = (size_t)bhi * LSEQ * PF;
  const size_t tg0 = ((size_t)bhi * NCHK) * 4096;
  const size_t kt0 = ((size_t)bhi * NCHK) * (512 * 64);

  // prologue: stage Kp(0) into sb[0]
  {
    const char* g = (const char*)(Kp + bh_base);
#pragma unroll
    for (int j = 0; j < 16; j++)
      gl_lds16(g + (w * 16 + j) * 1024 + lane * 16, &sb[0][(w * 16 + j) * 1024]);
  }
  MEMFENCE;
  WAITLGKM; BARRIER();   // sWT zeros visible

  int cur = 0;
  for (int c = 0; c < NCHK; c++) {
    BARRIER();  // B0: prev-iter readers of sb/sTG/sUT done

    const size_t cb = bh_base + (size_t)c * CHK * PF;
    const char* TmC  = (const char*)(Tm + tg0 + (size_t)c * 4096);
    const char* GsC  = (const char*)(Gs + tg0 + (size_t)c * 4096);
    const char* KpTC = (const char*)(KpT + kt0 + (size_t)c * (512 * 64));
    const char* QpC  = (const char*)(Qp + cb);
    const char* KpN  = (const char*)(Kp + cb + CHK * PF);

    // V (compiler-managed waits)
    const bf16* vp = vh + ((size_t)bhi * LSEQ + c * 64 + w * 16 + lg * 4) * 64 + dq * 16 + l16;
    const float v0 = b2f(vp[0]),   v1 = b2f(vp[64]);
    const float v2 = b2f(vp[128]), v3 = b2f(vp[192]);
    MEMFENCE;
    // stage T(c) -> sTG
#pragma unroll
    for (int j = 0; j < 2; j++)
      gl_lds16(TmC + (w * 2 + j) * 1024 + lane * 16, &sTG[(w * 2 + j) * 1024]);
    MEMFENCE;
    // stage KpT(c) -> sb[cur^1]
#pragma unroll
    for (int j = 0; j < 16; j++)
      gl_lds16(KpTC + (w * 16 + j) * 1024 + lane * 16, &sb[cur ^ 1][(w * 16 + j) * 1024]);
    MEMFENCE;
    WAITV(22);  // Kp(c) ready

    // ---- upre = V - Kp*W(old) ----
    f32x4 a0v = (f32x4){0.f,0.f,0.f,0.f}, a1v = (f32x4){0.f,0.f,0.f,0.f};
#pragma unroll
    for (int ks = 0; ks < 16; ks += 2) {
      const bf16x8 aa0 = *(const bf16x8*)&sb[cur][(16 * w + l16) * 1024 + ((((ks    ) * 4 + lg) ^ xs) << 4)];
      const bf16x8 bb0 = *(const bf16x8*)&sWT[l16 * 1024 + ((((ks    ) * 4 + lg) ^ xs) << 4)];
      a0v = MFMA(aa0, bb0, a0v);
      const bf16x8 aa1 = *(const bf16x8*)&sb[cur][(16 * w + l16) * 1024 + ((((ks + 1) * 4 + lg) ^ xs) << 4)];
      const bf16x8 bb1 = *(const bf16x8*)&sWT[l16 * 1024 + ((((ks + 1) * 4 + lg) ^ xs) << 4)];
      a1v = MFMA(aa1, bb1, a1v);
    }
    {
      const int l0r = 16 * w + lg * 4;
      const unsigned plo = pkbf(v0 - (a0v[0] + a1v[0]), v1 - (a0v[1] + a1v[1]));
      const unsigned phi = pkbf(v2 - (a0v[2] + a1v[2]), v3 - (a0v[3] + a1v[3]));
      *(uint2*)&suP[l16 * 128 + ((((l0r >> 3)) ^ xs) << 4) + (l0r & 7) * 2] = make_uint2(plo, phi);
    }
    WAITLGKM; BARRIER();  // B1: suP ready
    WAITV(16);            // T ready

    // ---- U = T * upre ----
    {
      f32x4 ua = (f32x4){0.f,0.f,0.f,0.f};
#pragma unroll
      for (int ks = 0; ks < 2; ks++) {
        const bf16x8 aa = *(const bf16x8*)&sTG[(16 * w + l16) * 128 + (((ks * 4 + lg) ^ xs) << 4)];
        const bf16x8 bb = *(const bf16x8*)&suP[l16 * 128 + (((ks * 4 + lg) ^ xs) << 4)];
        ua = MFMA(aa, bb, ua);
      }
      const int l0r = 16 * w + lg * 4;
      *(uint2*)&sUT[l16 * 128 + ((((l0r >> 3)) ^ xs) << 4) + (l0r & 7) * 2] =
          make_uint2(pkbf(ua[0], ua[1]), pkbf(ua[2], ua[3]));
    }
    WAITLGKM; BARRIER();  // B2: sUT ready

    // stage Qp(c) -> sb[cur]
#pragma unroll
    for (int j = 0; j < 16; j++)
      gl_lds16(QpC + (w * 16 + j) * 1024 + lane * 16, &sb[cur][(w * 16 + j) * 1024]);
    MEMFENCE;
    WAITV(16);            // KpT ready

    // ---- W += KpT * U ----
    {
      bf16x8 bu[2];
#pragma unroll
      for (int ks = 0; ks < 2; ks++)
        bu[ks] = *(const bf16x8*)&sUT[l16 * 128 + (((ks * 4 + lg) ^ xs) << 4)];
#pragma unroll
      for (int mt = 0; mt < 8; mt++) {
        const int p = w * 128 + mt * 16 + l16;
#pragma unroll
        for (int ks = 0; ks < 2; ks++) {
          const bf16x8 aa = *(const bf16x8*)&sb[cur ^ 1][p * 128 + (((ks * 4 + lg) ^ xs) << 4)];
          Wacc[mt] = MFMA(aa, bu[ks], Wacc[mt]);
        }
      }
#pragma unroll
      for (int mt = 0; mt < 8; mt++) {
        const int p0m = w * 128 + mt * 16 + lg * 4;
        *(uint2*)&sWT[l16 * 1024 + ((((p0m >> 3)) ^ xs) << 4) + (p0m & 7) * 2] =
            make_uint2(pkbf(Wacc[mt][0], Wacc[mt][1]), pkbf(Wacc[mt][2], Wacc[mt][3]));
      }
    }
    WAITLGKM; BARRIER();  // B3: sWT(new) ready

    // stage Gs(c) -> sTG ; prefetch Kp(c+1) -> sb[cur^1]
#pragma unroll
    for (int j = 0; j < 2; j++)
      gl_lds16(GsC + (w * 2 + j) * 1024 + lane * 16, &sTG[(w * 2 + j) * 1024]);
    MEMFENCE;
    if (c < NCHK - 1) {
#pragma unroll
      for (int j = 0; j < 16; j++)
        gl_lds16(KpN + (w * 16 + j) * 1024 + lane * 16, &sb[cur ^ 1][(w * 16 + j) * 1024]);
    }
    MEMFENCE;
    if (c < NCHK - 1) { WAITV(18); } else { WAITV(2); }   // Qp ready

    // ---- out = 0.125 * (Qp*W_new - Gs*U) ----
    f32x4 o0 = (f32x4){0.f,0.f,0.f,0.f}, o1 = (f32x4){0.f,0.f,0.f,0.f};
#pragma unroll
    for (int ks = 0; ks < 16; ks += 2) {
      const bf16x8 aa0 = *(const bf16x8*)&sb[cur][(16 * w + l16) * 1024 + ((((ks    ) * 4 + lg) ^ xs) << 4)];
      const bf16x8 bb0 = *(const bf16x8*)&sWT[l16 * 1024 + ((((ks    ) * 4 + lg) ^ xs) << 4)];
      o0 = MFMA(aa0, bb0, o0);
      const bf16x8 aa1 = *(const bf16x8*)&sb[cur][(16 * w + l16) * 1024 + ((((ks + 1) * 4 + lg) ^ xs) << 4)];
      const bf16x8 bb1 = *(const bf16x8*)&sWT[l16 * 1024 + ((((ks + 1) * 4 + lg) ^ xs) << 4)];
      o1 = MFMA(aa1, bb1, o1);
    }
    if (c < NCHK - 1) { WAITV(16); } else { WAITV(0); }   // Gs ready
#pragma unroll
    for (int ks = 0; ks < 2; ks++) {
      const bf16x8 aa = *(const bf16x8*)&sTG[(16 * w + l16) * 128 + (((ks * 4 + lg) ^ xs) << 4)];
      const bf16x8 bb = *(const bf16x8*)&sUT[l16 * 128 + (((ks * 4 + lg) ^ xs) << 4)];
      o0 = MFMA(aa, bb, o0);   // Gs pre-negated by producer
    }
    {
      const int colb = hd * 64 + dq * 16 + l16;
#pragma unroll
      for (int reg = 0; reg < 4; reg++) {
        const int l = c * 64 + 16 * w + lg * 4 + reg;
        const int r = l * BSZN + bidx;
        const int cp = (colb & ~63) | ((((colb >> 3) & 7) ^ (r & 7)) << 3) | (colb & 7);
        lobf[(size_t)r * DMODEL + cp] = f2b(0.125f * (o0[reg] + o1[reg]));
      }
    }
    cur ^= 1;
  }
}

// ---------------------------------------------------------------------------
// K5b: LayerNorm (unchanged)
// ---------------------------------------------------------------------------
__global__ __launch_bounds__(256)
void k_ln(const float* __restrict__ ao, const float* __restrict__ gamma,
          const float* __restrict__ beta, float* __restrict__ out)
{
  const int row = blockIdx.x;
  const int tid = threadIdx.x;
  __shared__ float r1[4], r2[4];
  const float4 v = *(const float4*)&ao[(size_t)row * DMODEL + tid * 4];
  float s1 = v.x + v.y + v.z + v.w;
  float s2 = v.x * v.x + v.y * v.y + v.z * v.z + v.w * v.w;
  for (int off = 32; off > 0; off >>= 1) {
    s1 += __shfl_down(s1, off);
    s2 += __shfl_down(s2, off);
  }
  if ((tid & 63) == 0) { r1[tid >> 6] = s1; r2[tid >> 6] = s2; }
  __syncthreads();
  const float ts1 = r1[0] + r1[1] + r1[2] + r1[3];
  const float ts2 = r2[0] + r2[1] + r2[2] + r2[3];
  const float mu = ts1 * (1.f / DMODEL);
  const float var = ts2 * (1.f / DMODEL) - mu * mu;
  const float rs = rsqrtf(var + 1e-5f);
  const float4 g = *(const float4*)&gamma[tid * 4];
  const float4 b = *(const float4*)&beta[tid * 4];
  float4 o;
  o.x = (v.x - mu) * rs * g.x + b.x;
  o.y = (v.y - mu) * rs * g.y + b.y;
  o.z = (v.z - mu) * rs * g.z + b.z;
  o.w = (v.w - mu) * rs * g.w + b.w;
  *(float4*)&out[(size_t)row * DMODEL + tid * 4] = o;
}

// ---------------------------------------------------------------------------
extern "C" void kernel_launch(void* const* d_in, const int* in_sizes, int n_in,
                              void* d_out, int out_size, void* d_ws, size_t ws_size,
                              hipStream_t stream)
{
  (void)in_sizes; (void)n_in; (void)out_size; (void)ws_size;
  const float* h   = (const float*)d_in[0];
  const float* Wq  = (const float*)d_in[1];
  const float* Wo  = (const float*)d_in[2];
  const float* gam = (const float*)d_in[3];
  const float* bet = (const float*)d_in[4];
  const float* pm  = (const float*)d_in[5];
  float* out = (float*)d_out;

  char* ws = (char*)d_ws;
  size_t off = 0;
  auto alloc = [&](size_t bytes) -> void* {
    void* p = ws + off;
    off += (bytes + 255) & ~(size_t)255;
    return p;
  };
  // total workspace ~= 229 MB
  bf16*  vh  = (bf16*)alloc((size_t)BHN * LSEQ * DH * 2);            //  8.4 MB
  float* bbf = (float*)alloc((size_t)BHN * LSEQ * 4);                //  0.3 MB
  bf16*  Kp  = (bf16*)alloc((size_t)BHN * LSEQ * PF * 2);            // 67.1 MB
  bf16*  Qp  = (bf16*)alloc((size_t)BHN * LSEQ * PF * 2);            // 67.1 MB
  bf16*  Tm  = (bf16*)alloc((size_t)BHN * NCHK * CHK * CHK * 2);     //  8.4 MB
  bf16*  Gs  = (bf16*)alloc((size_t)BHN * NCHK * CHK * CHK * 2);     //  8.4 MB
  char*  R   = (char*)alloc((size_t)BHN * NCHK * 512 * 64 * 2);      // 67.1 MB shared
  bf16*  WoT = (bf16*)alloc((size_t)DMODEL * DMODEL * 2);            //  2.1 MB
  // region R lifetimes:
  //  phase1 (cvt/qkvb/feat): qh(8.4) | kh(8.4) | hbf(8.4) | WqT(6.6)
  //  phase2 (sgsolve/scan):  KpT (67.1)
  //  phase3 (outgemm/ln):    ao (16.8 f32)
  bf16*  qh  = (bf16*)R;
  bf16*  kh  = (bf16*)(R + (size_t)BHN * LSEQ * DH * 2);
  bf16*  hbf = (bf16*)(R + (size_t)2 * BHN * LSEQ * DH * 2);
  bf16*  WqT = (bf16*)(R + (size_t)3 * BHN * LSEQ * DH * 2);
  bf16*  KpT = (bf16*)R;
  float* ao  = (float*)R;
  bf16*  lobf = (bf16*)d_out;   // d_out scratch; fully rewritten by k_ln

  k_cvth     <<<dim3(2048),                       256, 0, stream>>>(h, hbf);
  k_cvtw     <<<dim3(NQPAD / 64, 16),             256, 0, stream>>>(Wq, WqT, NQKV);
  k_cvtw     <<<dim3(DMODEL / 64, 16),            256, 0, stream>>>(Wo, WoT, DMODEL);
  k_gemm_qkvb<<<dim3(NQPAD / 128, 4096 / 128),    256, 0, stream>>>(hbf, WqT, qh, kh, vh, bbf);
  k_feat     <<<dim3(LSEQ / 16, BHN),             256, 0, stream>>>(qh, kh, pm, Qp, Kp);
  k_sgsolve  <<<dim3(NCHK, BHN),                  256, 0, stream>>>(Kp, Qp, bbf, Gs, Tm, KpT);
  k_scan     <<<dim3(128),                        256, 0, stream>>>(Kp, Qp, vh, Tm, Gs, KpT, lobf);
  k_gemm_out <<<dim3(DMODEL / 128, 4096 / 128),   256, 0, stream>>>(lobf, WoT, h, ao);
  k_ln       <<<dim3(4096),                       256, 0, stream>>>(ao, gam, bet, out);
}

// Round 6
// 476.312 us; speedup vs baseline: 3.5317x; 1.0787x over previous
//
#include <hip/hip_runtime.h>
#include <hip/hip_bf16.h>

// Problem constants (from reference)
#define LSEQ   2048
#define BSZN   2
#define DMODEL 1024
#define NHEAD  16
#define DH     64
#define MPROJ  256
#define PF     512   // 2*MPROJ feature dim
#define CHK    64    // chunk length
#define NCHK   32    // LSEQ/CHK
#define BHN    32    // BSZN*NHEAD
#define NQKV   3088  // NHEAD*(3*DH+1)
#define NQPAD  3200  // NQKV padded to 25*128

typedef __hip_bfloat16 bf16;
typedef short bf16x8 __attribute__((ext_vector_type(8)));
typedef float f32x4 __attribute__((ext_vector_type(4)));

#define MFMA(a, b, c) __builtin_amdgcn_mfma_f32_16x16x32_bf16(a, b, c, 0, 0, 0)

// unpack a u32 holding two bf16 (little-endian: low half = first element)
#define UNP(u, a, b) { a = __uint_as_float((unsigned)(u) << 16); b = __uint_as_float((unsigned)(u) & 0xffff0000u); }

static __device__ __forceinline__ float b2f(bf16 x) {
  unsigned short us = *(unsigned short*)&x;
  return __uint_as_float((unsigned)us << 16);
}
static __device__ __forceinline__ bf16 f2b(float x) { return __float2bfloat16(x); }
static __device__ __forceinline__ unsigned pkbf(float a, float b) {
  bf16 x = __float2bfloat16(a), y = __float2bfloat16(b);
  return ((unsigned)(*(unsigned short*)&y) << 16) | (unsigned)(*(unsigned short*)&x);
}

// async global->LDS, 16B per lane. gsrc is PER-LANE; ldst wave-uniform base.
static __device__ __forceinline__ void gl_lds16(const void* gsrc, void* ldst) {
  __builtin_amdgcn_global_load_lds(
      (const __attribute__((address_space(1))) unsigned int*)gsrc,
      (__attribute__((address_space(3))) unsigned int*)ldst, 16, 0, 0);
}

#define MEMFENCE asm volatile("" ::: "memory")
#define WAITV(n) asm volatile("s_waitcnt vmcnt(" #n ")" ::: "memory")
#define WAITLGKM asm volatile("s_waitcnt lgkmcnt(0)" ::: "memory")
#define BARRIER() __builtin_amdgcn_s_barrier()

// ---------------------------------------------------------------------------
// K0a: h (f32) -> hbf (bf16), pre-swizzled: within each 64-elem group, 16B
// unit u stored at u ^ (row&7).
// ---------------------------------------------------------------------------
__global__ __launch_bounds__(256)
void k_cvth(const float* __restrict__ h, bf16* __restrict__ hbf)
{
  const int gt = blockIdx.x * 256 + threadIdx.x;   // unit id, 4096*128 total
  const int r = gt >> 7, ug = gt & 127;
  const int grp = ug >> 3, u = ug & 7;
  const float4 f0 = *(const float4*)&h[(size_t)r * 1024 + grp * 64 + u * 8];
  const float4 f1 = *(const float4*)&h[(size_t)r * 1024 + grp * 64 + u * 8 + 4];
  uint4 o;
  o.x = pkbf(f0.x, f0.y); o.y = pkbf(f0.z, f0.w);
  o.z = pkbf(f1.x, f1.y); o.w = pkbf(f1.z, f1.w);
  *(uint4*)&hbf[(size_t)r * 1024 + grp * 64 + ((u ^ (r & 7)) << 3)] = o;
}

// ---------------------------------------------------------------------------
// K0b: W [1024][nsrc] f32 -> WT [gridDim.x*64][1024] bf16 transposed,
// pre-swizzled, zero-padded rows beyond nsrc.
// ---------------------------------------------------------------------------
__global__ __launch_bounds__(256)
void k_cvtw(const float* __restrict__ W, bf16* __restrict__ WT, int nsrc)
{
  __shared__ float sT[64][65];
  const int tid = threadIdx.x;
  const int n0 = blockIdx.x * 64, k0 = blockIdx.y * 64;
#pragma unroll
  for (int j = 0; j < 16; j++) {
    const int e = j * 256 + tid;
    const int r = e >> 6, c = e & 63;
    sT[r][c] = (n0 + c < nsrc) ? W[(size_t)(k0 + r) * nsrc + n0 + c] : 0.f;
  }
  __syncthreads();
#pragma unroll
  for (int j = 0; j < 2; j++) {
    const int uid = j * 256 + tid;
    const int rp = uid >> 3, u = uid & 7;
    uint4 o;
    o.x = pkbf(sT[u * 8 + 0][rp], sT[u * 8 + 1][rp]);
    o.y = pkbf(sT[u * 8 + 2][rp], sT[u * 8 + 3][rp]);
    o.z = pkbf(sT[u * 8 + 4][rp], sT[u * 8 + 5][rp]);
    o.w = pkbf(sT[u * 8 + 6][rp], sT[u * 8 + 7][rp]);
    *(uint4*)&WT[(size_t)(n0 + rp) * 1024 + k0 + ((u ^ (rp & 7)) << 3)] = o;
  }
}

// ---------------------------------------------------------------------------
// K0c: pm [64][256] f32 -> pmT hi/lo [256 n][64 d] bf16 (split compensation),
// scaled by 64^-0.25 = 2^-1.5, transposed, row-swizzled (key n&7).
// ---------------------------------------------------------------------------
__global__ __launch_bounds__(256)
void k_cvtpm(const float* __restrict__ pm, bf16* __restrict__ pmThi,
             bf16* __restrict__ pmTlo)
{
  const int n = threadIdx.x;
  float v[64];
#pragma unroll
  for (int d = 0; d < 64; d++) v[d] = pm[d * MPROJ + n] * 0.35355339059327373f;
  const int key = n & 7;
#pragma unroll
  for (int u = 0; u < 8; u++) {
    unsigned hi[4], lo[4];
#pragma unroll
    for (int j = 0; j < 4; j++) {
      const float a = v[u * 8 + j * 2], b = v[u * 8 + j * 2 + 1];
      const bf16 ah = f2b(a), bh_ = f2b(b);
      const float ar = a - b2f(ah), br = b - b2f(bh_);
      hi[j] = ((unsigned)(*(const unsigned short*)&bh_) << 16) | (unsigned)(*(const unsigned short*)&ah);
      const bf16 al = f2b(ar), bl = f2b(br);
      lo[j] = ((unsigned)(*(const unsigned short*)&bl) << 16) | (unsigned)(*(const unsigned short*)&al);
    }
    *(uint4*)&pmThi[(size_t)n * 64 + ((u ^ key) << 3)] = make_uint4(hi[0], hi[1], hi[2], hi[3]);
    *(uint4*)&pmTlo[(size_t)n * 64 + ((u ^ key) << 3)] = make_uint4(lo[0], lo[1], lo[2], lo[3]);
  }
}

// ---------------------------------------------------------------------------
// MFMA GEMM core: C[128m x 128n] tile, BK=64, 4 waves (2x2), double-buffered
// global_load_lds staging, xor-swizzled LDS reads (sources pre-swizzled).
// ---------------------------------------------------------------------------
#define GEMM_STAGE(Abase, Bbase, kt, b) {                                      \
  const size_t kb = (size_t)(kt) * 128;   /* byte offset of k-window */        \
  _Pragma("unroll")                                                            \
  for (int j = 0; j < 4; j++) {                                                \
    const int row = (w * 4 + j) * 8 + (lane >> 3);                             \
    gl_lds16((const char*)(Abase) + (size_t)(m0 + row) * 2048 + kb + (lane & 7) * 16, \
             &sA[b][(w * 4 + j) * 1024]);                                      \
  }                                                                            \
  _Pragma("unroll")                                                            \
  for (int j = 0; j < 4; j++) {                                                \
    const int row = (w * 4 + j) * 8 + (lane >> 3);                             \
    gl_lds16((const char*)(Bbase) + (size_t)(n0 + row) * 2048 + kb + (lane & 7) * 16, \
             &sB[b][(w * 4 + j) * 1024]);                                      \
  } }

#define GEMM_COMPUTE(b) {                                                      \
  _Pragma("unroll")                                                            \
  for (int ks = 0; ks < 2; ks++) {                                             \
    bf16x8 af[4], bfr[4];                                                      \
    _Pragma("unroll")                                                          \
    for (int f = 0; f < 4; f++) {                                              \
      const int row = wm * 64 + f * 16 + l16;                                  \
      af[f] = *(const bf16x8*)&sA[b][row * 128 + (((ks * 4 + lg) ^ xs) << 4)]; \
    }                                                                          \
    _Pragma("unroll")                                                          \
    for (int f = 0; f < 4; f++) {                                              \
      const int row = wn * 64 + f * 16 + l16;                                  \
      bfr[f] = *(const bf16x8*)&sB[b][row * 128 + (((ks * 4 + lg) ^ xs) << 4)]; \
    }                                                                          \
    _Pragma("unroll")                                                          \
    for (int fm = 0; fm < 4; fm++)                                             \
      _Pragma("unroll")                                                        \
      for (int fn = 0; fn < 4; fn++)                                           \
        acc[fm][fn] = MFMA(af[fm], bfr[fn], acc[fm][fn]);                      \
  } }

#define GEMM_PREAMBLE                                                          \
  __shared__ __align__(16) char sA[2][16384];                                  \
  __shared__ __align__(16) char sB[2][16384];                                  \
  const int tid = threadIdx.x, w = tid >> 6, lane = tid & 63;                  \
  const int l16 = lane & 15, lg = lane >> 4;                                   \
  const int wm = w >> 1, wn = w & 1;                                           \
  const int m0 = blockIdx.y * 128, n0 = blockIdx.x * 128;                      \
  const int xs = l16 & 7;                                                      \
  f32x4 acc[4][4];                                                             \
  _Pragma("unroll")                                                            \
  for (int i = 0; i < 4; i++)                                                  \
    _Pragma("unroll")                                                          \
    for (int j = 0; j < 4; j++) acc[i][j] = (f32x4){0.f, 0.f, 0.f, 0.f};

// K1: qkvb = hbf @ WqT^T, epilogue scatters to qh/kh (bf16, PRE-SWIZZLED for
// featm staging), vh (bf16, linear) + sigmoid b.
__global__ __launch_bounds__(256, 2)
void k_gemm_qkvb(const bf16* __restrict__ A, const bf16* __restrict__ B,
                 bf16* __restrict__ qh, bf16* __restrict__ kh,
                 bf16* __restrict__ vh, float* __restrict__ bbuf)
{
  GEMM_PREAMBLE
  GEMM_STAGE(A, B, 0, 0);
  __syncthreads();
  for (int kt = 0; kt < 16; kt++) {
    const int b = kt & 1;
    if (kt < 15) GEMM_STAGE(A, B, kt + 1, b ^ 1);
    GEMM_COMPUTE(b);
    __syncthreads();
  }
#pragma unroll
  for (int fm = 0; fm < 4; fm++)
#pragma unroll
    for (int fn = 0; fn < 4; fn++)
#pragma unroll
      for (int reg = 0; reg < 4; reg++) {
        const int m = m0 + wm * 64 + fm * 16 + lg * 4 + reg;
        const int n = n0 + wn * 64 + fn * 16 + l16;
        if (n >= NQKV) continue;
        const float v = acc[fm][fn][reg];
        const int l = m >> 1, bidx = m & 1;
        const int hd = n / 193;
        const int rem = n - hd * 193;
        const int bhi = bidx * NHEAD + hd;
        const size_t o = ((size_t)bhi * LSEQ + l) * DH;
        if (rem < 64) {
          const int d = rem;
          qh[o + ((((d >> 3) ^ (l & 7)) << 3) | (d & 7))] = f2b(v);
        } else if (rem < 128) {
          const int d = rem - 64;
          kh[o + ((((d >> 3) ^ (l & 7)) << 3) | (d & 7))] = f2b(v);
        } else if (rem < 192) {
          vh[o + rem - 128] = f2b(v);
        } else {
          bbuf[(size_t)bhi * LSEQ + l] = 1.f / (1.f + __expf(-v));
        }
      }
}

// K5a: ao = h + lobf @ WoT^T (f32 out)
__global__ __launch_bounds__(256, 2)
void k_gemm_out(const bf16* __restrict__ A, const bf16* __restrict__ B,
                const float* __restrict__ h, float* __restrict__ ao)
{
  GEMM_PREAMBLE
  GEMM_STAGE(A, B, 0, 0);
  __syncthreads();
  for (int kt = 0; kt < 16; kt++) {
    const int b = kt & 1;
    if (kt < 15) GEMM_STAGE(A, B, kt + 1, b ^ 1);
    GEMM_COMPUTE(b);
    __syncthreads();
  }
#pragma unroll
  for (int fm = 0; fm < 4; fm++)
#pragma unroll
    for (int fn = 0; fn < 4; fn++)
#pragma unroll
      for (int reg = 0; reg < 4; reg++) {
        const int m = m0 + wm * 64 + fm * 16 + lg * 4 + reg;
        const int n = n0 + wn * 64 + fn * 16 + l16;
        const size_t o = (size_t)m * DMODEL + n;
        ao[o] = acc[fm][fn][reg] + h[o];
      }
}

// ---------------------------------------------------------------------------
// K2 (MFMA rewrite): FAVOR+ features. Block = 128 rows x one bh, 4 waves,
// 1 block/CU (99 KB LDS). proj = x_bf16 . (s*pm) with pm in bf16 hi+lo
// (2-pass split compensation; x is exactly bf16, s folded into pm).
// Epilogue: exp/row-sum via shfl_xor over the 16 same-row lanes, then
// normalization folded into the exponent: val = exp(p - hn - lnD) + 1e-4/D.
// ---------------------------------------------------------------------------
__global__ __launch_bounds__(256, 1)
void k_featm(const bf16* __restrict__ qh, const bf16* __restrict__ kh,
             const bf16* __restrict__ pmThi, const bf16* __restrict__ pmTlo,
             bf16* __restrict__ Qp, bf16* __restrict__ Kp)
{
  __shared__ __align__(16) char sPM[2][32768];   // pmT hi, lo [256 n][64 d]
  __shared__ __align__(16) char sX[2][16384];    // q rows, k rows [128][64]
  __shared__ float hnp[2][128];

  const int tid = threadIdx.x, w = tid >> 6, lane = tid & 63;
  const int l16 = lane & 15, lg = lane >> 4;
  const int xs = l16 & 7;
  const int l0 = blockIdx.x * 128, bhi = blockIdx.y;

  // stage pm hi+lo (64 KB) and X q+k (32 KB); all pre-swizzled in global
  {
#pragma unroll
    for (int j = 0; j < 8; j++)
      gl_lds16((const char*)pmThi + (size_t)(w * 8 + j) * 1024 + lane * 16,
               &sPM[0][(w * 8 + j) * 1024]);
#pragma unroll
    for (int j = 0; j < 8; j++)
      gl_lds16((const char*)pmTlo + (size_t)(w * 8 + j) * 1024 + lane * 16,
               &sPM[1][(w * 8 + j) * 1024]);
    const char* qb = (const char*)(qh + ((size_t)bhi * LSEQ + l0) * DH);
    const char* kb = (const char*)(kh + ((size_t)bhi * LSEQ + l0) * DH);
#pragma unroll
    for (int j = 0; j < 4; j++)
      gl_lds16(qb + (size_t)(w * 4 + j) * 1024 + lane * 16, &sX[0][(w * 4 + j) * 1024]);
#pragma unroll
    for (int j = 0; j < 4; j++)
      gl_lds16(kb + (size_t)(w * 4 + j) * 1024 + lane * 16, &sX[1][(w * 4 + j) * 1024]);
  }
  MEMFENCE;
  WAITV(0); BARRIER();

  // hn per row: hn = 0.5*sum(xn^2) = 0.0625*sum(x^2)  (s^2 = 0.125 exact)
  {
    const int r = tid & 127, whh = tid >> 7;
    const char* sxw = sX[whh];
    float a = 0.f;
#pragma unroll
    for (int u = 0; u < 8; u++) {
      const uint4 vv = *(const uint4*)&sxw[r * 128 + ((u ^ (r & 7)) << 4)];
      float f0, f1, f2, f3, f4, f5, f6, f7;
      UNP(vv.x, f0, f1); UNP(vv.y, f2, f3); UNP(vv.z, f4, f5); UNP(vv.w, f6, f7);
      a = fmaf(f0, f0, a); a = fmaf(f1, f1, a); a = fmaf(f2, f2, a); a = fmaf(f3, f3, a);
      a = fmaf(f4, f4, a); a = fmaf(f5, f5, a); a = fmaf(f6, f6, a); a = fmaf(f7, f7, a);
    }
    hnp[whh][r] = a * 0.0625f;
  }
  __syncthreads();

  for (int wh = 0; wh < 2; wh++) {
    bf16* dst = wh ? Kp : Qp;
    const char* sxw = sX[wh];
#pragma unroll
    for (int mt = 0; mt < 2; mt++) {
      const int rowb = w * 32 + mt * 16;
      f32x4 acc[16];
#pragma unroll
      for (int i = 0; i < 16; i++) acc[i] = (f32x4){0.f, 0.f, 0.f, 0.f};
#pragma unroll
      for (int ks = 0; ks < 2; ks++) {
        const bf16x8 a = *(const bf16x8*)&sxw[(rowb + l16) * 128 + (((ks * 4 + lg) ^ xs) << 4)];
#pragma unroll
        for (int nt = 0; nt < 16; nt++) {
          const bf16x8 bh_ = *(const bf16x8*)&sPM[0][(nt * 16 + l16) * 128 + (((ks * 4 + lg) ^ xs) << 4)];
          acc[nt] = MFMA(a, bh_, acc[nt]);
          const bf16x8 bl_ = *(const bf16x8*)&sPM[1][(nt * 16 + l16) * 128 + (((ks * 4 + lg) ^ xs) << 4)];
          acc[nt] = MFMA(a, bl_, acc[nt]);
        }
      }
      // phase 1: raw sums per row (rows lg*4+reg of this m-tile)
      float hn4[4], s4[4];
#pragma unroll
      for (int reg = 0; reg < 4; reg++) {
        hn4[reg] = hnp[wh][rowb + lg * 4 + reg];
        s4[reg] = 0.f;
      }
#pragma unroll
      for (int nt = 0; nt < 16; nt++)
#pragma unroll
        for (int reg = 0; reg < 4; reg++) {
          const float p = acc[nt][reg];
          s4[reg] += __expf(p - hn4[reg]) + __expf(-p - hn4[reg]);
        }
#pragma unroll
      for (int m = 1; m < 16; m <<= 1) {
#pragma unroll
        for (int reg = 0; reg < 4; reg++) s4[reg] += __shfl_xor(s4[reg], m);
      }
      float e4[4], c4[4];
#pragma unroll
      for (int reg = 0; reg < 4; reg++) {
        const float D = s4[reg] + 0.0512f;   // + 512 * 1e-4 (eps terms in sum)
        c4[reg] = 1e-4f / D;
        e4[reg] = hn4[reg] + __logf(D);
      }
      // phase 2: recompute exp with folded normalizer, store swizzled bf16
#pragma unroll
      for (int reg = 0; reg < 4; reg++) {
        const size_t gb = ((size_t)bhi * LSEQ + l0 + rowb + lg * 4 + reg) * PF;
        const int key = (lg * 4 + reg) & 7;   // rowb is a multiple of 16
        const int fl = l16 & 7, fh = l16 >> 3;
#pragma unroll
        for (int nt = 0; nt < 16; nt++) {
          const float p = acc[nt][reg];
          const float ve = __expf(p - e4[reg]) + c4[reg];
          const float vn = __expf(-p - e4[reg]) + c4[reg];
          const int fu = nt * 2 + fh;
          dst[gb + (size_t)(((fu      ) ^ key) << 3) + fl] = f2b(ve);
          dst[gb + (size_t)(((fu + 32) ^ key) << 3) + fl] = f2b(vn);
        }
      }
    }
  }
}

// ---------------------------------------------------------------------------
// K3 (MFMA): per (chunk, bh): S = Kp Kp^T, G = Qp Kp^T via mfma, KpT fused,
// T = (I + tril_strict(diag(b)S))^{-1} diag(b) by 64-lane forward subst.
// ---------------------------------------------------------------------------
__global__ __launch_bounds__(256, 2)
void k_sgsolve(const bf16* __restrict__ Kp, const bf16* __restrict__ Qp,
               const float* __restrict__ bbuf,
               bf16* __restrict__ Gs, bf16* __restrict__ Tm,
               bf16* __restrict__ KpT)
{
  __shared__ __align__(16) char bufK[2][8192];
  __shared__ __align__(16) char bufQ[2][8192];
  __shared__ float sS[CHK][65];
  __shared__ float sT[CHK][65];
  __shared__ float sBeta[CHK];

  const int tid = threadIdx.x, w = tid >> 6, lane = tid & 63;
  const int l16 = lane & 15, lg = lane >> 4;
  const int xs = l16 & 7;
  const int c = blockIdx.x, bhi = blockIdx.y;
  const size_t cb = ((size_t)bhi * LSEQ + (size_t)c * CHK) * PF;
  const size_t rowb = (size_t)bhi * LSEQ + (size_t)c * CHK;
  const size_t ktb = (((size_t)bhi * NCHK + c) * 512) * 64;
  const size_t sb = (((size_t)bhi * NCHK + c) * CHK) * CHK;

  if (tid < CHK) sBeta[tid] = bbuf[rowb + tid];

  f32x4 accS[4], accG[4];
#pragma unroll
  for (int i = 0; i < 4; i++) { accS[i] = (f32x4){0.f,0.f,0.f,0.f}; accG[i] = (f32x4){0.f,0.f,0.f,0.f}; }

#define SG_STAGE(win, b) {                                                     \
  _Pragma("unroll")                                                            \
  for (int j = 0; j < 2; j++) {                                                \
    const int row = w * 16 + j * 8 + (lane >> 3);                              \
    gl_lds16((const char*)(Kp + cb) + (size_t)row * 1024 + (size_t)(win) * 128 + (lane & 7) * 16, \
             &bufK[b][(w * 16 + j * 8) * 128]);                                \
  }                                                                            \
  _Pragma("unroll")                                                            \
  for (int j = 0; j < 2; j++) {                                                \
    const int row = w * 16 + j * 8 + (lane >> 3);                              \
    gl_lds16((const char*)(Qp + cb) + (size_t)row * 1024 + (size_t)(win) * 128 + (lane & 7) * 16, \
             &bufQ[b][(w * 16 + j * 8) * 128]);                                \
  } }

  SG_STAGE(0, 0);
  MEMFENCE;

  for (int win = 0; win < 8; win++) {
    const int b = win & 1;
    if (win < 7) { SG_STAGE(win + 1, b ^ 1); MEMFENCE; }
    if (win == 0)      { WAITV(4); }
    else if (win < 7)  { WAITV(6); }
    else               { WAITV(2); }
    BARRIER();

#pragma unroll
    for (int ks = 0; ks < 2; ks++) {
      const bf16x8 aK = *(const bf16x8*)&bufK[b][(16 * w + l16) * 128 + (((ks * 4 + lg) ^ xs) << 4)];
      const bf16x8 aQ = *(const bf16x8*)&bufQ[b][(16 * w + l16) * 128 + (((ks * 4 + lg) ^ xs) << 4)];
      bf16x8 bK[4];
#pragma unroll
      for (int nt = 0; nt < 4; nt++)
        bK[nt] = *(const bf16x8*)&bufK[b][(nt * 16 + l16) * 128 + (((ks * 4 + lg) ^ xs) << 4)];
#pragma unroll
      for (int nt = 0; nt < 4; nt++) {
        accS[nt] = MFMA(aK, bK[nt], accS[nt]);
        accG[nt] = MFMA(aQ, bK[nt], accG[nt]);
      }
    }

    // KpT emission for this window: KpT[p][l], p = win*64 + pl
#pragma unroll
    for (int jj = 0; jj < 2; jj++) {
      const int idx = jj * 256 + tid;
      const int pl = idx >> 3, l8 = idx & 7;
      unsigned short v[8];
#pragma unroll
      for (int j = 0; j < 8; j++) {
        const int l = l8 * 8 + j;
        v[j] = *(const unsigned short*)&bufK[b][l * 128 + (((pl >> 3) ^ (l & 7)) << 4) + (pl & 7) * 2];
      }
      uint4 o;
      o.x = ((unsigned)v[1] << 16) | v[0];
      o.y = ((unsigned)v[3] << 16) | v[2];
      o.z = ((unsigned)v[5] << 16) | v[4];
      o.w = ((unsigned)v[7] << 16) | v[6];
      const int p = win * 64 + pl;
      *(uint4*)&KpT[ktb + (size_t)p * 64 + ((l8 ^ (p & 7)) << 3)] = o;
    }
    BARRIER();
  }
#undef SG_STAGE

  // epilogue: S -> LDS f32, G -> global (negated strict-upper, swizzled)
#pragma unroll
  for (int nt = 0; nt < 4; nt++)
#pragma unroll
    for (int reg = 0; reg < 4; reg++) {
      const int ri = 16 * w + lg * 4 + reg;
      const int cj = nt * 16 + l16;
      sS[ri][cj] = accS[nt][reg];
      Gs[sb + ri * 64 + (((cj >> 3) ^ (ri & 7)) << 3) + (cj & 7)] =
          f2b((cj > ri) ? -accG[nt][reg] : 0.f);
    }
  __syncthreads();

  if (tid < CHK) {
    const int j = tid;
    for (int i = 0; i < CHK; i++) {
      float acc = (i == j) ? 1.f : 0.f;
      for (int k = 0; k < i; k++) acc = fmaf(-sS[i][k], sT[k][j], acc);
      sT[i][j] = sBeta[i] * acc;
    }
  }
  __syncthreads();
  for (int t = tid; t < CHK * CHK; t += 256) {
    const int r = t >> 6, ccj = t & 63;
    Tm[sb + r * 64 + (((ccj >> 3) ^ (r & 7)) << 3) + (ccj & 7)] = f2b(sT[r][ccj]);
  }
}

// ---------------------------------------------------------------------------
// K4: MFMA chunk scan (unchanged; verified in rounds 3-5)
// ---------------------------------------------------------------------------
__global__ __launch_bounds__(256, 1)
void k_scan(const bf16* __restrict__ Kp, const bf16* __restrict__ Qp,
            const bf16* __restrict__ vh, const bf16* __restrict__ Tm,
            const bf16* __restrict__ Gs, const bf16* __restrict__ KpT,
            bf16* __restrict__ lobf)
{
  __shared__ __align__(16) char sb[2][65536];   // dbuf: Kp / KpT / Qp
  __shared__ __align__(16) char sWT[16384];     // WT[d=16][p=512] bf16, xor-swz
  __shared__ __align__(16) char sTG[8192];      // T then Gs (producer-swz)
  __shared__ __align__(16) char sUT[2048];      // U^T[d=16][l=64] bf16, xor-swz
  __shared__ __align__(16) char suP[2048];      // upre^T, same layout

  const int tid = threadIdx.x;
  const int w = tid >> 6, lane = tid & 63;
  const int l16 = lane & 15, lg = lane >> 4;
  const int bhi = blockIdx.x & 31, dq = blockIdx.x >> 5;
  const int bidx = bhi >> 4, hd = bhi & 15;
  const int xs = l16 & 7;                       // xor key

  for (int i = tid; i < 4096; i += 256) ((unsigned*)sWT)[i] = 0u;

  f32x4 Wacc[8];
#pragma unroll
  for (int i = 0; i < 8; i++) Wacc[i] = (f32x4){0.f, 0.f, 0.f, 0.f};

  const size_t bh_base = (size_t)bhi * LSEQ * PF;
  const size_t tg0 = ((size_t)bhi * NCHK) * 4096;
  const size_t kt0 = ((size_t)bhi * NCHK) * (512 * 64);

  // prologue: stage Kp(0) into sb[0]
  {
    const char* g = (const char*)(Kp + bh_base);
#pragma unroll
    for (int j = 0; j < 16; j++)
      gl_lds16(g + (w * 16 + j) * 1024 + lane * 16, &sb[0][(w * 16 + j) * 1024]);
  }
  MEMFENCE;
  WAITLGKM; BARRIER();   // sWT zeros visible

  int cur = 0;
  for (int c = 0; c < NCHK; c++) {
    BARRIER();  // B0: prev-iter readers of sb/sTG/sUT done

    const size_t cb = bh_base + (size_t)c * CHK * PF;
    const char* TmC  = (const char*)(Tm + tg0 + (size_t)c * 4096);
    const char* GsC  = (const char*)(Gs + tg0 + (size_t)c * 4096);
    const char* KpTC = (const char*)(KpT + kt0 + (size_t)c * (512 * 64));
    const char* QpC  = (const char*)(Qp + cb);
    const char* KpN  = (const char*)(Kp + cb + CHK * PF);

    // V (compiler-managed waits)
    const bf16* vp = vh + ((size_t)bhi * LSEQ + c * 64 + w * 16 + lg * 4) * 64 + dq * 16 + l16;
    const float v0 = b2f(vp[0]),   v1 = b2f(vp[64]);
    const float v2 = b2f(vp[128]), v3 = b2f(vp[192]);
    MEMFENCE;
    // stage T(c) -> sTG
#pragma unroll
    for (int j = 0; j < 2; j++)
      gl_lds16(TmC + (w * 2 + j) * 1024 + lane * 16, &sTG[(w * 2 + j) * 1024]);
    MEMFENCE;
    // stage KpT(c) -> sb[cur^1]
#pragma unroll
    for (int j = 0; j < 16; j++)
      gl_lds16(KpTC + (w * 16 + j) * 1024 + lane * 16, &sb[cur ^ 1][(w * 16 + j) * 1024]);
    MEMFENCE;
    WAITV(22);  // Kp(c) ready

    // ---- upre = V - Kp*W(old) ----
    f32x4 a0v = (f32x4){0.f,0.f,0.f,0.f}, a1v = (f32x4){0.f,0.f,0.f,0.f};
#pragma unroll
    for (int ks = 0; ks < 16; ks += 2) {
      const bf16x8 aa0 = *(const bf16x8*)&sb[cur][(16 * w + l16) * 1024 + ((((ks    ) * 4 + lg) ^ xs) << 4)];
      const bf16x8 bb0 = *(const bf16x8*)&sWT[l16 * 1024 + ((((ks    ) * 4 + lg) ^ xs) << 4)];
      a0v = MFMA(aa0, bb0, a0v);
      const bf16x8 aa1 = *(const bf16x8*)&sb[cur][(16 * w + l16) * 1024 + ((((ks + 1) * 4 + lg) ^ xs) << 4)];
      const bf16x8 bb1 = *(const bf16x8*)&sWT[l16 * 1024 + ((((ks + 1) * 4 + lg) ^ xs) << 4)];
      a1v = MFMA(aa1, bb1, a1v);
    }
    {
      const int l0r = 16 * w + lg * 4;
      const unsigned plo = pkbf(v0 - (a0v[0] + a1v[0]), v1 - (a0v[1] + a1v[1]));
      const unsigned phi = pkbf(v2 - (a0v[2] + a1v[2]), v3 - (a0v[3] + a1v[3]));
      *(uint2*)&suP[l16 * 128 + ((((l0r >> 3)) ^ xs) << 4) + (l0r & 7) * 2] = make_uint2(plo, phi);
    }
    WAITLGKM; BARRIER();  // B1: suP ready
    WAITV(16);            // T ready

    // ---- U = T * upre ----
    {
      f32x4 ua = (f32x4){0.f,0.f,0.f,0.f};
#pragma unroll
      for (int ks = 0; ks < 2; ks++) {
        const bf16x8 aa = *(const bf16x8*)&sTG[(16 * w + l16) * 128 + (((ks * 4 + lg) ^ xs) << 4)];
        const bf16x8 bb = *(const bf16x8*)&suP[l16 * 128 + (((ks * 4 + lg) ^ xs) << 4)];
        ua = MFMA(aa, bb, ua);
      }
      const int l0r = 16 * w + lg * 4;
      *(uint2*)&sUT[l16 * 128 + ((((l0r >> 3)) ^ xs) << 4) + (l0r & 7) * 2] =
          make_uint2(pkbf(ua[0], ua[1]), pkbf(ua[2], ua[3]));
    }
    WAITLGKM; BARRIER();  // B2: sUT ready

    // stage Qp(c) -> sb[cur]
#pragma unroll
    for (int j = 0; j < 16; j++)
      gl_lds16(QpC + (w * 16 + j) * 1024 + lane * 16, &sb[cur][(w * 16 + j) * 1024]);
    MEMFENCE;
    WAITV(16);            // KpT ready

    // ---- W += KpT * U ----
    {
      bf16x8 bu[2];
#pragma unroll
      for (int ks = 0; ks < 2; ks++)
        bu[ks] = *(const bf16x8*)&sUT[l16 * 128 + (((ks * 4 + lg) ^ xs) << 4)];
#pragma unroll
      for (int mt = 0; mt < 8; mt++) {
        const int p = w * 128 + mt * 16 + l16;
#pragma unroll
        for (int ks = 0; ks < 2; ks++) {
          const bf16x8 aa = *(const bf16x8*)&sb[cur ^ 1][p * 128 + (((ks * 4 + lg) ^ xs) << 4)];
          Wacc[mt] = MFMA(aa, bu[ks], Wacc[mt]);
        }
      }
#pragma unroll
      for (int mt = 0; mt < 8; mt++) {
        const int p0m = w * 128 + mt * 16 + lg * 4;
        *(uint2*)&sWT[l16 * 1024 + ((((p0m >> 3)) ^ xs) << 4) + (p0m & 7) * 2] =
            make_uint2(pkbf(Wacc[mt][0], Wacc[mt][1]), pkbf(Wacc[mt][2], Wacc[mt][3]));
      }
    }
    WAITLGKM; BARRIER();  // B3: sWT(new) ready

    // stage Gs(c) -> sTG ; prefetch Kp(c+1) -> sb[cur^1]
#pragma unroll
    for (int j = 0; j < 2; j++)
      gl_lds16(GsC + (w * 2 + j) * 1024 + lane * 16, &sTG[(w * 2 + j) * 1024]);
    MEMFENCE;
    if (c < NCHK - 1) {
#pragma unroll
      for (int j = 0; j < 16; j++)
        gl_lds16(KpN + (w * 16 + j) * 1024 + lane * 16, &sb[cur ^ 1][(w * 16 + j) * 1024]);
    }
    MEMFENCE;
    if (c < NCHK - 1) { WAITV(18); } else { WAITV(2); }   // Qp ready

    // ---- out = 0.125 * (Qp*W_new - Gs*U) ----
    f32x4 o0 = (f32x4){0.f,0.f,0.f,0.f}, o1 = (f32x4){0.f,0.f,0.f,0.f};
#pragma unroll
    for (int ks = 0; ks < 16; ks += 2) {
      const bf16x8 aa0 = *(const bf16x8*)&sb[cur][(16 * w + l16) * 1024 + ((((ks    ) * 4 + lg) ^ xs) << 4)];
      const bf16x8 bb0 = *(const bf16x8*)&sWT[l16 * 1024 + ((((ks    ) * 4 + lg) ^ xs) << 4)];
      o0 = MFMA(aa0, bb0, o0);
      const bf16x8 aa1 = *(const bf16x8*)&sb[cur][(16 * w + l16) * 1024 + ((((ks + 1) * 4 + lg) ^ xs) << 4)];
      const bf16x8 bb1 = *(const bf16x8*)&sWT[l16 * 1024 + ((((ks + 1) * 4 + lg) ^ xs) << 4)];
      o1 = MFMA(aa1, bb1, o1);
    }
    if (c < NCHK - 1) { WAITV(16); } else { WAITV(0); }   // Gs ready
#pragma unroll
    for (int ks = 0; ks < 2; ks++) {
      const bf16x8 aa = *(const bf16x8*)&sTG[(16 * w + l16) * 128 + (((ks * 4 + lg) ^ xs) << 4)];
      const bf16x8 bb = *(const bf16x8*)&sUT[l16 * 128 + (((ks * 4 + lg) ^ xs) << 4)];
      o0 = MFMA(aa, bb, o0);   // Gs pre-negated by producer
    }
    {
      const int colb = hd * 64 + dq * 16 + l16;
#pragma unroll
      for (int reg = 0; reg < 4; reg++) {
        const int l = c * 64 + 16 * w + lg * 4 + reg;
        const int r = l * BSZN + bidx;
        const int cp = (colb & ~63) | ((((colb >> 3) & 7) ^ (r & 7)) << 3) | (colb & 7);
        lobf[(size_t)r * DMODEL + cp] = f2b(0.125f * (o0[reg] + o1[reg]));
      }
    }
    cur ^= 1;
  }
}

// ---------------------------------------------------------------------------
// K5b: LayerNorm (unchanged)
// ---------------------------------------------------------------------------
__global__ __launch_bounds__(256)
void k_ln(const float* __restrict__ ao, const float* __restrict__ gamma,
          const float* __restrict__ beta, float* __restrict__ out)
{
  const int row = blockIdx.x;
  const int tid = threadIdx.x;
  __shared__ float r1[4], r2[4];
  const float4 v = *(const float4*)&ao[(size_t)row * DMODEL + tid * 4];
  float s1 = v.x + v.y + v.z + v.w;
  float s2 = v.x * v.x + v.y * v.y + v.z * v.z + v.w * v.w;
  for (int off = 32; off > 0; off >>= 1) {
    s1 += __shfl_down(s1, off);
    s2 += __shfl_down(s2, off);
  }
  if ((tid & 63) == 0) { r1[tid >> 6] = s1; r2[tid >> 6] = s2; }
  __syncthreads();
  const float ts1 = r1[0] + r1[1] + r1[2] + r1[3];
  const float ts2 = r2[0] + r2[1] + r2[2] + r2[3];
  const float mu = ts1 * (1.f / DMODEL);
  const float var = ts2 * (1.f / DMODEL) - mu * mu;
  const float rs = rsqrtf(var + 1e-5f);
  const float4 g = *(const float4*)&gamma[tid * 4];
  const float4 b = *(const float4*)&beta[tid * 4];
  float4 o;
  o.x = (v.x - mu) * rs * g.x + b.x;
  o.y = (v.y - mu) * rs * g.y + b.y;
  o.z = (v.z - mu) * rs * g.z + b.z;
  o.w = (v.w - mu) * rs * g.w + b.w;
  *(float4*)&out[(size_t)row * DMODEL + tid * 4] = o;
}

// ---------------------------------------------------------------------------
extern "C" void kernel_launch(void* const* d_in, const int* in_sizes, int n_in,
                              void* d_out, int out_size, void* d_ws, size_t ws_size,
                              hipStream_t stream)
{
  (void)in_sizes; (void)n_in; (void)out_size; (void)ws_size;
  const float* h   = (const float*)d_in[0];
  const float* Wq  = (const float*)d_in[1];
  const float* Wo  = (const float*)d_in[2];
  const float* gam = (const float*)d_in[3];
  const float* bet = (const float*)d_in[4];
  const float* pm  = (const float*)d_in[5];
  float* out = (float*)d_out;

  char* ws = (char*)d_ws;
  size_t off = 0;
  auto alloc = [&](size_t bytes) -> void* {
    void* p = ws + off;
    off += (bytes + 255) & ~(size_t)255;
    return p;
  };
  // total workspace ~= 229 MB
  bf16*  vh  = (bf16*)alloc((size_t)BHN * LSEQ * DH * 2);            //  8.4 MB
  float* bbf = (float*)alloc((size_t)BHN * LSEQ * 4);                //  0.3 MB
  bf16*  Kp  = (bf16*)alloc((size_t)BHN * LSEQ * PF * 2);            // 67.1 MB
  bf16*  Qp  = (bf16*)alloc((size_t)BHN * LSEQ * PF * 2);            // 67.1 MB
  bf16*  Tm  = (bf16*)alloc((size_t)BHN * NCHK * CHK * CHK * 2);     //  8.4 MB
  bf16*  Gs  = (bf16*)alloc((size_t)BHN * NCHK * CHK * CHK * 2);     //  8.4 MB
  char*  R   = (char*)alloc((size_t)BHN * NCHK * 512 * 64 * 2);      // 67.1 MB shared
  bf16*  WoT = (bf16*)alloc((size_t)DMODEL * DMODEL * 2);            //  2.1 MB
  bf16*  pmThi = (bf16*)alloc((size_t)MPROJ * 64 * 2);               // 32 KB
  bf16*  pmTlo = (bf16*)alloc((size_t)MPROJ * 64 * 2);               // 32 KB
  // region R lifetimes:
  //  phase1 (cvt/qkvb/featm): qh(8.4) | kh(8.4) | hbf(8.4) | WqT(6.6)
  //  phase2 (sgsolve/scan):   KpT (67.1)
  //  phase3 (outgemm/ln):     ao (16.8 f32)
  bf16*  qh  = (bf16*)R;
  bf16*  kh  = (bf16*)(R + (size_t)BHN * LSEQ * DH * 2);
  bf16*  hbf = (bf16*)(R + (size_t)2 * BHN * LSEQ * DH * 2);
  bf16*  WqT = (bf16*)(R + (size_t)3 * BHN * LSEQ * DH * 2);
  bf16*  KpT = (bf16*)R;
  float* ao  = (float*)R;
  bf16*  lobf = (bf16*)d_out;   // d_out scratch; fully rewritten by k_ln

  k_cvth     <<<dim3(2048),                       256, 0, stream>>>(h, hbf);
  k_cvtw     <<<dim3(NQPAD / 64, 16),             256, 0, stream>>>(Wq, WqT, NQKV);
  k_cvtw     <<<dim3(DMODEL / 64, 16),            256, 0, stream>>>(Wo, WoT, DMODEL);
  k_cvtpm    <<<dim3(1),                          256, 0, stream>>>(pm, pmThi, pmTlo);
  k_gemm_qkvb<<<dim3(NQPAD / 128, 4096 / 128),    256, 0, stream>>>(hbf, WqT, qh, kh, vh, bbf);
  k_featm    <<<dim3(LSEQ / 128, BHN),            256, 0, stream>>>(qh, kh, pmThi, pmTlo, Qp, Kp);
  k_sgsolve  <<<dim3(NCHK, BHN),                  256, 0, stream>>>(Kp, Qp, bbf, Gs, Tm, KpT);
  k_scan     <<<dim3(128),                        256, 0, stream>>>(Kp, Qp, vh, Tm, Gs, KpT, lobf);
  k_gemm_out <<<dim3(DMODEL / 128, 4096 / 128),   256, 0, stream>>>(lobf, WoT, h, ao);
  k_ln       <<<dim3(4096),                       256, 0, stream>>>(ao, gam, bet, out);
}

// Round 7
// 398.274 us; speedup vs baseline: 4.2236x; 1.1959x over previous
//
#include <hip/hip_runtime.h>
#include <hip/hip_bf16.h>

// Problem constants (from reference)
#define LSEQ   2048
#define BSZN   2
#define DMODEL 1024
#define NHEAD  16
#define DH     64
#define MPROJ  256
#define PF     512   // 2*MPROJ feature dim
#define CHK    64    // chunk length
#define NCHK   32    // LSEQ/CHK
#define BHN    32    // BSZN*NHEAD
#define NQKV   3088  // NHEAD*(3*DH+1)
#define NQPAD  3200  // NQKV padded to 25*128

typedef __hip_bfloat16 bf16;
typedef short bf16x8 __attribute__((ext_vector_type(8)));
typedef float f32x4 __attribute__((ext_vector_type(4)));

#define MFMA(a, b, c) __builtin_amdgcn_mfma_f32_16x16x32_bf16(a, b, c, 0, 0, 0)

// unpack a u32 holding two bf16 (little-endian: low half = first element)
#define UNP(u, a, b) { a = __uint_as_float((unsigned)(u) << 16); b = __uint_as_float((unsigned)(u) & 0xffff0000u); }

static __device__ __forceinline__ float b2f(bf16 x) {
  unsigned short us = *(unsigned short*)&x;
  return __uint_as_float((unsigned)us << 16);
}
static __device__ __forceinline__ bf16 f2b(float x) { return __float2bfloat16(x); }
static __device__ __forceinline__ unsigned pkbf(float a, float b) {
  bf16 x = __float2bfloat16(a), y = __float2bfloat16(b);
  return ((unsigned)(*(unsigned short*)&y) << 16) | (unsigned)(*(unsigned short*)&x);
}

// async global->LDS, 16B per lane. gsrc is PER-LANE; ldst wave-uniform base.
static __device__ __forceinline__ void gl_lds16(const void* gsrc, void* ldst) {
  __builtin_amdgcn_global_load_lds(
      (const __attribute__((address_space(1))) unsigned int*)gsrc,
      (__attribute__((address_space(3))) unsigned int*)ldst, 16, 0, 0);
}

#define MEMFENCE asm volatile("" ::: "memory")
#define WAITV(n) asm volatile("s_waitcnt vmcnt(" #n ")" ::: "memory")
#define WAITLGKM asm volatile("s_waitcnt lgkmcnt(0)" ::: "memory")
#define BARRIER() __builtin_amdgcn_s_barrier()

// ---------------------------------------------------------------------------
// K0a: h (f32) -> hbf (bf16), pre-swizzled: within each 64-elem group, 16B
// unit u stored at u ^ (row&7).
// ---------------------------------------------------------------------------
__global__ __launch_bounds__(256)
void k_cvth(const float* __restrict__ h, bf16* __restrict__ hbf)
{
  const int gt = blockIdx.x * 256 + threadIdx.x;   // unit id, 4096*128 total
  const int r = gt >> 7, ug = gt & 127;
  const int grp = ug >> 3, u = ug & 7;
  const float4 f0 = *(const float4*)&h[(size_t)r * 1024 + grp * 64 + u * 8];
  const float4 f1 = *(const float4*)&h[(size_t)r * 1024 + grp * 64 + u * 8 + 4];
  uint4 o;
  o.x = pkbf(f0.x, f0.y); o.y = pkbf(f0.z, f0.w);
  o.z = pkbf(f1.x, f1.y); o.w = pkbf(f1.z, f1.w);
  *(uint4*)&hbf[(size_t)r * 1024 + grp * 64 + ((u ^ (r & 7)) << 3)] = o;
}

// ---------------------------------------------------------------------------
// K0b: W [1024][nsrc] f32 -> WT [gridDim.x*64][1024] bf16 transposed,
// pre-swizzled, zero-padded rows beyond nsrc.
// ---------------------------------------------------------------------------
__global__ __launch_bounds__(256)
void k_cvtw(const float* __restrict__ W, bf16* __restrict__ WT, int nsrc)
{
  __shared__ float sT[64][65];
  const int tid = threadIdx.x;
  const int n0 = blockIdx.x * 64, k0 = blockIdx.y * 64;
#pragma unroll
  for (int j = 0; j < 16; j++) {
    const int e = j * 256 + tid;
    const int r = e >> 6, c = e & 63;
    sT[r][c] = (n0 + c < nsrc) ? W[(size_t)(k0 + r) * nsrc + n0 + c] : 0.f;
  }
  __syncthreads();
#pragma unroll
  for (int j = 0; j < 2; j++) {
    const int uid = j * 256 + tid;
    const int rp = uid >> 3, u = uid & 7;
    uint4 o;
    o.x = pkbf(sT[u * 8 + 0][rp], sT[u * 8 + 1][rp]);
    o.y = pkbf(sT[u * 8 + 2][rp], sT[u * 8 + 3][rp]);
    o.z = pkbf(sT[u * 8 + 4][rp], sT[u * 8 + 5][rp]);
    o.w = pkbf(sT[u * 8 + 6][rp], sT[u * 8 + 7][rp]);
    *(uint4*)&WT[(size_t)(n0 + rp) * 1024 + k0 + ((u ^ (rp & 7)) << 3)] = o;
  }
}

// ---------------------------------------------------------------------------
// K0c: pm [64][256] f32 -> pmT hi/lo [256 n][64 d] bf16 (split compensation),
// scaled by 64^-0.25 = 2^-1.5, transposed, row-swizzled (key n&7).
// ---------------------------------------------------------------------------
__global__ __launch_bounds__(256)
void k_cvtpm(const float* __restrict__ pm, bf16* __restrict__ pmThi,
             bf16* __restrict__ pmTlo)
{
  const int n = threadIdx.x;
  float v[64];
#pragma unroll
  for (int d = 0; d < 64; d++) v[d] = pm[d * MPROJ + n] * 0.35355339059327373f;
  const int key = n & 7;
#pragma unroll
  for (int u = 0; u < 8; u++) {
    unsigned hi[4], lo[4];
#pragma unroll
    for (int j = 0; j < 4; j++) {
      const float a = v[u * 8 + j * 2], b = v[u * 8 + j * 2 + 1];
      const bf16 ah = f2b(a), bh_ = f2b(b);
      const float ar = a - b2f(ah), br = b - b2f(bh_);
      hi[j] = ((unsigned)(*(const unsigned short*)&bh_) << 16) | (unsigned)(*(const unsigned short*)&ah);
      const bf16 al = f2b(ar), bl = f2b(br);
      lo[j] = ((unsigned)(*(const unsigned short*)&bl) << 16) | (unsigned)(*(const unsigned short*)&al);
    }
    *(uint4*)&pmThi[(size_t)n * 64 + ((u ^ key) << 3)] = make_uint4(hi[0], hi[1], hi[2], hi[3]);
    *(uint4*)&pmTlo[(size_t)n * 64 + ((u ^ key) << 3)] = make_uint4(lo[0], lo[1], lo[2], lo[3]);
  }
}

// ---------------------------------------------------------------------------
// MFMA GEMM core: C[128m x 128n] tile, BK=64, 4 waves (2x2), double-buffered
// global_load_lds staging, xor-swizzled LDS reads (sources pre-swizzled).
// ---------------------------------------------------------------------------
#define GEMM_STAGE(Abase, Bbase, kt, b) {                                      \
  const size_t kb = (size_t)(kt) * 128;   /* byte offset of k-window */        \
  _Pragma("unroll")                                                            \
  for (int j = 0; j < 4; j++) {                                                \
    const int row = (w * 4 + j) * 8 + (lane >> 3);                             \
    gl_lds16((const char*)(Abase) + (size_t)(m0 + row) * 2048 + kb + (lane & 7) * 16, \
             &sA[b][(w * 4 + j) * 1024]);                                      \
  }                                                                            \
  _Pragma("unroll")                                                            \
  for (int j = 0; j < 4; j++) {                                                \
    const int row = (w * 4 + j) * 8 + (lane >> 3);                             \
    gl_lds16((const char*)(Bbase) + (size_t)(n0 + row) * 2048 + kb + (lane & 7) * 16, \
             &sB[b][(w * 4 + j) * 1024]);                                      \
  } }

#define GEMM_COMPUTE(b) {                                                      \
  _Pragma("unroll")                                                            \
  for (int ks = 0; ks < 2; ks++) {                                             \
    bf16x8 af[4], bfr[4];                                                      \
    _Pragma("unroll")                                                          \
    for (int f = 0; f < 4; f++) {                                              \
      const int row = wm * 64 + f * 16 + l16;                                  \
      af[f] = *(const bf16x8*)&sA[b][row * 128 + (((ks * 4 + lg) ^ xs) << 4)]; \
    }                                                                          \
    _Pragma("unroll")                                                          \
    for (int f = 0; f < 4; f++) {                                              \
      const int row = wn * 64 + f * 16 + l16;                                  \
      bfr[f] = *(const bf16x8*)&sB[b][row * 128 + (((ks * 4 + lg) ^ xs) << 4)]; \
    }                                                                          \
    _Pragma("unroll")                                                          \
    for (int fm = 0; fm < 4; fm++)                                             \
      _Pragma("unroll")                                                        \
      for (int fn = 0; fn < 4; fn++)                                           \
        acc[fm][fn] = MFMA(af[fm], bfr[fn], acc[fm][fn]);                      \
  } }

#define GEMM_PREAMBLE                                                          \
  __shared__ __align__(16) char sA[2][16384];                                  \
  __shared__ __align__(16) char sB[2][16384];                                  \
  const int tid = threadIdx.x, w = tid >> 6, lane = tid & 63;                  \
  const int l16 = lane & 15, lg = lane >> 4;                                   \
  const int wm = w >> 1, wn = w & 1;                                           \
  const int m0 = blockIdx.y * 128, n0 = blockIdx.x * 128;                      \
  const int xs = l16 & 7;                                                      \
  f32x4 acc[4][4];                                                             \
  _Pragma("unroll")                                                            \
  for (int i = 0; i < 4; i++)                                                  \
    _Pragma("unroll")                                                          \
    for (int j = 0; j < 4; j++) acc[i][j] = (f32x4){0.f, 0.f, 0.f, 0.f};

// K1: qkvb = hbf @ WqT^T, epilogue scatters to qh/kh (bf16, PRE-SWIZZLED for
// featm staging), vh (bf16, linear) + sigmoid b.
__global__ __launch_bounds__(256, 2)
void k_gemm_qkvb(const bf16* __restrict__ A, const bf16* __restrict__ B,
                 bf16* __restrict__ qh, bf16* __restrict__ kh,
                 bf16* __restrict__ vh, float* __restrict__ bbuf)
{
  GEMM_PREAMBLE
  GEMM_STAGE(A, B, 0, 0);
  __syncthreads();
  for (int kt = 0; kt < 16; kt++) {
    const int b = kt & 1;
    if (kt < 15) GEMM_STAGE(A, B, kt + 1, b ^ 1);
    GEMM_COMPUTE(b);
    __syncthreads();
  }
#pragma unroll
  for (int fm = 0; fm < 4; fm++)
#pragma unroll
    for (int fn = 0; fn < 4; fn++)
#pragma unroll
      for (int reg = 0; reg < 4; reg++) {
        const int m = m0 + wm * 64 + fm * 16 + lg * 4 + reg;
        const int n = n0 + wn * 64 + fn * 16 + l16;
        if (n >= NQKV) continue;
        const float v = acc[fm][fn][reg];
        const int l = m >> 1, bidx = m & 1;
        const int hd = n / 193;
        const int rem = n - hd * 193;
        const int bhi = bidx * NHEAD + hd;
        const size_t o = ((size_t)bhi * LSEQ + l) * DH;
        if (rem < 64) {
          const int d = rem;
          qh[o + ((((d >> 3) ^ (l & 7)) << 3) | (d & 7))] = f2b(v);
        } else if (rem < 128) {
          const int d = rem - 64;
          kh[o + ((((d >> 3) ^ (l & 7)) << 3) | (d & 7))] = f2b(v);
        } else if (rem < 192) {
          vh[o + rem - 128] = f2b(v);
        } else {
          bbuf[(size_t)bhi * LSEQ + l] = 1.f / (1.f + __expf(-v));
        }
      }
}

// K5a: ao = h + lobf @ WoT^T (f32 out)
__global__ __launch_bounds__(256, 2)
void k_gemm_out(const bf16* __restrict__ A, const bf16* __restrict__ B,
                const float* __restrict__ h, float* __restrict__ ao)
{
  GEMM_PREAMBLE
  GEMM_STAGE(A, B, 0, 0);
  __syncthreads();
  for (int kt = 0; kt < 16; kt++) {
    const int b = kt & 1;
    if (kt < 15) GEMM_STAGE(A, B, kt + 1, b ^ 1);
    GEMM_COMPUTE(b);
    __syncthreads();
  }
#pragma unroll
  for (int fm = 0; fm < 4; fm++)
#pragma unroll
    for (int fn = 0; fn < 4; fn++)
#pragma unroll
      for (int reg = 0; reg < 4; reg++) {
        const int m = m0 + wm * 64 + fm * 16 + lg * 4 + reg;
        const int n = n0 + wn * 64 + fn * 16 + l16;
        const size_t o = (size_t)m * DMODEL + n;
        ao[o] = acc[fm][fn][reg] + h[o];
      }
}

// ---------------------------------------------------------------------------
// K2 v2: FAVOR+ features, orientation-B MFMA (A = pmT, B = x rows): each lane
// owns ONE seq row (col of C) and 64 proj values -> row-sum = 2 shfl_xor,
// stores are uint2 (4 consecutive n). 64 rows/block, LDS 72 KB -> 2 blocks/CU.
// sched_barrier(0) per store group caps live registers (round-6 spill fix).
// ---------------------------------------------------------------------------
__global__ __launch_bounds__(256, 2)
void k_featm(const bf16* __restrict__ qh, const bf16* __restrict__ kh,
             const bf16* __restrict__ pmThi, const bf16* __restrict__ pmTlo,
             bf16* __restrict__ Qp, bf16* __restrict__ Kp)
{
  __shared__ __align__(16) char sPM[2][32768];   // pmT hi, lo [256 n][64 d]
  __shared__ __align__(16) char sX[8192];        // 64 rows x 128 B (q, then k)

  const int tid = threadIdx.x, w = tid >> 6, lane = tid & 63;
  const int l16 = lane & 15, lg = lane >> 4;
  const int xs = l16 & 7;
  const int l0 = blockIdx.x * 64, bhi = blockIdx.y;

  // prologue staging: pm hi+lo (64 KB) + q rows (8 KB); sources pre-swizzled
#pragma unroll
  for (int j = 0; j < 8; j++)
    gl_lds16((const char*)pmThi + (size_t)(w * 8 + j) * 1024 + lane * 16,
             &sPM[0][(w * 8 + j) * 1024]);
#pragma unroll
  for (int j = 0; j < 8; j++)
    gl_lds16((const char*)pmTlo + (size_t)(w * 8 + j) * 1024 + lane * 16,
             &sPM[1][(w * 8 + j) * 1024]);
  {
    const char* qb = (const char*)(qh + ((size_t)bhi * LSEQ + l0) * DH);
#pragma unroll
    for (int j = 0; j < 2; j++)
      gl_lds16(qb + (size_t)(w * 2 + j) * 1024 + lane * 16, &sX[(w * 2 + j) * 1024]);
  }
  MEMFENCE;
  WAITV(0); BARRIER();

  const int srow = w * 16 + l16;                 // seq row in block (per lane)
  const size_t gsr = (size_t)bhi * LSEQ + l0 + srow;

  for (int wh = 0; wh < 2; wh++) {
    bf16* dst = wh ? Kp : Qp;

    // hn = 0.0625 * sum(x^2): each lane 2 stored units of its row + butterfly
    float hn;
    {
      const char* xrow = &sX[srow * 128];
      const uint4 a0 = *(const uint4*)&xrow[lg * 32];
      const uint4 a1 = *(const uint4*)&xrow[lg * 32 + 16];
      float f0, f1, f2, f3, f4, f5, f6, f7, a = 0.f;
      UNP(a0.x, f0, f1); UNP(a0.y, f2, f3); UNP(a0.z, f4, f5); UNP(a0.w, f6, f7);
      a = fmaf(f0, f0, a); a = fmaf(f1, f1, a); a = fmaf(f2, f2, a); a = fmaf(f3, f3, a);
      a = fmaf(f4, f4, a); a = fmaf(f5, f5, a); a = fmaf(f6, f6, a); a = fmaf(f7, f7, a);
      UNP(a1.x, f0, f1); UNP(a1.y, f2, f3); UNP(a1.z, f4, f5); UNP(a1.w, f6, f7);
      a = fmaf(f0, f0, a); a = fmaf(f1, f1, a); a = fmaf(f2, f2, a); a = fmaf(f3, f3, a);
      a = fmaf(f4, f4, a); a = fmaf(f5, f5, a); a = fmaf(f6, f6, a); a = fmaf(f7, f7, a);
      a += __shfl_xor(a, 16); a += __shfl_xor(a, 32);
      hn = a * 0.0625f;
    }

    // proj via MFMA: C rows = proj n (pmT), C cols = seq (x)
    f32x4 acc[16];
#pragma unroll
    for (int i = 0; i < 16; i++) acc[i] = (f32x4){0.f, 0.f, 0.f, 0.f};
#pragma unroll
    for (int ks = 0; ks < 2; ks++) {
      const bf16x8 bx = *(const bf16x8*)&sX[srow * 128 + (((ks * 4 + lg) ^ xs) << 4)];
#pragma unroll
      for (int mt = 0; mt < 16; mt++) {
        const bf16x8 ah = *(const bf16x8*)&sPM[0][(mt * 16 + l16) * 128 + (((ks * 4 + lg) ^ xs) << 4)];
        acc[mt] = MFMA(ah, bx, acc[mt]);
        const bf16x8 al = *(const bf16x8*)&sPM[1][(mt * 16 + l16) * 128 + (((ks * 4 + lg) ^ xs) << 4)];
        acc[mt] = MFMA(al, bx, acc[mt]);
      }
    }

    if (wh == 0) {
      BARRIER();   // all waves done reading sX(q); restage with k (async)
      const char* kb = (const char*)(kh + ((size_t)bhi * LSEQ + l0) * DH);
#pragma unroll
      for (int j = 0; j < 2; j++)
        gl_lds16(kb + (size_t)(w * 2 + j) * 1024 + lane * 16, &sX[(w * 2 + j) * 1024]);
      MEMFENCE;
    }

    // phase 1: full row-sum (lane has 64 of 256 n; butterfly over lg)
    float ss = 0.f;
#pragma unroll
    for (int mt = 0; mt < 16; mt++)
#pragma unroll
      for (int r = 0; r < 4; r++) {
        const float p = acc[mt][r];
        ss += __expf(p - hn) + __expf(-p - hn);
      }
    ss += __shfl_xor(ss, 16); ss += __shfl_xor(ss, 32);
    const float D = ss + 0.0512f;        // + 512 * 1e-4 eps terms
    const float cc = 1e-4f / D;
    const float eo = hn + __logf(D);

    // phase 2: recompute with folded normalizer; uint2 stores, swizzled
    const size_t gb = gsr * PF;
    const int half = (lg & 1) * 4;
    const int ub = lg >> 1;
#pragma unroll
    for (int mt = 0; mt < 16; mt++) {
      const float v0 = __expf(acc[mt][0] - eo) + cc;
      const float v1 = __expf(acc[mt][1] - eo) + cc;
      const float v2 = __expf(acc[mt][2] - eo) + cc;
      const float v3 = __expf(acc[mt][3] - eo) + cc;
      const float n0 = __expf(-acc[mt][0] - eo) + cc;
      const float n1 = __expf(-acc[mt][1] - eo) + cc;
      const float n2 = __expf(-acc[mt][2] - eo) + cc;
      const float n3 = __expf(-acc[mt][3] - eo) + cc;
      const int u = mt * 2 + ub;
      *(uint2*)&dst[gb + ((u ^ xs) << 3) + half] = make_uint2(pkbf(v0, v1), pkbf(v2, v3));
      *(uint2*)&dst[gb + (((u + 32) ^ xs) << 3) + half] = make_uint2(pkbf(n0, n1), pkbf(n2, n3));
      __builtin_amdgcn_sched_barrier(0);
    }

    if (wh == 0) { WAITV(32); BARRIER(); }   // k staged (<=32 q-stores pending)
  }
}

// ---------------------------------------------------------------------------
// K3 (MFMA): per (chunk, bh): S = Kp Kp^T, G = Qp Kp^T via mfma, KpT fused,
// T = (I + tril_strict(diag(b)S))^{-1} diag(b) by 64-lane forward subst.
// ---------------------------------------------------------------------------
__global__ __launch_bounds__(256, 2)
void k_sgsolve(const bf16* __restrict__ Kp, const bf16* __restrict__ Qp,
               const float* __restrict__ bbuf,
               bf16* __restrict__ Gs, bf16* __restrict__ Tm,
               bf16* __restrict__ KpT)
{
  __shared__ __align__(16) char bufK[2][8192];
  __shared__ __align__(16) char bufQ[2][8192];
  __shared__ float sS[CHK][65];
  __shared__ float sT[CHK][65];
  __shared__ float sBeta[CHK];

  const int tid = threadIdx.x, w = tid >> 6, lane = tid & 63;
  const int l16 = lane & 15, lg = lane >> 4;
  const int xs = l16 & 7;
  const int c = blockIdx.x, bhi = blockIdx.y;
  const size_t cb = ((size_t)bhi * LSEQ + (size_t)c * CHK) * PF;
  const size_t rowb = (size_t)bhi * LSEQ + (size_t)c * CHK;
  const size_t ktb = (((size_t)bhi * NCHK + c) * 512) * 64;
  const size_t sb = (((size_t)bhi * NCHK + c) * CHK) * CHK;

  if (tid < CHK) sBeta[tid] = bbuf[rowb + tid];

  f32x4 accS[4], accG[4];
#pragma unroll
  for (int i = 0; i < 4; i++) { accS[i] = (f32x4){0.f,0.f,0.f,0.f}; accG[i] = (f32x4){0.f,0.f,0.f,0.f}; }

#define SG_STAGE(win, b) {                                                     \
  _Pragma("unroll")                                                            \
  for (int j = 0; j < 2; j++) {                                                \
    const int row = w * 16 + j * 8 + (lane >> 3);                              \
    gl_lds16((const char*)(Kp + cb) + (size_t)row * 1024 + (size_t)(win) * 128 + (lane & 7) * 16, \
             &bufK[b][(w * 16 + j * 8) * 128]);                                \
  }                                                                            \
  _Pragma("unroll")                                                            \
  for (int j = 0; j < 2; j++) {                                                \
    const int row = w * 16 + j * 8 + (lane >> 3);                              \
    gl_lds16((const char*)(Qp + cb) + (size_t)row * 1024 + (size_t)(win) * 128 + (lane & 7) * 16, \
             &bufQ[b][(w * 16 + j * 8) * 128]);                                \
  } }

  SG_STAGE(0, 0);
  MEMFENCE;

  for (int win = 0; win < 8; win++) {
    const int b = win & 1;
    if (win < 7) { SG_STAGE(win + 1, b ^ 1); MEMFENCE; }
    if (win == 0)      { WAITV(4); }
    else if (win < 7)  { WAITV(6); }
    else               { WAITV(2); }
    BARRIER();

#pragma unroll
    for (int ks = 0; ks < 2; ks++) {
      const bf16x8 aK = *(const bf16x8*)&bufK[b][(16 * w + l16) * 128 + (((ks * 4 + lg) ^ xs) << 4)];
      const bf16x8 aQ = *(const bf16x8*)&bufQ[b][(16 * w + l16) * 128 + (((ks * 4 + lg) ^ xs) << 4)];
      bf16x8 bK[4];
#pragma unroll
      for (int nt = 0; nt < 4; nt++)
        bK[nt] = *(const bf16x8*)&bufK[b][(nt * 16 + l16) * 128 + (((ks * 4 + lg) ^ xs) << 4)];
#pragma unroll
      for (int nt = 0; nt < 4; nt++) {
        accS[nt] = MFMA(aK, bK[nt], accS[nt]);
        accG[nt] = MFMA(aQ, bK[nt], accG[nt]);
      }
    }

    // KpT emission for this window: KpT[p][l], p = win*64 + pl
#pragma unroll
    for (int jj = 0; jj < 2; jj++) {
      const int idx = jj * 256 + tid;
      const int pl = idx >> 3, l8 = idx & 7;
      unsigned short v[8];
#pragma unroll
      for (int j = 0; j < 8; j++) {
        const int l = l8 * 8 + j;
        v[j] = *(const unsigned short*)&bufK[b][l * 128 + (((pl >> 3) ^ (l & 7)) << 4) + (pl & 7) * 2];
      }
      uint4 o;
      o.x = ((unsigned)v[1] << 16) | v[0];
      o.y = ((unsigned)v[3] << 16) | v[2];
      o.z = ((unsigned)v[5] << 16) | v[4];
      o.w = ((unsigned)v[7] << 16) | v[6];
      const int p = win * 64 + pl;
      *(uint4*)&KpT[ktb + (size_t)p * 64 + ((l8 ^ (p & 7)) << 3)] = o;
    }
    BARRIER();
  }
#undef SG_STAGE

  // epilogue: S -> LDS f32, G -> global (negated strict-upper, swizzled)
#pragma unroll
  for (int nt = 0; nt < 4; nt++)
#pragma unroll
    for (int reg = 0; reg < 4; reg++) {
      const int ri = 16 * w + lg * 4 + reg;
      const int cj = nt * 16 + l16;
      sS[ri][cj] = accS[nt][reg];
      Gs[sb + ri * 64 + (((cj >> 3) ^ (ri & 7)) << 3) + (cj & 7)] =
          f2b((cj > ri) ? -accG[nt][reg] : 0.f);
    }
  __syncthreads();

  if (tid < CHK) {
    const int j = tid;
    for (int i = 0; i < CHK; i++) {
      float acc = (i == j) ? 1.f : 0.f;
      for (int k = 0; k < i; k++) acc = fmaf(-sS[i][k], sT[k][j], acc);
      sT[i][j] = sBeta[i] * acc;
    }
  }
  __syncthreads();
  for (int t = tid; t < CHK * CHK; t += 256) {
    const int r = t >> 6, ccj = t & 63;
    Tm[sb + r * 64 + (((ccj >> 3) ^ (r & 7)) << 3) + (ccj & 7)] = f2b(sT[r][ccj]);
  }
}

// ---------------------------------------------------------------------------
// K4: MFMA chunk scan. Round-7 edit: Qp(c) is issued EARLY (after the wave's
// own upre ds-reads drain, pre-B1) -- each wave's sb quarter is private, so
// this is safe; gains ~2 phases of HBM-latency cover. vmcnt re-derived.
// ---------------------------------------------------------------------------
__global__ __launch_bounds__(256, 1)
void k_scan(const bf16* __restrict__ Kp, const bf16* __restrict__ Qp,
            const bf16* __restrict__ vh, const bf16* __restrict__ Tm,
            const bf16* __restrict__ Gs, const bf16* __restrict__ KpT,
            bf16* __restrict__ lobf)
{
  __shared__ __align__(16) char sb[2][65536];   // dbuf: Kp / KpT / Qp
  __shared__ __align__(16) char sWT[16384];     // WT[d=16][p=512] bf16, xor-swz
  __shared__ __align__(16) char sTG[8192];      // T then Gs (producer-swz)
  __shared__ __align__(16) char sUT[2048];      // U^T[d=16][l=64] bf16, xor-swz
  __shared__ __align__(16) char suP[2048];      // upre^T, same layout

  const int tid = threadIdx.x;
  const int w = tid >> 6, lane = tid & 63;
  const int l16 = lane & 15, lg = lane >> 4;
  const int bhi = blockIdx.x & 31, dq = blockIdx.x >> 5;
  const int bidx = bhi >> 4, hd = bhi & 15;
  const int xs = l16 & 7;                       // xor key

  for (int i = tid; i < 4096; i += 256) ((unsigned*)sWT)[i] = 0u;

  f32x4 Wacc[8];
#pragma unroll
  for (int i = 0; i < 8; i++) Wacc[i] = (f32x4){0.f, 0.f, 0.f, 0.f};

  const size_t bh_base = (size_t)bhi * LSEQ * PF;
  const size_t tg0 = ((size_t)bhi * NCHK) * 4096;
  const size_t kt0 = ((size_t)bhi * NCHK) * (512 * 64);

  // prologue: stage Kp(0) into sb[0]
  {
    const char* g = (const char*)(Kp + bh_base);
#pragma unroll
    for (int j = 0; j < 16; j++)
      gl_lds16(g + (w * 16 + j) * 1024 + lane * 16, &sb[0][(w * 16 + j) * 1024]);
  }
  MEMFENCE;
  WAITLGKM; BARRIER();   // sWT zeros visible

  int cur = 0;
  for (int c = 0; c < NCHK; c++) {
    BARRIER();  // B0: prev-iter readers of sb/sTG/sUT done

    const size_t cb = bh_base + (size_t)c * CHK * PF;
    const char* TmC  = (const char*)(Tm + tg0 + (size_t)c * 4096);
    const char* GsC  = (const char*)(Gs + tg0 + (size_t)c * 4096);
    const char* KpTC = (const char*)(KpT + kt0 + (size_t)c * (512 * 64));
    const char* QpC  = (const char*)(Qp + cb);
    const char* KpN  = (const char*)(Kp + cb + CHK * PF);

    // V (compiler-managed waits)
    const bf16* vp = vh + ((size_t)bhi * LSEQ + c * 64 + w * 16 + lg * 4) * 64 + dq * 16 + l16;
    const float v0 = b2f(vp[0]),   v1 = b2f(vp[64]);
    const float v2 = b2f(vp[128]), v3 = b2f(vp[192]);
    MEMFENCE;
    // stage T(c) -> sTG
#pragma unroll
    for (int j = 0; j < 2; j++)
      gl_lds16(TmC + (w * 2 + j) * 1024 + lane * 16, &sTG[(w * 2 + j) * 1024]);
    MEMFENCE;
    // stage KpT(c) -> sb[cur^1]
#pragma unroll
    for (int j = 0; j < 16; j++)
      gl_lds16(KpTC + (w * 16 + j) * 1024 + lane * 16, &sb[cur ^ 1][(w * 16 + j) * 1024]);
    MEMFENCE;
    WAITV(22);  // Kp(c) ready (younger: prev stores4 + T2 + KpT16)

    // ---- upre = V - Kp*W(old) ----
    f32x4 a0v = (f32x4){0.f,0.f,0.f,0.f}, a1v = (f32x4){0.f,0.f,0.f,0.f};
#pragma unroll
    for (int ks = 0; ks < 16; ks += 2) {
      const bf16x8 aa0 = *(const bf16x8*)&sb[cur][(16 * w + l16) * 1024 + ((((ks    ) * 4 + lg) ^ xs) << 4)];
      const bf16x8 bb0 = *(const bf16x8*)&sWT[l16 * 1024 + ((((ks    ) * 4 + lg) ^ xs) << 4)];
      a0v = MFMA(aa0, bb0, a0v);
      const bf16x8 aa1 = *(const bf16x8*)&sb[cur][(16 * w + l16) * 1024 + ((((ks + 1) * 4 + lg) ^ xs) << 4)];
      const bf16x8 bb1 = *(const bf16x8*)&sWT[l16 * 1024 + ((((ks + 1) * 4 + lg) ^ xs) << 4)];
      a1v = MFMA(aa1, bb1, a1v);
    }
    {
      const int l0r = 16 * w + lg * 4;
      const unsigned plo = pkbf(v0 - (a0v[0] + a1v[0]), v1 - (a0v[1] + a1v[1]));
      const unsigned phi = pkbf(v2 - (a0v[2] + a1v[2]), v3 - (a0v[3] + a1v[3]));
      *(uint2*)&suP[l16 * 128 + ((((l0r >> 3)) ^ xs) << 4) + (l0r & 7) * 2] = make_uint2(plo, phi);
    }
    WAITLGKM;
    // EARLY stage Qp(c) -> sb[cur] (own-wave quarter; own upre reads drained)
#pragma unroll
    for (int j = 0; j < 16; j++)
      gl_lds16(QpC + (w * 16 + j) * 1024 + lane * 16, &sb[cur][(w * 16 + j) * 1024]);
    MEMFENCE;
    BARRIER();  // B1: suP ready
    WAITV(32);  // T ready (younger: KpT16 + Qp16)

    // ---- U = T * upre ----
    {
      f32x4 ua = (f32x4){0.f,0.f,0.f,0.f};
#pragma unroll
      for (int ks = 0; ks < 2; ks++) {
        const bf16x8 aa = *(const bf16x8*)&sTG[(16 * w + l16) * 128 + (((ks * 4 + lg) ^ xs) << 4)];
        const bf16x8 bb = *(const bf16x8*)&suP[l16 * 128 + (((ks * 4 + lg) ^ xs) << 4)];
        ua = MFMA(aa, bb, ua);
      }
      const int l0r = 16 * w + lg * 4;
      *(uint2*)&sUT[l16 * 128 + ((((l0r >> 3)) ^ xs) << 4) + (l0r & 7) * 2] =
          make_uint2(pkbf(ua[0], ua[1]), pkbf(ua[2], ua[3]));
    }
    WAITLGKM; BARRIER();  // B2: sUT ready
    WAITV(16);            // KpT ready (younger: Qp16)

    // ---- W += KpT * U ----
    {
      bf16x8 bu[2];
#pragma unroll
      for (int ks = 0; ks < 2; ks++)
        bu[ks] = *(const bf16x8*)&sUT[l16 * 128 + (((ks * 4 + lg) ^ xs) << 4)];
#pragma unroll
      for (int mt = 0; mt < 8; mt++) {
        const int p = w * 128 + mt * 16 + l16;
#pragma unroll
        for (int ks = 0; ks < 2; ks++) {
          const bf16x8 aa = *(const bf16x8*)&sb[cur ^ 1][p * 128 + (((ks * 4 + lg) ^ xs) << 4)];
          Wacc[mt] = MFMA(aa, bu[ks], Wacc[mt]);
        }
      }
#pragma unroll
      for (int mt = 0; mt < 8; mt++) {
        const int p0m = w * 128 + mt * 16 + lg * 4;
        *(uint2*)&sWT[l16 * 1024 + ((((p0m >> 3)) ^ xs) << 4) + (p0m & 7) * 2] =
            make_uint2(pkbf(Wacc[mt][0], Wacc[mt][1]), pkbf(Wacc[mt][2], Wacc[mt][3]));
      }
    }
    WAITLGKM; BARRIER();  // B3: sWT(new) ready

    // stage Gs(c) -> sTG ; prefetch Kp(c+1) -> sb[cur^1]
#pragma unroll
    for (int j = 0; j < 2; j++)
      gl_lds16(GsC + (w * 2 + j) * 1024 + lane * 16, &sTG[(w * 2 + j) * 1024]);
    MEMFENCE;
    if (c < NCHK - 1) {
#pragma unroll
      for (int j = 0; j < 16; j++)
        gl_lds16(KpN + (w * 16 + j) * 1024 + lane * 16, &sb[cur ^ 1][(w * 16 + j) * 1024]);
    }
    MEMFENCE;
    if (c < NCHK - 1) { WAITV(18); } else { WAITV(2); }   // Qp ready

    // ---- out = 0.125 * (Qp*W_new - Gs*U) ----
    f32x4 o0 = (f32x4){0.f,0.f,0.f,0.f}, o1 = (f32x4){0.f,0.f,0.f,0.f};
#pragma unroll
    for (int ks = 0; ks < 16; ks += 2) {
      const bf16x8 aa0 = *(const bf16x8*)&sb[cur][(16 * w + l16) * 1024 + ((((ks    ) * 4 + lg) ^ xs) << 4)];
      const bf16x8 bb0 = *(const bf16x8*)&sWT[l16 * 1024 + ((((ks    ) * 4 + lg) ^ xs) << 4)];
      o0 = MFMA(aa0, bb0, o0);
      const bf16x8 aa1 = *(const bf16x8*)&sb[cur][(16 * w + l16) * 1024 + ((((ks + 1) * 4 + lg) ^ xs) << 4)];
      const bf16x8 bb1 = *(const bf16x8*)&sWT[l16 * 1024 + ((((ks + 1) * 4 + lg) ^ xs) << 4)];
      o1 = MFMA(aa1, bb1, o1);
    }
    if (c < NCHK - 1) { WAITV(16); } else { WAITV(0); }   // Gs ready
#pragma unroll
    for (int ks = 0; ks < 2; ks++) {
      const bf16x8 aa = *(const bf16x8*)&sTG[(16 * w + l16) * 128 + (((ks * 4 + lg) ^ xs) << 4)];
      const bf16x8 bb = *(const bf16x8*)&sUT[l16 * 128 + (((ks * 4 + lg) ^ xs) << 4)];
      o0 = MFMA(aa, bb, o0);   // Gs pre-negated by producer
    }
    {
      const int colb = hd * 64 + dq * 16 + l16;
#pragma unroll
      for (int reg = 0; reg < 4; reg++) {
        const int l = c * 64 + 16 * w + lg * 4 + reg;
        const int r = l * BSZN + bidx;
        const int cp = (colb & ~63) | ((((colb >> 3) & 7) ^ (r & 7)) << 3) | (colb & 7);
        lobf[(size_t)r * DMODEL + cp] = f2b(0.125f * (o0[reg] + o1[reg]));
      }
    }
    cur ^= 1;
  }
}

// ---------------------------------------------------------------------------
// K5b: LayerNorm (unchanged)
// ---------------------------------------------------------------------------
__global__ __launch_bounds__(256)
void k_ln(const float* __restrict__ ao, const float* __restrict__ gamma,
          const float* __restrict__ beta, float* __restrict__ out)
{
  const int row = blockIdx.x;
  const int tid = threadIdx.x;
  __shared__ float r1[4], r2[4];
  const float4 v = *(const float4*)&ao[(size_t)row * DMODEL + tid * 4];
  float s1 = v.x + v.y + v.z + v.w;
  float s2 = v.x * v.x + v.y * v.y + v.z * v.z + v.w * v.w;
  for (int off = 32; off > 0; off >>= 1) {
    s1 += __shfl_down(s1, off);
    s2 += __shfl_down(s2, off);
  }
  if ((tid & 63) == 0) { r1[tid >> 6] = s1; r2[tid >> 6] = s2; }
  __syncthreads();
  const float ts1 = r1[0] + r1[1] + r1[2] + r1[3];
  const float ts2 = r2[0] + r2[1] + r2[2] + r2[3];
  const float mu = ts1 * (1.f / DMODEL);
  const float var = ts2 * (1.f / DMODEL) - mu * mu;
  const float rs = rsqrtf(var + 1e-5f);
  const float4 g = *(const float4*)&gamma[tid * 4];
  const float4 b = *(const float4*)&beta[tid * 4];
  float4 o;
  o.x = (v.x - mu) * rs * g.x + b.x;
  o.y = (v.y - mu) * rs * g.y + b.y;
  o.z = (v.z - mu) * rs * g.z + b.z;
  o.w = (v.w - mu) * rs * g.w + b.w;
  *(float4*)&out[(size_t)row * DMODEL + tid * 4] = o;
}

// ---------------------------------------------------------------------------
extern "C" void kernel_launch(void* const* d_in, const int* in_sizes, int n_in,
                              void* d_out, int out_size, void* d_ws, size_t ws_size,
                              hipStream_t stream)
{
  (void)in_sizes; (void)n_in; (void)out_size; (void)ws_size;
  const float* h   = (const float*)d_in[0];
  const float* Wq  = (const float*)d_in[1];
  const float* Wo  = (const float*)d_in[2];
  const float* gam = (const float*)d_in[3];
  const float* bet = (const float*)d_in[4];
  const float* pm  = (const float*)d_in[5];
  float* out = (float*)d_out;

  char* ws = (char*)d_ws;
  size_t off = 0;
  auto alloc = [&](size_t bytes) -> void* {
    void* p = ws + off;
    off += (bytes + 255) & ~(size_t)255;
    return p;
  };
  // total workspace ~= 229 MB
  bf16*  vh  = (bf16*)alloc((size_t)BHN * LSEQ * DH * 2);            //  8.4 MB
  float* bbf = (float*)alloc((size_t)BHN * LSEQ * 4);                //  0.3 MB
  bf16*  Kp  = (bf16*)alloc((size_t)BHN * LSEQ * PF * 2);            // 67.1 MB
  bf16*  Qp  = (bf16*)alloc((size_t)BHN * LSEQ * PF * 2);            // 67.1 MB
  bf16*  Tm  = (bf16*)alloc((size_t)BHN * NCHK * CHK * CHK * 2);     //  8.4 MB
  bf16*  Gs  = (bf16*)alloc((size_t)BHN * NCHK * CHK * CHK * 2);     //  8.4 MB
  char*  R   = (char*)alloc((size_t)BHN * NCHK * 512 * 64 * 2);      // 67.1 MB shared
  bf16*  WoT = (bf16*)alloc((size_t)DMODEL * DMODEL * 2);            //  2.1 MB
  bf16*  pmThi = (bf16*)alloc((size_t)MPROJ * 64 * 2);               // 32 KB
  bf16*  pmTlo = (bf16*)alloc((size_t)MPROJ * 64 * 2);               // 32 KB
  // region R lifetimes:
  //  phase1 (cvt/qkvb/featm): qh(8.4) | kh(8.4) | hbf(8.4) | WqT(6.6)
  //  phase2 (sgsolve/scan):   KpT (67.1)
  //  phase3 (outgemm/ln):     ao (16.8 f32)
  bf16*  qh  = (bf16*)R;
  bf16*  kh  = (bf16*)(R + (size_t)BHN * LSEQ * DH * 2);
  bf16*  hbf = (bf16*)(R + (size_t)2 * BHN * LSEQ * DH * 2);
  bf16*  WqT = (bf16*)(R + (size_t)3 * BHN * LSEQ * DH * 2);
  bf16*  KpT = (bf16*)R;
  float* ao  = (float*)R;
  bf16*  lobf = (bf16*)d_out;   // d_out scratch; fully rewritten by k_ln

  k_cvth     <<<dim3(2048),                       256, 0, stream>>>(h, hbf);
  k_cvtw     <<<dim3(NQPAD / 64, 16),             256, 0, stream>>>(Wq, WqT, NQKV);
  k_cvtw     <<<dim3(DMODEL / 64, 16),            256, 0, stream>>>(Wo, WoT, DMODEL);
  k_cvtpm    <<<dim3(1),                          256, 0, stream>>>(pm, pmThi, pmTlo);
  k_gemm_qkvb<<<dim3(NQPAD / 128, 4096 / 128),    256, 0, stream>>>(hbf, WqT, qh, kh, vh, bbf);
  k_featm    <<<dim3(LSEQ / 64, BHN),             256, 0, stream>>>(qh, kh, pmThi, pmTlo, Qp, Kp);
  k_sgsolve  <<<dim3(NCHK, BHN),                  256, 0, stream>>>(Kp, Qp, bbf, Gs, Tm, KpT);
  k_scan     <<<dim3(128),                        256, 0, stream>>>(Kp, Qp, vh, Tm, Gs, KpT, lobf);
  k_gemm_out <<<dim3(DMODEL / 128, 4096 / 128),   256, 0, stream>>>(lobf, WoT, h, ao);
  k_ln       <<<dim3(4096),                       256, 0, stream>>>(ao, gam, bet, out);
}